// Round 19
// baseline (140.170 us; speedup 1.0000x reference)
//
#include <hip/hip_runtime.h>
#include <hip/hip_bf16.h>
#include <math.h>

typedef __bf16 bfx4 __attribute__((ext_vector_type(4)));
typedef __bf16 bfx8 __attribute__((ext_vector_type(8)));
typedef float  f32x4 __attribute__((ext_vector_type(4)));

#define BATCH 16
#define NTOK  1024
#define CDIM  256
#define NHEAD 8
#define DHEAD 32
#define QKVD  768
#define INNER 256
#define SCALE 0.17677669529663687f
#define LOG2E 1.4426950408889634f

#if __has_builtin(__builtin_amdgcn_exp2f)
#define EXP2(x) __builtin_amdgcn_exp2f(x)
#else
#define EXP2(x) exp2f(x)
#endif

// ------- fused transpose + LN1: x[B][C][N] -> t_bf bf16 [tok][C], hln bf16 --
__launch_bounds__(256)
__global__ void txln_kernel(const float* __restrict__ x, const float* __restrict__ g,
                            const float* __restrict__ bb, __bf16* __restrict__ tb,
                            __bf16* __restrict__ hln) {
  __shared__ float tile[256][65];
  const int b = blockIdx.z, n0 = blockIdx.x * 64;
  const int tt = threadIdx.x;
  const float* src = x + (size_t)b * CDIM * NTOK;
  const int rc = tt >> 4, nc = (tt & 15) * 4;
  #pragma unroll
  for (int i = 0; i < 16; ++i) {
    int c = rc + i * 16;
    *(float4*)&tile[c][nc] = *(const float4*)&src[(size_t)c * NTOK + n0 + nc];
  }
  __syncthreads();
  const int n = tt >> 2, c0 = (tt & 3) * 64;
  float vals[64];
  float s = 0.f, s2 = 0.f;
  #pragma unroll
  for (int j = 0; j < 64; ++j) {
    float v = tile[c0 + j][n];
    vals[j] = v; s += v; s2 += v * v;
  }
  s  += __shfl_xor(s, 1);  s  += __shfl_xor(s, 2);
  s2 += __shfl_xor(s2, 1); s2 += __shfl_xor(s2, 2);
  float mu = s * 0.00390625f;
  float var = s2 * 0.00390625f - mu * mu;
  float rs = rsqrtf(var + 1e-5f);
  size_t row = ((size_t)b * NTOK + n0 + n) * CDIM;
  #pragma unroll
  for (int j = 0; j < 64; j += 4) {
    const float4 gg = *(const float4*)&g[c0 + j];
    const float4 bv = *(const float4*)&bb[c0 + j];
    bfx4 tv;
    tv[0] = (__bf16)vals[j];     tv[1] = (__bf16)vals[j + 1];
    tv[2] = (__bf16)vals[j + 2]; tv[3] = (__bf16)vals[j + 3];
    *(bfx4*)&tb[row + c0 + j] = tv;
    bfx4 o;
    o[0] = (__bf16)((vals[j]     - mu) * rs * gg.x + bv.x);
    o[1] = (__bf16)((vals[j + 1] - mu) * rs * gg.y + bv.y);
    o[2] = (__bf16)((vals[j + 2] - mu) * rs * gg.z + bv.z);
    o[3] = (__bf16)((vals[j + 3] - mu) * rs * gg.w + bv.w);
    *(bfx4*)&hln[row + c0 + j] = o;
  }
}

// ---- merged prep: weight transpose+cast (blocks 0..2047) + bias (2048..6143)
__launch_bounds__(256)
__global__ void prep_kernel(const float* __restrict__ Wqkv, const float* __restrict__ Wo,
                            const float* __restrict__ W1, const float* __restrict__ W2,
                            __bf16* __restrict__ Wqkvt, __bf16* __restrict__ Wot,
                            __bf16* __restrict__ W1t, __bf16* __restrict__ W2t,
                            const float* __restrict__ table, __bf16* __restrict__ biasB) {
  if (blockIdx.x < 2048) {
    int idx = blockIdx.x * 256 + threadIdx.x;
    const float* W; __bf16* Wt; int lk, Nn, off;
    if (idx < 196608)      { W = Wqkv; Wt = Wqkvt; lk = 8; Nn = 768; off = idx; }
    else if (idx < 262144) { W = Wo;   Wt = Wot;   lk = 8; Nn = 256; off = idx - 196608; }
    else if (idx < 393216) { W = W1;   Wt = W1t;   lk = 8; Nn = 512; off = idx - 262144; }
    else                   { W = W2;   Wt = W2t;   lk = 9; Nn = 256; off = idx - 393216; }
    int n = off >> lk, k = off & ((1 << lk) - 1);
    Wt[off] = (__bf16)W[(size_t)k * Nn + n];
  } else {
    int idx = (blockIdx.x - 2048) * 256 + threadIdx.x;   // h*2^17 + q*2^7 + k8
    int k8 = (idx & 127) * 8, q = (idx >> 7) & 1023, h = idx >> 17;
    int qi = q >> 5, qj = q & 31;
    bfx8 o;
    #pragma unroll
    for (int j = 0; j < 8; ++j) {
      int k = k8 + j, ki = k >> 5, kj = k & 31;
      int r = (qi - ki + 31) * 63 + (qj - kj + 31);
      o[j] = (__bf16)(table[r * 8 + h] * LOG2E);
    }
    *(bfx8*)&biasB[((size_t)idx) * 8] = o;
  }
}

// ---------------- GEMM 128x128 tile, BK=64, k-permuted LDS (R13) ------------
// EPI 0: store bf16 (qkv: if vTout && n0>=512, scatter V into vT instead).
// EPI 2: +bias, GELU -> bf16.
// EPI 4: +bias[n] + residb(bf16) -> fp32 TRANSPOSED to out[b][c][tok] via LDS.
template <int EPI>
__launch_bounds__(256)
__global__ void gemm128_kernel(const __bf16* __restrict__ A, const __bf16* __restrict__ Bt,
                               const float* __restrict__ bias,
                               const __bf16* __restrict__ residb,
                               void* __restrict__ outp, __bf16* __restrict__ vTout,
                               int Nn, int K) {
  __shared__ char smem[36864];
  __bf16 (*As)[72] = (__bf16(*)[72])smem;
  __bf16 (*Bs)[72] = (__bf16(*)[72])(smem + 18432);
  const int t = threadIdx.x, lane = t & 63, w = t >> 6;
  const int m0 = blockIdx.x * 128, n0 = blockIdx.y * 128;
  const int wr = w >> 1, wc = w & 1;
  const int lr = lane & 15, kb = (lane >> 4) * 4;
  int srow[4], sp0[4], sp1[4];
  #pragma unroll
  for (int i = 0; i < 4; ++i) {
    int cid = i * 256 + t, kb8 = (cid & 7) * 8;
    srow[i] = cid >> 3;
    int b0 = kb8, b1 = kb8 + 4;
    sp0[i] = (b0 & 32) + ((b0 & 12) << 1) + (((b0 >> 4) & 1) << 2) + (b0 & 3);
    sp1[i] = (b1 & 32) + ((b1 & 12) << 1) + (((b1 >> 4) & 1) << 2) + (b1 & 3);
  }
  f32x4 acc[4][4] = {};
  bfx8 ra[4], rb[4];
  auto gload = [&](int k0) {
    #pragma unroll
    for (int i = 0; i < 4; ++i) {
      int kc8 = ((i * 256 + t) & 7) * 8;
      ra[i] = *(const bfx8*)&A[(size_t)(m0 + srow[i]) * K + k0 + kc8];
      rb[i] = *(const bfx8*)&Bt[(size_t)(n0 + srow[i]) * K + k0 + kc8];
    }
  };
  gload(0);
  for (int k0 = 0; k0 < K; k0 += 64) {
    __syncthreads();
    #pragma unroll
    for (int i = 0; i < 4; ++i) {
      *(bfx4*)&As[srow[i]][sp0[i]] = __builtin_shufflevector(ra[i], ra[i], 0, 1, 2, 3);
      *(bfx4*)&As[srow[i]][sp1[i]] = __builtin_shufflevector(ra[i], ra[i], 4, 5, 6, 7);
      *(bfx4*)&Bs[srow[i]][sp0[i]] = __builtin_shufflevector(rb[i], rb[i], 0, 1, 2, 3);
      *(bfx4*)&Bs[srow[i]][sp1[i]] = __builtin_shufflevector(rb[i], rb[i], 4, 5, 6, 7);
    }
    __syncthreads();
    if (k0 + 64 < K) gload(k0 + 64);
    #pragma unroll
    for (int ks = 0; ks < 2; ++ks) {
      bfx8 af[4], bf[4];
      #pragma unroll
      for (int mi = 0; mi < 4; ++mi)
        af[mi] = *(const bfx8*)&As[wr * 64 + mi * 16 + lr][ks * 32 + kb * 2];
      #pragma unroll
      for (int ni = 0; ni < 4; ++ni)
        bf[ni] = *(const bfx8*)&Bs[wc * 64 + ni * 16 + lr][ks * 32 + kb * 2];
      #pragma unroll
      for (int mi = 0; mi < 4; ++mi)
        #pragma unroll
        for (int ni = 0; ni < 4; ++ni)
          acc[mi][ni] = __builtin_amdgcn_mfma_f32_16x16x32_bf16(af[mi], bf[ni],
                                                                acc[mi][ni], 0, 0, 0);
    }
  }
  if (EPI == 4) {
    float* Ty = (float*)smem;
    const int bb_ = m0 >> 10, tok0 = m0 & 1023;
    float* obase = (float*)outp + (size_t)bb_ * CDIM * NTOK + tok0;
    #pragma unroll
    for (int h2 = 0; h2 < 2; ++h2) {
      __syncthreads();
      if (wc == h2) {
        #pragma unroll
        for (int ni = 0; ni < 4; ++ni) {
          int ch = ni * 16 + lr;
          float bn = bias[n0 + h2 * 64 + ch];
          #pragma unroll
          for (int mi = 0; mi < 4; ++mi) {
            int tk = wr * 64 + mi * 16 + kb;
            float4 v4;
            #pragma unroll
            for (int r = 0; r < 4; ++r)
              ((float*)&v4)[r] = acc[mi][ni][r] + bn +
                  (float)residb[(size_t)(m0 + tk + r) * Nn + n0 + h2 * 64 + ch];
            *(float4*)&Ty[ch * 132 + tk] = v4;
          }
        }
      }
      __syncthreads();
      int ch = t >> 2, sc = t & 3;
      #pragma unroll
      for (int j = 0; j < 8; ++j) {
        int c4 = sc + j * 4;
        *(float4*)&obase[(size_t)(n0 + h2 * 64 + ch) * NTOK + c4 * 4] =
            *(const float4*)&Ty[ch * 132 + c4 * 4];
      }
    }
    return;
  }
  if (EPI == 0 && vTout != nullptr && n0 >= 512) {
    #pragma unroll
    for (int mi = 0; mi < 4; ++mi)
      #pragma unroll
      for (int ni = 0; ni < 4; ++ni) {
        int n = n0 + wc * 64 + ni * 16 + lr;
        int cp = n - 512, hh = cp >> 5, dd = cp & 31;
        int m = m0 + wr * 64 + mi * 16 + kb;
        int bb_ = m >> 10, tok = m & 1023;
        bfx4 o;
        o[0] = (__bf16)acc[mi][ni][0]; o[1] = (__bf16)acc[mi][ni][1];
        o[2] = (__bf16)acc[mi][ni][2]; o[3] = (__bf16)acc[mi][ni][3];
        *(bfx4*)&vTout[(((size_t)bb_ * NHEAD + hh) * DHEAD + dd) * NTOK + tok] = o;
      }
    return;
  }
  #pragma unroll
  for (int mi = 0; mi < 4; ++mi)
    #pragma unroll
    for (int ni = 0; ni < 4; ++ni)
      #pragma unroll
      for (int r = 0; r < 4; ++r) {
        int m = m0 + wr * 64 + mi * 16 + kb + r;
        int n = n0 + wc * 64 + ni * 16 + lr;
        float v = acc[mi][ni][r];
        if (EPI == 0) {
          ((__bf16*)outp)[(size_t)m * Nn + n] = (__bf16)v;
        } else if (EPI == 2) {
          v += bias[n];
          v = 0.5f * v * (1.0f + erff(v * 0.70710678118f));
          ((__bf16*)outp)[(size_t)m * Nn + n] = (__bf16)v;
        }
      }
}

// ---- Wo GEMM (BM=64, BN=256 full width) + bias + resid + fused LN2 ---------
__launch_bounds__(512)
__global__ void gemmWoLn_kernel(const __bf16* __restrict__ A, const __bf16* __restrict__ Bt,
                                const float* __restrict__ bias,
                                const __bf16* __restrict__ residb,
                                const float* __restrict__ g2, const float* __restrict__ b2v,
                                __bf16* __restrict__ t2, __bf16* __restrict__ hln) {
  __shared__ char smem[46080];
  __bf16 (*As)[72] = (__bf16(*)[72])smem;             // 64 x 72
  __bf16 (*Bs)[72] = (__bf16(*)[72])(smem + 9216);    // 256 x 72
  const int t = threadIdx.x, lane = t & 63, w = t >> 6;
  const int m0 = blockIdx.x * 64;
  const int wr = w >> 2, wc = w & 3;
  const int lr = lane & 15, kb = (lane >> 4) * 4;
  const int K = 256;
  const int arow = t >> 3, ac8 = (t & 7) * 8;
  int ap0, ap1;
  {
    int b0 = ac8, b1 = ac8 + 4;
    ap0 = (b0 & 32) + ((b0 & 12) << 1) + (((b0 >> 4) & 1) << 2) + (b0 & 3);
    ap1 = (b1 & 32) + ((b1 & 12) << 1) + (((b1 >> 4) & 1) << 2) + (b1 & 3);
  }
  int brow[4], bp0[4], bp1[4], bc8[4];
  #pragma unroll
  for (int j = 0; j < 4; ++j) {
    int cid = j * 512 + t;
    brow[j] = cid >> 3;
    bc8[j] = (cid & 7) * 8;
    int b0 = bc8[j], b1 = bc8[j] + 4;
    bp0[j] = (b0 & 32) + ((b0 & 12) << 1) + (((b0 >> 4) & 1) << 2) + (b0 & 3);
    bp1[j] = (b1 & 32) + ((b1 & 12) << 1) + (((b1 >> 4) & 1) << 2) + (b1 & 3);
  }
  f32x4 acc[2][4] = {};
  bfx8 ra, rb[4];
  auto gload = [&](int k0) {
    ra = *(const bfx8*)&A[(size_t)(m0 + arow) * K + k0 + ac8];
    #pragma unroll
    for (int j = 0; j < 4; ++j)
      rb[j] = *(const bfx8*)&Bt[(size_t)brow[j] * K + k0 + bc8[j]];
  };
  gload(0);
  for (int k0 = 0; k0 < K; k0 += 64) {
    __syncthreads();
    *(bfx4*)&As[arow][ap0] = __builtin_shufflevector(ra, ra, 0, 1, 2, 3);
    *(bfx4*)&As[arow][ap1] = __builtin_shufflevector(ra, ra, 4, 5, 6, 7);
    #pragma unroll
    for (int j = 0; j < 4; ++j) {
      *(bfx4*)&Bs[brow[j]][bp0[j]] = __builtin_shufflevector(rb[j], rb[j], 0, 1, 2, 3);
      *(bfx4*)&Bs[brow[j]][bp1[j]] = __builtin_shufflevector(rb[j], rb[j], 4, 5, 6, 7);
    }
    __syncthreads();
    if (k0 + 64 < K) gload(k0 + 64);
    #pragma unroll
    for (int ks = 0; ks < 2; ++ks) {
      bfx8 af[2], bf[4];
      #pragma unroll
      for (int mi = 0; mi < 2; ++mi)
        af[mi] = *(const bfx8*)&As[wr * 32 + mi * 16 + lr][ks * 32 + kb * 2];
      #pragma unroll
      for (int ni = 0; ni < 4; ++ni)
        bf[ni] = *(const bfx8*)&Bs[wc * 64 + ni * 16 + lr][ks * 32 + kb * 2];
      #pragma unroll
      for (int mi = 0; mi < 2; ++mi)
        #pragma unroll
        for (int ni = 0; ni < 4; ++ni)
          acc[mi][ni] = __builtin_amdgcn_mfma_f32_16x16x32_bf16(af[mi], bf[ni],
                                                                acc[mi][ni], 0, 0, 0);
    }
  }
  float colg[4], colb[4];
  #pragma unroll
  for (int ni = 0; ni < 4; ++ni) {
    int colq = wc * 64 + ni * 16 + lr;
    float bn = bias[colq];
    colg[ni] = g2[colq];
    colb[ni] = b2v[colq];
    #pragma unroll
    for (int mi = 0; mi < 2; ++mi)
      #pragma unroll
      for (int r = 0; r < 4; ++r) {
        int m = m0 + wr * 32 + mi * 16 + kb + r;
        acc[mi][ni][r] += bn + (float)residb[(size_t)m * CDIM + colq];
      }
  }
  float ps[2][4], pq[2][4];
  #pragma unroll
  for (int mi = 0; mi < 2; ++mi)
    #pragma unroll
    for (int r = 0; r < 4; ++r) {
      float s = 0.f, q = 0.f;
      #pragma unroll
      for (int ni = 0; ni < 4; ++ni) {
        float v = acc[mi][ni][r];
        s += v; q += v * v;
      }
      #pragma unroll
      for (int o = 1; o < 16; o <<= 1) { s += __shfl_xor(s, o); q += __shfl_xor(q, o); }
      ps[mi][r] = s; pq[mi][r] = q;
    }
  __syncthreads();
  float* red = (float*)smem;              // [64][8]: sum[wc], sq[4+wc]
  if (lr == 0) {
    #pragma unroll
    for (int mi = 0; mi < 2; ++mi)
      #pragma unroll
      for (int r = 0; r < 4; ++r) {
        int rl = wr * 32 + mi * 16 + kb + r;
        red[rl * 8 + wc] = ps[mi][r];
        red[rl * 8 + 4 + wc] = pq[mi][r];
      }
  }
  __syncthreads();
  if (t < 64) {
    float s = red[t * 8] + red[t * 8 + 1] + red[t * 8 + 2] + red[t * 8 + 3];
    float q = red[t * 8 + 4] + red[t * 8 + 5] + red[t * 8 + 6] + red[t * 8 + 7];
    float mu = s * 0.00390625f;
    float var = q * 0.00390625f - mu * mu;
    red[t * 8] = mu;
    red[t * 8 + 1] = rsqrtf(var + 1e-5f);
  }
  __syncthreads();
  #pragma unroll
  for (int mi = 0; mi < 2; ++mi)
    #pragma unroll
    for (int r = 0; r < 4; ++r) {
      int rl = wr * 32 + mi * 16 + kb + r;
      float mu = red[rl * 8], rs = red[rl * 8 + 1];
      size_t rowoff = (size_t)(m0 + rl) * CDIM;
      #pragma unroll
      for (int ni = 0; ni < 4; ++ni) {
        int colq = wc * 64 + ni * 16 + lr;
        float v = acc[mi][ni][r];
        t2[rowoff + colq] = (__bf16)v;
        hln[rowoff + colq] = (__bf16)((v - mu) * rs * colg[ni] + colb[ni]);
      }
    }
}

// ---- flash attention, QBLK=128, 8 waves (16 q-rows/wave), 4 blocks/CU ------
__launch_bounds__(512)
__global__ void attn_kernel(const __bf16* __restrict__ qkv, const __bf16* __restrict__ vT,
                            const __bf16* __restrict__ biasB, __bf16* __restrict__ outb) {
  __shared__ __bf16 Ks[64][40];
  __shared__ __bf16 Vs[32][72];
  __shared__ __bf16 Bls[128][72];
  const int q0 = blockIdx.x * 128, h = blockIdx.y, b = blockIdx.z;
  const int t = threadIdx.x, lane = t & 63, w = t >> 6;     // 8 waves
  const int lr = lane & 15, kb = (lane >> 4) * 4;
  const size_t qbase = (size_t)b * NTOK * QKVD;
  const float qsc = SCALE * LOG2E;
  bfx8 qf;
  {
    const __bf16* qp = &qkv[qbase + (size_t)(q0 + 16 * w + lr) * QKVD + h * DHEAD];
    bfx4 lo = *(const bfx4*)&qp[kb];
    bfx4 hi = *(const bfx4*)&qp[kb + 16];
    #pragma unroll
    for (int j = 0; j < 4; ++j) {
      qf[j]     = (__bf16)((float)lo[j] * qsc);
      qf[j + 4] = (__bf16)((float)hi[j] * qsc);
    }
  }
  float l_run = 0.f;
  f32x4 oacc[2] = {};
  const int st_ = t & 255;
  const int krow = st_ >> 2, kc8 = (st_ & 3) * 8;   // K stage (t<256): 64x32
  const int vrow = st_ >> 3, vc8 = (st_ & 7) * 8;   // V stage (t>=256): 32x64
  const __bf16* kvptr = (t < 256)
      ? &qkv[qbase + (size_t)krow * QKVD + INNER + h * DHEAD + kc8]
      : &vT[(((size_t)b * NHEAD + h) * DHEAD + vrow) * NTOK + vc8];
  const __bf16* bbase = &biasB[((size_t)h * NTOK + q0) * NTOK];
  bfx8 rkv, rbias[2];
  auto issue = [&](int k0) {
    rkv = (t < 256) ? *(const bfx8*)&kvptr[(size_t)k0 * QKVD]
                    : *(const bfx8*)&kvptr[k0];
    #pragma unroll
    for (int j = 0; j < 2; ++j) {
      int lin = j * 512 + t;                  // 1024 chunks: 128 rows x 128B
      int br = lin >> 3, bc8 = (lin & 7) * 8;
      rbias[j] = *(const bfx8*)&bbase[(size_t)br * NTOK + k0 + bc8];
    }
  };
  issue(0);
  for (int kt = 0; kt < 16; ++kt) {
    __syncthreads();
    if (t < 256) *(bfx8*)&Ks[krow][kc8] = rkv;
    else         *(bfx8*)&Vs[vrow][vc8] = rkv;
    #pragma unroll
    for (int j = 0; j < 2; ++j) {
      int lin = j * 512 + t;
      int br = lin >> 3, bc8 = (lin & 7) * 8;
      *(bfx8*)&Bls[br][bc8] = rbias[j];
    }
    __syncthreads();
    if (kt < 15) issue((kt + 1) * 64);
    bfx8 kf[4], vfr[4];
    #pragma unroll
    for (int f = 0; f < 4; ++f) {
      bfx4 klo = *(const bfx4*)&Ks[16 * f + lr][kb];
      bfx4 khi = *(const bfx4*)&Ks[16 * f + lr][kb + 16];
      kf[f] = __builtin_shufflevector(klo, khi, 0, 1, 2, 3, 4, 5, 6, 7);
    }
    #pragma unroll
    for (int s = 0; s < 2; ++s)
      #pragma unroll
      for (int df = 0; df < 2; ++df) {
        bfx4 vlo = *(const bfx4*)&Vs[16 * df + lr][s * 32 + kb];
        bfx4 vhi = *(const bfx4*)&Vs[16 * df + lr][s * 32 + kb + 16];
        vfr[s * 2 + df] = __builtin_shufflevector(vlo, vhi, 0, 1, 2, 3, 4, 5, 6, 7);
      }
    const int qrow_l = 16 * w + lr;
    f32x4 st[4];
    #pragma unroll
    for (int f = 0; f < 4; ++f) {
      bfx4 bv = *(const bfx4*)&Bls[qrow_l][16 * f + kb];
      f32x4 c;
      c[0] = (float)bv[0]; c[1] = (float)bv[1];
      c[2] = (float)bv[2]; c[3] = (float)bv[3];
      st[f] = __builtin_amdgcn_mfma_f32_16x16x32_bf16(kf[f], qf, c, 0, 0, 0);
    }
    float p[4][4], tsum = 0.f;
    #pragma unroll
    for (int f = 0; f < 4; ++f)
      #pragma unroll
      for (int r = 0; r < 4; ++r) {
        float e = EXP2(st[f][r]);
        p[f][r] = e;
        tsum += e;
      }
    l_run += tsum;
    bfx8 pa0, pa1;
    #pragma unroll
    for (int r = 0; r < 4; ++r) {
      pa0[r] = (__bf16)p[0][r];  pa0[r + 4] = (__bf16)p[1][r];
      pa1[r] = (__bf16)p[2][r];  pa1[r + 4] = (__bf16)p[3][r];
    }
    #pragma unroll
    for (int s = 0; s < 2; ++s) {
      bfx8 pa = s ? pa1 : pa0;
      #pragma unroll
      for (int df = 0; df < 2; ++df)
        oacc[df] = __builtin_amdgcn_mfma_f32_16x16x32_bf16(pa, vfr[s * 2 + df],
                                                           oacc[df], 0, 0, 0);
    }
  }
  {
    float l = l_run;
    l += __shfl_xor(l, 16);
    l += __shfl_xor(l, 32);
    float il[4];
    #pragma unroll
    for (int r = 0; r < 4; ++r) il[r] = 1.f / __shfl(l, kb + r);
    #pragma unroll
    for (int r = 0; r < 4; ++r) {
      size_t rowoff = (size_t)b * NTOK * CDIM +
                      (size_t)(q0 + 16 * w + kb + r) * CDIM + h * DHEAD;
      outb[rowoff + lr]      = (__bf16)(oacc[0][r] * il[r]);
      outb[rowoff + 16 + lr] = (__bf16)(oacc[1][r] * il[r]);
    }
  }
}

// ---------------------------------------------------------------------------
extern "C" void kernel_launch(void* const* d_in, const int* in_sizes, int n_in,
                              void* d_out, int out_size, void* d_ws, size_t ws_size,
                              hipStream_t stream) {
  const float* x     = (const float*)d_in[0];
  const float* ln1_g = (const float*)d_in[2];
  const float* ln1_b = (const float*)d_in[3];
  const float* Wqkv  = (const float*)d_in[4];
  const float* table = (const float*)d_in[5];
  const float* Wo    = (const float*)d_in[6];
  const float* bo    = (const float*)d_in[7];
  const float* ln2_g = (const float*)d_in[8];
  const float* ln2_b = (const float*)d_in[9];
  const float* W1    = (const float*)d_in[10];
  const float* b1    = (const float*)d_in[11];
  const float* W2    = (const float*)d_in[12];
  const float* b2    = (const float*)d_in[13];

  char* ws = (char*)d_ws;
  __bf16* t_bf  = (__bf16*)(ws + 0);          // 8 MB residual 1 (bf16)
  __bf16* t2_bf = (__bf16*)(ws + 8388608);    // 8 MB residual 2 (bf16)
  __bf16* qkv   = (__bf16*)(ws + 33554432);   // 24 MB
  __bf16* hln   = (__bf16*)(ws + 58720256);   // 8 MB (ln1 out, reused for ln2)
  __bf16* aout  = (__bf16*)(ws + 67108864);   // 8 MB
  __bf16* hid   = (__bf16*)(ws + 75497472);   // 16 MB (aliased: vT during attention)
  __bf16* vT    = (__bf16*)(ws + 75497472);   // 8.4 MB, dead before hid is written
  __bf16* biasB = (__bf16*)(ws + 92274688);   // 16 MB
  __bf16* Wqkvt = (__bf16*)(ws + 109051904);
  __bf16* Wot   = (__bf16*)(ws + 109445120);
  __bf16* W1t   = (__bf16*)(ws + 109576192);
  __bf16* W2t   = (__bf16*)(ws + 109838336);  // ends 110100480
  if (ws_size < 110100480) return;            // visible failure instead of OOB

  prep_kernel<<<6144, 256, 0, stream>>>(Wqkv, Wo, W1, W2, Wqkvt, Wot, W1t, W2t,
                                        table, biasB);
  txln_kernel<<<dim3(16, 1, 16), 256, 0, stream>>>(x, ln1_g, ln1_b, t_bf, hln);
  gemm128_kernel<0><<<dim3(128, 6), 256, 0, stream>>>(hln, Wqkvt, nullptr, nullptr, qkv, vT, 768, 256);
  attn_kernel<<<dim3(8, 8, 16), 512, 0, stream>>>(qkv, vT, biasB, aout);
  gemmWoLn_kernel<<<256, 512, 0, stream>>>(aout, Wot, bo, t_bf, ln2_g, ln2_b, t2_bf, hln);
  gemm128_kernel<2><<<dim3(128, 4), 256, 0, stream>>>(hln, W1t, b1, nullptr, hid, nullptr, 512, 256);
  gemm128_kernel<4><<<dim3(128, 2), 256, 0, stream>>>(hid, W2t, b2, t2_bf, d_out, nullptr, 256, 512);
}

// Round 21
// 131.007 us; speedup vs baseline: 1.0699x; 1.0699x over previous
//
#include <hip/hip_runtime.h>
#include <hip/hip_bf16.h>
#include <math.h>

typedef __bf16 bfx4 __attribute__((ext_vector_type(4)));
typedef __bf16 bfx8 __attribute__((ext_vector_type(8)));
typedef float  f32x4 __attribute__((ext_vector_type(4)));

#define BATCH 16
#define NTOK  1024
#define CDIM  256
#define NHEAD 8
#define DHEAD 32
#define QKVD  768
#define INNER 256
#define SCALE 0.17677669529663687f
#define LOG2E 1.4426950408889634f

#if __has_builtin(__builtin_amdgcn_exp2f)
#define EXP2(x) __builtin_amdgcn_exp2f(x)
#else
#define EXP2(x) exp2f(x)
#endif

// ------- fused transpose + LN1: x[B][C][N] -> t_bf bf16 [tok][C], hln bf16 --
__launch_bounds__(256)
__global__ void txln_kernel(const float* __restrict__ x, const float* __restrict__ g,
                            const float* __restrict__ bb, __bf16* __restrict__ tb,
                            __bf16* __restrict__ hln) {
  __shared__ float tile[256][65];
  const int b = blockIdx.z, n0 = blockIdx.x * 64;
  const int tt = threadIdx.x;
  const float* src = x + (size_t)b * CDIM * NTOK;
  const int rc = tt >> 4, nc = (tt & 15) * 4;
  #pragma unroll
  for (int i = 0; i < 16; ++i) {
    int c = rc + i * 16;
    *(float4*)&tile[c][nc] = *(const float4*)&src[(size_t)c * NTOK + n0 + nc];
  }
  __syncthreads();
  const int n = tt >> 2, c0 = (tt & 3) * 64;
  float vals[64];
  float s = 0.f, s2 = 0.f;
  #pragma unroll
  for (int j = 0; j < 64; ++j) {
    float v = tile[c0 + j][n];
    vals[j] = v; s += v; s2 += v * v;
  }
  s  += __shfl_xor(s, 1);  s  += __shfl_xor(s, 2);
  s2 += __shfl_xor(s2, 1); s2 += __shfl_xor(s2, 2);
  float mu = s * 0.00390625f;
  float var = s2 * 0.00390625f - mu * mu;
  float rs = rsqrtf(var + 1e-5f);
  size_t row = ((size_t)b * NTOK + n0 + n) * CDIM;
  #pragma unroll
  for (int j = 0; j < 64; j += 4) {
    const float4 gg = *(const float4*)&g[c0 + j];
    const float4 bv = *(const float4*)&bb[c0 + j];
    bfx4 tv;
    tv[0] = (__bf16)vals[j];     tv[1] = (__bf16)vals[j + 1];
    tv[2] = (__bf16)vals[j + 2]; tv[3] = (__bf16)vals[j + 3];
    *(bfx4*)&tb[row + c0 + j] = tv;
    bfx4 o;
    o[0] = (__bf16)((vals[j]     - mu) * rs * gg.x + bv.x);
    o[1] = (__bf16)((vals[j + 1] - mu) * rs * gg.y + bv.y);
    o[2] = (__bf16)((vals[j + 2] - mu) * rs * gg.z + bv.z);
    o[3] = (__bf16)((vals[j + 3] - mu) * rs * gg.w + bv.w);
    *(bfx4*)&hln[row + c0 + j] = o;
  }
}

// ---- merged prep: weight transpose+cast (blocks 0..2047) + bias (2048..6143)
__launch_bounds__(256)
__global__ void prep_kernel(const float* __restrict__ Wqkv, const float* __restrict__ Wo,
                            const float* __restrict__ W1, const float* __restrict__ W2,
                            __bf16* __restrict__ Wqkvt, __bf16* __restrict__ Wot,
                            __bf16* __restrict__ W1t, __bf16* __restrict__ W2t,
                            const float* __restrict__ table, __bf16* __restrict__ biasB) {
  if (blockIdx.x < 2048) {
    int idx = blockIdx.x * 256 + threadIdx.x;
    const float* W; __bf16* Wt; int lk, Nn, off;
    if (idx < 196608)      { W = Wqkv; Wt = Wqkvt; lk = 8; Nn = 768; off = idx; }
    else if (idx < 262144) { W = Wo;   Wt = Wot;   lk = 8; Nn = 256; off = idx - 196608; }
    else if (idx < 393216) { W = W1;   Wt = W1t;   lk = 8; Nn = 512; off = idx - 262144; }
    else                   { W = W2;   Wt = W2t;   lk = 9; Nn = 256; off = idx - 393216; }
    int n = off >> lk, k = off & ((1 << lk) - 1);
    Wt[off] = (__bf16)W[(size_t)k * Nn + n];
  } else {
    int idx = (blockIdx.x - 2048) * 256 + threadIdx.x;   // h*2^17 + q*2^7 + k8
    int k8 = (idx & 127) * 8, q = (idx >> 7) & 1023, h = idx >> 17;
    int qi = q >> 5, qj = q & 31;
    bfx8 o;
    #pragma unroll
    for (int j = 0; j < 8; ++j) {
      int k = k8 + j, ki = k >> 5, kj = k & 31;
      int r = (qi - ki + 31) * 63 + (qj - kj + 31);
      o[j] = (__bf16)(table[r * 8 + h] * LOG2E);
    }
    *(bfx8*)&biasB[((size_t)idx) * 8] = o;
  }
}

// ---------------- GEMM 128x128 tile, BK=64, k-permuted LDS (R13) ------------
// EPI 0: store bf16 (qkv: if vTout && n0>=512, scatter V into vT instead).
// EPI 2: +bias, GELU -> bf16.
// EPI 4: +bias[n] + residb(bf16) -> fp32 TRANSPOSED to out[b][c][tok] via LDS.
template <int EPI>
__launch_bounds__(256)
__global__ void gemm128_kernel(const __bf16* __restrict__ A, const __bf16* __restrict__ Bt,
                               const float* __restrict__ bias,
                               const __bf16* __restrict__ residb,
                               void* __restrict__ outp, __bf16* __restrict__ vTout,
                               int Nn, int K) {
  __shared__ char smem[36864];
  __bf16 (*As)[72] = (__bf16(*)[72])smem;
  __bf16 (*Bs)[72] = (__bf16(*)[72])(smem + 18432);
  const int t = threadIdx.x, lane = t & 63, w = t >> 6;
  const int m0 = blockIdx.x * 128, n0 = blockIdx.y * 128;
  const int wr = w >> 1, wc = w & 1;
  const int lr = lane & 15, kb = (lane >> 4) * 4;
  int srow[4], sp0[4], sp1[4];
  #pragma unroll
  for (int i = 0; i < 4; ++i) {
    int cid = i * 256 + t, kb8 = (cid & 7) * 8;
    srow[i] = cid >> 3;
    int b0 = kb8, b1 = kb8 + 4;
    sp0[i] = (b0 & 32) + ((b0 & 12) << 1) + (((b0 >> 4) & 1) << 2) + (b0 & 3);
    sp1[i] = (b1 & 32) + ((b1 & 12) << 1) + (((b1 >> 4) & 1) << 2) + (b1 & 3);
  }
  f32x4 acc[4][4] = {};
  bfx8 ra[4], rb[4];
  auto gload = [&](int k0) {
    #pragma unroll
    for (int i = 0; i < 4; ++i) {
      int kc8 = ((i * 256 + t) & 7) * 8;
      ra[i] = *(const bfx8*)&A[(size_t)(m0 + srow[i]) * K + k0 + kc8];
      rb[i] = *(const bfx8*)&Bt[(size_t)(n0 + srow[i]) * K + k0 + kc8];
    }
  };
  gload(0);
  for (int k0 = 0; k0 < K; k0 += 64) {
    __syncthreads();
    #pragma unroll
    for (int i = 0; i < 4; ++i) {
      *(bfx4*)&As[srow[i]][sp0[i]] = __builtin_shufflevector(ra[i], ra[i], 0, 1, 2, 3);
      *(bfx4*)&As[srow[i]][sp1[i]] = __builtin_shufflevector(ra[i], ra[i], 4, 5, 6, 7);
      *(bfx4*)&Bs[srow[i]][sp0[i]] = __builtin_shufflevector(rb[i], rb[i], 0, 1, 2, 3);
      *(bfx4*)&Bs[srow[i]][sp1[i]] = __builtin_shufflevector(rb[i], rb[i], 4, 5, 6, 7);
    }
    __syncthreads();
    if (k0 + 64 < K) gload(k0 + 64);
    #pragma unroll
    for (int ks = 0; ks < 2; ++ks) {
      bfx8 af[4], bf[4];
      #pragma unroll
      for (int mi = 0; mi < 4; ++mi)
        af[mi] = *(const bfx8*)&As[wr * 64 + mi * 16 + lr][ks * 32 + kb * 2];
      #pragma unroll
      for (int ni = 0; ni < 4; ++ni)
        bf[ni] = *(const bfx8*)&Bs[wc * 64 + ni * 16 + lr][ks * 32 + kb * 2];
      #pragma unroll
      for (int mi = 0; mi < 4; ++mi)
        #pragma unroll
        for (int ni = 0; ni < 4; ++ni)
          acc[mi][ni] = __builtin_amdgcn_mfma_f32_16x16x32_bf16(af[mi], bf[ni],
                                                                acc[mi][ni], 0, 0, 0);
    }
  }
  if (EPI == 4) {
    float* Ty = (float*)smem;
    const int bb_ = m0 >> 10, tok0 = m0 & 1023;
    float* obase = (float*)outp + (size_t)bb_ * CDIM * NTOK + tok0;
    #pragma unroll
    for (int h2 = 0; h2 < 2; ++h2) {
      __syncthreads();
      if (wc == h2) {
        #pragma unroll
        for (int ni = 0; ni < 4; ++ni) {
          int ch = ni * 16 + lr;
          float bn = bias[n0 + h2 * 64 + ch];
          #pragma unroll
          for (int mi = 0; mi < 4; ++mi) {
            int tk = wr * 64 + mi * 16 + kb;
            float4 v4;
            #pragma unroll
            for (int r = 0; r < 4; ++r)
              ((float*)&v4)[r] = acc[mi][ni][r] + bn +
                  (float)residb[(size_t)(m0 + tk + r) * Nn + n0 + h2 * 64 + ch];
            *(float4*)&Ty[ch * 132 + tk] = v4;
          }
        }
      }
      __syncthreads();
      int ch = t >> 2, sc = t & 3;
      #pragma unroll
      for (int j = 0; j < 8; ++j) {
        int c4 = sc + j * 4;
        *(float4*)&obase[(size_t)(n0 + h2 * 64 + ch) * NTOK + c4 * 4] =
            *(const float4*)&Ty[ch * 132 + c4 * 4];
      }
    }
    return;
  }
  if (EPI == 0 && vTout != nullptr && n0 >= 512) {
    #pragma unroll
    for (int mi = 0; mi < 4; ++mi)
      #pragma unroll
      for (int ni = 0; ni < 4; ++ni) {
        int n = n0 + wc * 64 + ni * 16 + lr;
        int cp = n - 512, hh = cp >> 5, dd = cp & 31;
        int m = m0 + wr * 64 + mi * 16 + kb;
        int bb_ = m >> 10, tok = m & 1023;
        bfx4 o;
        o[0] = (__bf16)acc[mi][ni][0]; o[1] = (__bf16)acc[mi][ni][1];
        o[2] = (__bf16)acc[mi][ni][2]; o[3] = (__bf16)acc[mi][ni][3];
        *(bfx4*)&vTout[(((size_t)bb_ * NHEAD + hh) * DHEAD + dd) * NTOK + tok] = o;
      }
    return;
  }
  #pragma unroll
  for (int mi = 0; mi < 4; ++mi)
    #pragma unroll
    for (int ni = 0; ni < 4; ++ni)
      #pragma unroll
      for (int r = 0; r < 4; ++r) {
        int m = m0 + wr * 64 + mi * 16 + kb + r;
        int n = n0 + wc * 64 + ni * 16 + lr;
        float v = acc[mi][ni][r];
        if (EPI == 0) {
          ((__bf16*)outp)[(size_t)m * Nn + n] = (__bf16)v;
        } else if (EPI == 2) {
          v += bias[n];
          v = 0.5f * v * (1.0f + erff(v * 0.70710678118f));
          ((__bf16*)outp)[(size_t)m * Nn + n] = (__bf16)v;
        }
      }
}

// ---- Wo GEMM (BM=64, BN=256 full width) + bias + resid + fused LN2 ---------
__launch_bounds__(512)
__global__ void gemmWoLn_kernel(const __bf16* __restrict__ A, const __bf16* __restrict__ Bt,
                                const float* __restrict__ bias,
                                const __bf16* __restrict__ residb,
                                const float* __restrict__ g2, const float* __restrict__ b2v,
                                __bf16* __restrict__ t2, __bf16* __restrict__ hln) {
  __shared__ char smem[46080];
  __bf16 (*As)[72] = (__bf16(*)[72])smem;             // 64 x 72
  __bf16 (*Bs)[72] = (__bf16(*)[72])(smem + 9216);    // 256 x 72
  const int t = threadIdx.x, lane = t & 63, w = t >> 6;
  const int m0 = blockIdx.x * 64;
  const int wr = w >> 2, wc = w & 3;
  const int lr = lane & 15, kb = (lane >> 4) * 4;
  const int K = 256;
  const int arow = t >> 3, ac8 = (t & 7) * 8;
  int ap0, ap1;
  {
    int b0 = ac8, b1 = ac8 + 4;
    ap0 = (b0 & 32) + ((b0 & 12) << 1) + (((b0 >> 4) & 1) << 2) + (b0 & 3);
    ap1 = (b1 & 32) + ((b1 & 12) << 1) + (((b1 >> 4) & 1) << 2) + (b1 & 3);
  }
  int brow[4], bp0[4], bp1[4], bc8[4];
  #pragma unroll
  for (int j = 0; j < 4; ++j) {
    int cid = j * 512 + t;
    brow[j] = cid >> 3;
    bc8[j] = (cid & 7) * 8;
    int b0 = bc8[j], b1 = bc8[j] + 4;
    bp0[j] = (b0 & 32) + ((b0 & 12) << 1) + (((b0 >> 4) & 1) << 2) + (b0 & 3);
    bp1[j] = (b1 & 32) + ((b1 & 12) << 1) + (((b1 >> 4) & 1) << 2) + (b1 & 3);
  }
  f32x4 acc[2][4] = {};
  bfx8 ra, rb[4];
  auto gload = [&](int k0) {
    ra = *(const bfx8*)&A[(size_t)(m0 + arow) * K + k0 + ac8];
    #pragma unroll
    for (int j = 0; j < 4; ++j)
      rb[j] = *(const bfx8*)&Bt[(size_t)brow[j] * K + k0 + bc8[j]];
  };
  gload(0);
  for (int k0 = 0; k0 < K; k0 += 64) {
    __syncthreads();
    *(bfx4*)&As[arow][ap0] = __builtin_shufflevector(ra, ra, 0, 1, 2, 3);
    *(bfx4*)&As[arow][ap1] = __builtin_shufflevector(ra, ra, 4, 5, 6, 7);
    #pragma unroll
    for (int j = 0; j < 4; ++j) {
      *(bfx4*)&Bs[brow[j]][bp0[j]] = __builtin_shufflevector(rb[j], rb[j], 0, 1, 2, 3);
      *(bfx4*)&Bs[brow[j]][bp1[j]] = __builtin_shufflevector(rb[j], rb[j], 4, 5, 6, 7);
    }
    __syncthreads();
    if (k0 + 64 < K) gload(k0 + 64);
    #pragma unroll
    for (int ks = 0; ks < 2; ++ks) {
      bfx8 af[2], bf[4];
      #pragma unroll
      for (int mi = 0; mi < 2; ++mi)
        af[mi] = *(const bfx8*)&As[wr * 32 + mi * 16 + lr][ks * 32 + kb * 2];
      #pragma unroll
      for (int ni = 0; ni < 4; ++ni)
        bf[ni] = *(const bfx8*)&Bs[wc * 64 + ni * 16 + lr][ks * 32 + kb * 2];
      #pragma unroll
      for (int mi = 0; mi < 2; ++mi)
        #pragma unroll
        for (int ni = 0; ni < 4; ++ni)
          acc[mi][ni] = __builtin_amdgcn_mfma_f32_16x16x32_bf16(af[mi], bf[ni],
                                                                acc[mi][ni], 0, 0, 0);
    }
  }
  float colg[4], colb[4];
  #pragma unroll
  for (int ni = 0; ni < 4; ++ni) {
    int colq = wc * 64 + ni * 16 + lr;
    float bn = bias[colq];
    colg[ni] = g2[colq];
    colb[ni] = b2v[colq];
    #pragma unroll
    for (int mi = 0; mi < 2; ++mi)
      #pragma unroll
      for (int r = 0; r < 4; ++r) {
        int m = m0 + wr * 32 + mi * 16 + kb + r;
        acc[mi][ni][r] += bn + (float)residb[(size_t)m * CDIM + colq];
      }
  }
  float ps[2][4], pq[2][4];
  #pragma unroll
  for (int mi = 0; mi < 2; ++mi)
    #pragma unroll
    for (int r = 0; r < 4; ++r) {
      float s = 0.f, q = 0.f;
      #pragma unroll
      for (int ni = 0; ni < 4; ++ni) {
        float v = acc[mi][ni][r];
        s += v; q += v * v;
      }
      #pragma unroll
      for (int o = 1; o < 16; o <<= 1) { s += __shfl_xor(s, o); q += __shfl_xor(q, o); }
      ps[mi][r] = s; pq[mi][r] = q;
    }
  __syncthreads();
  float* red = (float*)smem;              // [64][8]: sum[wc], sq[4+wc]
  if (lr == 0) {
    #pragma unroll
    for (int mi = 0; mi < 2; ++mi)
      #pragma unroll
      for (int r = 0; r < 4; ++r) {
        int rl = wr * 32 + mi * 16 + kb + r;
        red[rl * 8 + wc] = ps[mi][r];
        red[rl * 8 + 4 + wc] = pq[mi][r];
      }
  }
  __syncthreads();
  if (t < 64) {
    float s = red[t * 8] + red[t * 8 + 1] + red[t * 8 + 2] + red[t * 8 + 3];
    float q = red[t * 8 + 4] + red[t * 8 + 5] + red[t * 8 + 6] + red[t * 8 + 7];
    float mu = s * 0.00390625f;
    float var = q * 0.00390625f - mu * mu;
    red[t * 8] = mu;
    red[t * 8 + 1] = rsqrtf(var + 1e-5f);
  }
  __syncthreads();
  #pragma unroll
  for (int mi = 0; mi < 2; ++mi)
    #pragma unroll
    for (int r = 0; r < 4; ++r) {
      int rl = wr * 32 + mi * 16 + kb + r;
      float mu = red[rl * 8], rs = red[rl * 8 + 1];
      size_t rowoff = (size_t)(m0 + rl) * CDIM;
      #pragma unroll
      for (int ni = 0; ni < 4; ++ni) {
        int colq = wc * 64 + ni * 16 + lr;
        float v = acc[mi][ni][r];
        t2[rowoff + colq] = (__bf16)v;
        hln[rowoff + colq] = (__bf16)((v - mu) * rs * colg[ni] + colb[ni]);
      }
    }
}

// -------- flash attention, QBLK=256, 8 waves (32 q-rows/wave) — R13 exact ---
__launch_bounds__(512)
__global__ void attn_kernel(const __bf16* __restrict__ qkv, const __bf16* __restrict__ vT,
                            const __bf16* __restrict__ biasB, __bf16* __restrict__ outb) {
  __shared__ __bf16 Ks[64][40];
  __shared__ __bf16 Vs[32][72];
  __shared__ __bf16 Bls[256][72];
  const int q0 = blockIdx.x * 256, h = blockIdx.y, b = blockIdx.z;
  const int t = threadIdx.x, lane = t & 63, w = t >> 6;     // 8 waves
  const int lr = lane & 15, kb = (lane >> 4) * 4;
  const size_t qbase = (size_t)b * NTOK * QKVD;
  const float qsc = SCALE * LOG2E;
  bfx8 qf[2];
  #pragma unroll
  for (int tq = 0; tq < 2; ++tq) {
    const __bf16* qp = &qkv[qbase + (size_t)(q0 + 32 * w + 16 * tq + lr) * QKVD + h * DHEAD];
    bfx4 lo = *(const bfx4*)&qp[kb];
    bfx4 hi = *(const bfx4*)&qp[kb + 16];
    #pragma unroll
    for (int j = 0; j < 4; ++j) {
      qf[tq][j]     = (__bf16)((float)lo[j] * qsc);
      qf[tq][j + 4] = (__bf16)((float)hi[j] * qsc);
    }
  }
  float l_run[2] = {0.f, 0.f};
  f32x4 oacc[2][2] = {};
  const int st_ = t & 255;
  const int krow = st_ >> 2, kc8 = (st_ & 3) * 8;   // K stage (t<256): 64x32
  const int vrow = st_ >> 3, vc8 = (st_ & 7) * 8;   // V stage (t>=256): 32x64
  const __bf16* kvptr = (t < 256)
      ? &qkv[qbase + (size_t)krow * QKVD + INNER + h * DHEAD + kc8]
      : &vT[(((size_t)b * NHEAD + h) * DHEAD + vrow) * NTOK + vc8];
  const __bf16* bbase = &biasB[((size_t)h * NTOK + q0) * NTOK];
  bfx8 rkv, rbias[4];
  auto issue = [&](int k0) {
    rkv = (t < 256) ? *(const bfx8*)&kvptr[(size_t)k0 * QKVD]
                    : *(const bfx8*)&kvptr[k0];
    #pragma unroll
    for (int j = 0; j < 4; ++j) {
      int lin = j * 512 + t;                  // 2048 chunks: 256 rows x 128B
      int br = lin >> 3, bc8 = (lin & 7) * 8;
      rbias[j] = *(const bfx8*)&bbase[(size_t)br * NTOK + k0 + bc8];
    }
  };
  issue(0);
  for (int kt = 0; kt < 16; ++kt) {
    __syncthreads();
    if (t < 256) *(bfx8*)&Ks[krow][kc8] = rkv;
    else         *(bfx8*)&Vs[vrow][vc8] = rkv;
    #pragma unroll
    for (int j = 0; j < 4; ++j) {
      int lin = j * 512 + t;
      int br = lin >> 3, bc8 = (lin & 7) * 8;
      *(bfx8*)&Bls[br][bc8] = rbias[j];
    }
    __syncthreads();
    if (kt < 15) issue((kt + 1) * 64);
    bfx8 kf[4], vfr[4];
    #pragma unroll
    for (int f = 0; f < 4; ++f) {
      bfx4 klo = *(const bfx4*)&Ks[16 * f + lr][kb];
      bfx4 khi = *(const bfx4*)&Ks[16 * f + lr][kb + 16];
      kf[f] = __builtin_shufflevector(klo, khi, 0, 1, 2, 3, 4, 5, 6, 7);
    }
    #pragma unroll
    for (int s = 0; s < 2; ++s)
      #pragma unroll
      for (int df = 0; df < 2; ++df) {
        bfx4 vlo = *(const bfx4*)&Vs[16 * df + lr][s * 32 + kb];
        bfx4 vhi = *(const bfx4*)&Vs[16 * df + lr][s * 32 + kb + 16];
        vfr[s * 2 + df] = __builtin_shufflevector(vlo, vhi, 0, 1, 2, 3, 4, 5, 6, 7);
      }
    #pragma unroll
    for (int tq = 0; tq < 2; ++tq) {
      const int qrow_l = 32 * w + 16 * tq + lr;
      f32x4 st[4];
      #pragma unroll
      for (int f = 0; f < 4; ++f) {
        bfx4 bv = *(const bfx4*)&Bls[qrow_l][16 * f + kb];
        f32x4 c;
        c[0] = (float)bv[0]; c[1] = (float)bv[1];
        c[2] = (float)bv[2]; c[3] = (float)bv[3];
        st[f] = __builtin_amdgcn_mfma_f32_16x16x32_bf16(kf[f], qf[tq], c, 0, 0, 0);
      }
      float p[4][4], tsum = 0.f;
      #pragma unroll
      for (int f = 0; f < 4; ++f)
        #pragma unroll
        for (int r = 0; r < 4; ++r) {
          float e = EXP2(st[f][r]);
          p[f][r] = e;
          tsum += e;
        }
      l_run[tq] += tsum;
      bfx8 pa0, pa1;
      #pragma unroll
      for (int r = 0; r < 4; ++r) {
        pa0[r] = (__bf16)p[0][r];  pa0[r + 4] = (__bf16)p[1][r];
        pa1[r] = (__bf16)p[2][r];  pa1[r + 4] = (__bf16)p[3][r];
      }
      #pragma unroll
      for (int s = 0; s < 2; ++s) {
        bfx8 pa = s ? pa1 : pa0;
        #pragma unroll
        for (int df = 0; df < 2; ++df)
          oacc[tq][df] = __builtin_amdgcn_mfma_f32_16x16x32_bf16(pa, vfr[s * 2 + df],
                                                                 oacc[tq][df], 0, 0, 0);
      }
    }
  }
  #pragma unroll
  for (int tq = 0; tq < 2; ++tq) {
    float l = l_run[tq];
    l += __shfl_xor(l, 16);
    l += __shfl_xor(l, 32);
    float il[4];
    #pragma unroll
    for (int r = 0; r < 4; ++r) il[r] = 1.f / __shfl(l, kb + r);
    #pragma unroll
    for (int r = 0; r < 4; ++r) {
      size_t rowoff = (size_t)b * NTOK * CDIM +
                      (size_t)(q0 + 32 * w + 16 * tq + kb + r) * CDIM + h * DHEAD;
      outb[rowoff + lr]      = (__bf16)(oacc[tq][0][r] * il[r]);
      outb[rowoff + 16 + lr] = (__bf16)(oacc[tq][1][r] * il[r]);
    }
  }
}

// ---------------------------------------------------------------------------
extern "C" void kernel_launch(void* const* d_in, const int* in_sizes, int n_in,
                              void* d_out, int out_size, void* d_ws, size_t ws_size,
                              hipStream_t stream) {
  const float* x     = (const float*)d_in[0];
  const float* ln1_g = (const float*)d_in[2];
  const float* ln1_b = (const float*)d_in[3];
  const float* Wqkv  = (const float*)d_in[4];
  const float* table = (const float*)d_in[5];
  const float* Wo    = (const float*)d_in[6];
  const float* bo    = (const float*)d_in[7];
  const float* ln2_g = (const float*)d_in[8];
  const float* ln2_b = (const float*)d_in[9];
  const float* W1    = (const float*)d_in[10];
  const float* b1    = (const float*)d_in[11];
  const float* W2    = (const float*)d_in[12];
  const float* b2    = (const float*)d_in[13];

  char* ws = (char*)d_ws;
  __bf16* t_bf  = (__bf16*)(ws + 0);          // 8 MB residual 1 (bf16)
  __bf16* t2_bf = (__bf16*)(ws + 8388608);    // 8 MB residual 2 (bf16)
  __bf16* qkv   = (__bf16*)(ws + 33554432);   // 24 MB
  __bf16* hln   = (__bf16*)(ws + 58720256);   // 8 MB (ln1 out, reused for ln2)
  __bf16* aout  = (__bf16*)(ws + 67108864);   // 8 MB
  __bf16* hid   = (__bf16*)(ws + 75497472);   // 16 MB (aliased: vT during attention)
  __bf16* vT    = (__bf16*)(ws + 75497472);   // 8.4 MB, dead before hid is written
  __bf16* biasB = (__bf16*)(ws + 92274688);   // 16 MB
  __bf16* Wqkvt = (__bf16*)(ws + 109051904);
  __bf16* Wot   = (__bf16*)(ws + 109445120);
  __bf16* W1t   = (__bf16*)(ws + 109576192);
  __bf16* W2t   = (__bf16*)(ws + 109838336);  // ends 110100480
  if (ws_size < 110100480) return;            // visible failure instead of OOB

  prep_kernel<<<6144, 256, 0, stream>>>(Wqkv, Wo, W1, W2, Wqkvt, Wot, W1t, W2t,
                                        table, biasB);
  txln_kernel<<<dim3(16, 1, 16), 256, 0, stream>>>(x, ln1_g, ln1_b, t_bf, hln);
  gemm128_kernel<0><<<dim3(128, 6), 256, 0, stream>>>(hln, Wqkvt, nullptr, nullptr, qkv, vT, 768, 256);
  attn_kernel<<<dim3(4, 8, 16), 512, 0, stream>>>(qkv, vT, biasB, aout);
  gemmWoLn_kernel<<<256, 512, 0, stream>>>(aout, Wot, bo, t_bf, ln2_g, ln2_b, t2_bf, hln);
  gemm128_kernel<2><<<dim3(128, 4), 256, 0, stream>>>(hln, W1t, b1, nullptr, hid, nullptr, 512, 256);
  gemm128_kernel<4><<<dim3(128, 2), 256, 0, stream>>>(hid, W2t, b2, t2_bf, d_out, nullptr, 256, 512);
}

// Round 24
// 128.872 us; speedup vs baseline: 1.0877x; 1.0166x over previous
//
#include <hip/hip_runtime.h>
#include <hip/hip_bf16.h>
#include <math.h>

typedef __bf16 bfx4 __attribute__((ext_vector_type(4)));
typedef __bf16 bfx8 __attribute__((ext_vector_type(8)));
typedef float  f32x4 __attribute__((ext_vector_type(4)));

#define BATCH 16
#define NTOK  1024
#define CDIM  256
#define NHEAD 8
#define DHEAD 32
#define QKVD  768
#define INNER 256
#define SCALE 0.17677669529663687f
#define LOG2E 1.4426950408889634f

#if __has_builtin(__builtin_amdgcn_exp2f)
#define EXP2(x) __builtin_amdgcn_exp2f(x)
#else
#define EXP2(x) exp2f(x)
#endif

// ------- fused transpose + LN1: x[B][C][N] -> t_bf bf16 [tok][C], hln bf16 --
// 32-token tiles, 33.8 KB LDS -> 2 blocks/CU (8 waves/CU vs old 4).
__launch_bounds__(256)
__global__ void txln_kernel(const float* __restrict__ x, const float* __restrict__ g,
                            const float* __restrict__ bb, __bf16* __restrict__ tb,
                            __bf16* __restrict__ hln) {
  __shared__ float tile[256][33];
  const int b = blockIdx.z, n0 = blockIdx.x * 32;
  const int tt = threadIdx.x;
  const float* src = x + (size_t)b * CDIM * NTOK;
  #pragma unroll
  for (int i = 0; i < 8; ++i) {
    int cid = i * 256 + tt;
    int c = cid >> 3, col4 = (cid & 7) * 4;
    *(float4*)&tile[c][col4] = *(const float4*)&src[(size_t)c * NTOK + n0 + col4];
  }
  __syncthreads();
  const int n = tt >> 3, c0 = (tt & 7) * 32;   // 8 threads per token
  float vals[32];
  float s = 0.f, s2 = 0.f;
  #pragma unroll
  for (int j = 0; j < 32; ++j) {
    float v = tile[c0 + j][n];
    vals[j] = v; s += v; s2 += v * v;
  }
  s  += __shfl_xor(s, 1);  s  += __shfl_xor(s, 2);  s  += __shfl_xor(s, 4);
  s2 += __shfl_xor(s2, 1); s2 += __shfl_xor(s2, 2); s2 += __shfl_xor(s2, 4);
  float mu = s * 0.00390625f;
  float var = s2 * 0.00390625f - mu * mu;
  float rs = rsqrtf(var + 1e-5f);
  size_t row = ((size_t)b * NTOK + n0 + n) * CDIM;
  #pragma unroll
  for (int j = 0; j < 32; j += 4) {
    const float4 gg = *(const float4*)&g[c0 + j];
    const float4 bv = *(const float4*)&bb[c0 + j];
    bfx4 tv;
    tv[0] = (__bf16)vals[j];     tv[1] = (__bf16)vals[j + 1];
    tv[2] = (__bf16)vals[j + 2]; tv[3] = (__bf16)vals[j + 3];
    *(bfx4*)&tb[row + c0 + j] = tv;
    bfx4 o;
    o[0] = (__bf16)((vals[j]     - mu) * rs * gg.x + bv.x);
    o[1] = (__bf16)((vals[j + 1] - mu) * rs * gg.y + bv.y);
    o[2] = (__bf16)((vals[j + 2] - mu) * rs * gg.z + bv.z);
    o[3] = (__bf16)((vals[j + 3] - mu) * rs * gg.w + bv.w);
    *(bfx4*)&hln[row + c0 + j] = o;
  }
}

// ---- merged prep: weight transpose+cast (blocks 0..2047) + bias (2048..6143)
__launch_bounds__(256)
__global__ void prep_kernel(const float* __restrict__ Wqkv, const float* __restrict__ Wo,
                            const float* __restrict__ W1, const float* __restrict__ W2,
                            __bf16* __restrict__ Wqkvt, __bf16* __restrict__ Wot,
                            __bf16* __restrict__ W1t, __bf16* __restrict__ W2t,
                            const float* __restrict__ table, __bf16* __restrict__ biasB) {
  if (blockIdx.x < 2048) {
    int idx = blockIdx.x * 256 + threadIdx.x;
    const float* W; __bf16* Wt; int lk, Nn, off;
    if (idx < 196608)      { W = Wqkv; Wt = Wqkvt; lk = 8; Nn = 768; off = idx; }
    else if (idx < 262144) { W = Wo;   Wt = Wot;   lk = 8; Nn = 256; off = idx - 196608; }
    else if (idx < 393216) { W = W1;   Wt = W1t;   lk = 8; Nn = 512; off = idx - 262144; }
    else                   { W = W2;   Wt = W2t;   lk = 9; Nn = 256; off = idx - 393216; }
    int n = off >> lk, k = off & ((1 << lk) - 1);
    Wt[off] = (__bf16)W[(size_t)k * Nn + n];
  } else {
    int idx = (blockIdx.x - 2048) * 256 + threadIdx.x;   // h*2^17 + q*2^7 + k8
    int k8 = (idx & 127) * 8, q = (idx >> 7) & 1023, h = idx >> 17;
    int qi = q >> 5, qj = q & 31;
    bfx8 o;
    #pragma unroll
    for (int j = 0; j < 8; ++j) {
      int k = k8 + j, ki = k >> 5, kj = k & 31;
      int r = (qi - ki + 31) * 63 + (qj - kj + 31);
      o[j] = (__bf16)(table[r * 8 + h] * LOG2E);
    }
    *(bfx8*)&biasB[((size_t)idx) * 8] = o;
  }
}

// ---------------- GEMM 128x128 tile, BK=64, k-permuted LDS (R13) ------------
// EPI 0: store bf16 (qkv: if vTout && n0>=512, scatter V into vT instead).
// EPI 2: +bias, GELU -> bf16.
// EPI 4: +bias[n] + residb(bf16) -> fp32 TRANSPOSED to out[b][c][tok] via LDS.
template <int EPI>
__launch_bounds__(256)
__global__ void gemm128_kernel(const __bf16* __restrict__ A, const __bf16* __restrict__ Bt,
                               const float* __restrict__ bias,
                               const __bf16* __restrict__ residb,
                               void* __restrict__ outp, __bf16* __restrict__ vTout,
                               int Nn, int K) {
  __shared__ char smem[36864];
  __bf16 (*As)[72] = (__bf16(*)[72])smem;
  __bf16 (*Bs)[72] = (__bf16(*)[72])(smem + 18432);
  const int t = threadIdx.x, lane = t & 63, w = t >> 6;
  const int m0 = blockIdx.x * 128, n0 = blockIdx.y * 128;
  const int wr = w >> 1, wc = w & 1;
  const int lr = lane & 15, kb = (lane >> 4) * 4;
  int srow[4], sp0[4], sp1[4];
  #pragma unroll
  for (int i = 0; i < 4; ++i) {
    int cid = i * 256 + t, kb8 = (cid & 7) * 8;
    srow[i] = cid >> 3;
    int b0 = kb8, b1 = kb8 + 4;
    sp0[i] = (b0 & 32) + ((b0 & 12) << 1) + (((b0 >> 4) & 1) << 2) + (b0 & 3);
    sp1[i] = (b1 & 32) + ((b1 & 12) << 1) + (((b1 >> 4) & 1) << 2) + (b1 & 3);
  }
  f32x4 acc[4][4] = {};
  bfx8 ra[4], rb[4];
  auto gload = [&](int k0) {
    #pragma unroll
    for (int i = 0; i < 4; ++i) {
      int kc8 = ((i * 256 + t) & 7) * 8;
      ra[i] = *(const bfx8*)&A[(size_t)(m0 + srow[i]) * K + k0 + kc8];
      rb[i] = *(const bfx8*)&Bt[(size_t)(n0 + srow[i]) * K + k0 + kc8];
    }
  };
  gload(0);
  for (int k0 = 0; k0 < K; k0 += 64) {
    __syncthreads();
    #pragma unroll
    for (int i = 0; i < 4; ++i) {
      *(bfx4*)&As[srow[i]][sp0[i]] = __builtin_shufflevector(ra[i], ra[i], 0, 1, 2, 3);
      *(bfx4*)&As[srow[i]][sp1[i]] = __builtin_shufflevector(ra[i], ra[i], 4, 5, 6, 7);
      *(bfx4*)&Bs[srow[i]][sp0[i]] = __builtin_shufflevector(rb[i], rb[i], 0, 1, 2, 3);
      *(bfx4*)&Bs[srow[i]][sp1[i]] = __builtin_shufflevector(rb[i], rb[i], 4, 5, 6, 7);
    }
    __syncthreads();
    if (k0 + 64 < K) gload(k0 + 64);
    #pragma unroll
    for (int ks = 0; ks < 2; ++ks) {
      bfx8 af[4], bf[4];
      #pragma unroll
      for (int mi = 0; mi < 4; ++mi)
        af[mi] = *(const bfx8*)&As[wr * 64 + mi * 16 + lr][ks * 32 + kb * 2];
      #pragma unroll
      for (int ni = 0; ni < 4; ++ni)
        bf[ni] = *(const bfx8*)&Bs[wc * 64 + ni * 16 + lr][ks * 32 + kb * 2];
      #pragma unroll
      for (int mi = 0; mi < 4; ++mi)
        #pragma unroll
        for (int ni = 0; ni < 4; ++ni)
          acc[mi][ni] = __builtin_amdgcn_mfma_f32_16x16x32_bf16(af[mi], bf[ni],
                                                                acc[mi][ni], 0, 0, 0);
    }
  }
  if (EPI == 4) {
    float* Ty = (float*)smem;
    const int bb_ = m0 >> 10, tok0 = m0 & 1023;
    float* obase = (float*)outp + (size_t)bb_ * CDIM * NTOK + tok0;
    #pragma unroll
    for (int h2 = 0; h2 < 2; ++h2) {
      __syncthreads();
      if (wc == h2) {
        #pragma unroll
        for (int ni = 0; ni < 4; ++ni) {
          int ch = ni * 16 + lr;
          float bn = bias[n0 + h2 * 64 + ch];
          #pragma unroll
          for (int mi = 0; mi < 4; ++mi) {
            int tk = wr * 64 + mi * 16 + kb;
            float4 v4;
            #pragma unroll
            for (int r = 0; r < 4; ++r)
              ((float*)&v4)[r] = acc[mi][ni][r] + bn +
                  (float)residb[(size_t)(m0 + tk + r) * Nn + n0 + h2 * 64 + ch];
            *(float4*)&Ty[ch * 132 + tk] = v4;
          }
        }
      }
      __syncthreads();
      int ch = t >> 2, sc = t & 3;
      #pragma unroll
      for (int j = 0; j < 8; ++j) {
        int c4 = sc + j * 4;
        *(float4*)&obase[(size_t)(n0 + h2 * 64 + ch) * NTOK + c4 * 4] =
            *(const float4*)&Ty[ch * 132 + c4 * 4];
      }
    }
    return;
  }
  if (EPI == 0 && vTout != nullptr && n0 >= 512) {
    #pragma unroll
    for (int mi = 0; mi < 4; ++mi)
      #pragma unroll
      for (int ni = 0; ni < 4; ++ni) {
        int n = n0 + wc * 64 + ni * 16 + lr;
        int cp = n - 512, hh = cp >> 5, dd = cp & 31;
        int m = m0 + wr * 64 + mi * 16 + kb;
        int bb_ = m >> 10, tok = m & 1023;
        bfx4 o;
        o[0] = (__bf16)acc[mi][ni][0]; o[1] = (__bf16)acc[mi][ni][1];
        o[2] = (__bf16)acc[mi][ni][2]; o[3] = (__bf16)acc[mi][ni][3];
        *(bfx4*)&vTout[(((size_t)bb_ * NHEAD + hh) * DHEAD + dd) * NTOK + tok] = o;
      }
    return;
  }
  #pragma unroll
  for (int mi = 0; mi < 4; ++mi)
    #pragma unroll
    for (int ni = 0; ni < 4; ++ni)
      #pragma unroll
      for (int r = 0; r < 4; ++r) {
        int m = m0 + wr * 64 + mi * 16 + kb + r;
        int n = n0 + wc * 64 + ni * 16 + lr;
        float v = acc[mi][ni][r];
        if (EPI == 0) {
          ((__bf16*)outp)[(size_t)m * Nn + n] = (__bf16)v;
        } else if (EPI == 2) {
          v += bias[n];
          v = 0.5f * v * (1.0f + erff(v * 0.70710678118f));
          ((__bf16*)outp)[(size_t)m * Nn + n] = (__bf16)v;
        }
      }
}

// ---- Wo GEMM (BM=64, BN=256 full width) + bias + resid + fused LN2 ---------
__launch_bounds__(512)
__global__ void gemmWoLn_kernel(const __bf16* __restrict__ A, const __bf16* __restrict__ Bt,
                                const float* __restrict__ bias,
                                const __bf16* __restrict__ residb,
                                const float* __restrict__ g2, const float* __restrict__ b2v,
                                __bf16* __restrict__ t2, __bf16* __restrict__ hln) {
  __shared__ char smem[46080];
  __bf16 (*As)[72] = (__bf16(*)[72])smem;             // 64 x 72
  __bf16 (*Bs)[72] = (__bf16(*)[72])(smem + 9216);    // 256 x 72
  const int t = threadIdx.x, lane = t & 63, w = t >> 6;
  const int m0 = blockIdx.x * 64;
  const int wr = w >> 2, wc = w & 3;
  const int lr = lane & 15, kb = (lane >> 4) * 4;
  const int K = 256;
  const int arow = t >> 3, ac8 = (t & 7) * 8;
  int ap0, ap1;
  {
    int b0 = ac8, b1 = ac8 + 4;
    ap0 = (b0 & 32) + ((b0 & 12) << 1) + (((b0 >> 4) & 1) << 2) + (b0 & 3);
    ap1 = (b1 & 32) + ((b1 & 12) << 1) + (((b1 >> 4) & 1) << 2) + (b1 & 3);
  }
  int brow[4], bp0[4], bp1[4], bc8[4];
  #pragma unroll
  for (int j = 0; j < 4; ++j) {
    int cid = j * 512 + t;
    brow[j] = cid >> 3;
    bc8[j] = (cid & 7) * 8;
    int b0 = bc8[j], b1 = bc8[j] + 4;
    bp0[j] = (b0 & 32) + ((b0 & 12) << 1) + (((b0 >> 4) & 1) << 2) + (b0 & 3);
    bp1[j] = (b1 & 32) + ((b1 & 12) << 1) + (((b1 >> 4) & 1) << 2) + (b1 & 3);
  }
  f32x4 acc[2][4] = {};
  bfx8 ra, rb[4];
  auto gload = [&](int k0) {
    ra = *(const bfx8*)&A[(size_t)(m0 + arow) * K + k0 + ac8];
    #pragma unroll
    for (int j = 0; j < 4; ++j)
      rb[j] = *(const bfx8*)&Bt[(size_t)brow[j] * K + k0 + bc8[j]];
  };
  gload(0);
  for (int k0 = 0; k0 < K; k0 += 64) {
    __syncthreads();
    *(bfx4*)&As[arow][ap0] = __builtin_shufflevector(ra, ra, 0, 1, 2, 3);
    *(bfx4*)&As[arow][ap1] = __builtin_shufflevector(ra, ra, 4, 5, 6, 7);
    #pragma unroll
    for (int j = 0; j < 4; ++j) {
      *(bfx4*)&Bs[brow[j]][bp0[j]] = __builtin_shufflevector(rb[j], rb[j], 0, 1, 2, 3);
      *(bfx4*)&Bs[brow[j]][bp1[j]] = __builtin_shufflevector(rb[j], rb[j], 4, 5, 6, 7);
    }
    __syncthreads();
    if (k0 + 64 < K) gload(k0 + 64);
    #pragma unroll
    for (int ks = 0; ks < 2; ++ks) {
      bfx8 af[2], bf[4];
      #pragma unroll
      for (int mi = 0; mi < 2; ++mi)
        af[mi] = *(const bfx8*)&As[wr * 32 + mi * 16 + lr][ks * 32 + kb * 2];
      #pragma unroll
      for (int ni = 0; ni < 4; ++ni)
        bf[ni] = *(const bfx8*)&Bs[wc * 64 + ni * 16 + lr][ks * 32 + kb * 2];
      #pragma unroll
      for (int mi = 0; mi < 2; ++mi)
        #pragma unroll
        for (int ni = 0; ni < 4; ++ni)
          acc[mi][ni] = __builtin_amdgcn_mfma_f32_16x16x32_bf16(af[mi], bf[ni],
                                                                acc[mi][ni], 0, 0, 0);
    }
  }
  float colg[4], colb[4];
  #pragma unroll
  for (int ni = 0; ni < 4; ++ni) {
    int colq = wc * 64 + ni * 16 + lr;
    float bn = bias[colq];
    colg[ni] = g2[colq];
    colb[ni] = b2v[colq];
    #pragma unroll
    for (int mi = 0; mi < 2; ++mi)
      #pragma unroll
      for (int r = 0; r < 4; ++r) {
        int m = m0 + wr * 32 + mi * 16 + kb + r;
        acc[mi][ni][r] += bn + (float)residb[(size_t)m * CDIM + colq];
      }
  }
  float ps[2][4], pq[2][4];
  #pragma unroll
  for (int mi = 0; mi < 2; ++mi)
    #pragma unroll
    for (int r = 0; r < 4; ++r) {
      float s = 0.f, q = 0.f;
      #pragma unroll
      for (int ni = 0; ni < 4; ++ni) {
        float v = acc[mi][ni][r];
        s += v; q += v * v;
      }
      #pragma unroll
      for (int o = 1; o < 16; o <<= 1) { s += __shfl_xor(s, o); q += __shfl_xor(q, o); }
      ps[mi][r] = s; pq[mi][r] = q;
    }
  __syncthreads();
  float* red = (float*)smem;              // [64][8]: sum[wc], sq[4+wc]
  if (lr == 0) {
    #pragma unroll
    for (int mi = 0; mi < 2; ++mi)
      #pragma unroll
      for (int r = 0; r < 4; ++r) {
        int rl = wr * 32 + mi * 16 + kb + r;
        red[rl * 8 + wc] = ps[mi][r];
        red[rl * 8 + 4 + wc] = pq[mi][r];
      }
  }
  __syncthreads();
  if (t < 64) {
    float s = red[t * 8] + red[t * 8 + 1] + red[t * 8 + 2] + red[t * 8 + 3];
    float q = red[t * 8 + 4] + red[t * 8 + 5] + red[t * 8 + 6] + red[t * 8 + 7];
    float mu = s * 0.00390625f;
    float var = q * 0.00390625f - mu * mu;
    red[t * 8] = mu;
    red[t * 8 + 1] = rsqrtf(var + 1e-5f);
  }
  __syncthreads();
  #pragma unroll
  for (int mi = 0; mi < 2; ++mi)
    #pragma unroll
    for (int r = 0; r < 4; ++r) {
      int rl = wr * 32 + mi * 16 + kb + r;
      float mu = red[rl * 8], rs = red[rl * 8 + 1];
      size_t rowoff = (size_t)(m0 + rl) * CDIM;
      #pragma unroll
      for (int ni = 0; ni < 4; ++ni) {
        int colq = wc * 64 + ni * 16 + lr;
        float v = acc[mi][ni][r];
        t2[rowoff + colq] = (__bf16)v;
        hln[rowoff + colq] = (__bf16)((v - mu) * rs * colg[ni] + colb[ni]);
      }
    }
}

// -------- flash attention, QBLK=256, 8 waves (32 q-rows/wave) — R13 exact ---
__launch_bounds__(512)
__global__ void attn_kernel(const __bf16* __restrict__ qkv, const __bf16* __restrict__ vT,
                            const __bf16* __restrict__ biasB, __bf16* __restrict__ outb) {
  __shared__ __bf16 Ks[64][40];
  __shared__ __bf16 Vs[32][72];
  __shared__ __bf16 Bls[256][72];
  const int q0 = blockIdx.x * 256, h = blockIdx.y, b = blockIdx.z;
  const int t = threadIdx.x, lane = t & 63, w = t >> 6;     // 8 waves
  const int lr = lane & 15, kb = (lane >> 4) * 4;
  const size_t qbase = (size_t)b * NTOK * QKVD;
  const float qsc = SCALE * LOG2E;
  bfx8 qf[2];
  #pragma unroll
  for (int tq = 0; tq < 2; ++tq) {
    const __bf16* qp = &qkv[qbase + (size_t)(q0 + 32 * w + 16 * tq + lr) * QKVD + h * DHEAD];
    bfx4 lo = *(const bfx4*)&qp[kb];
    bfx4 hi = *(const bfx4*)&qp[kb + 16];
    #pragma unroll
    for (int j = 0; j < 4; ++j) {
      qf[tq][j]     = (__bf16)((float)lo[j] * qsc);
      qf[tq][j + 4] = (__bf16)((float)hi[j] * qsc);
    }
  }
  float l_run[2] = {0.f, 0.f};
  f32x4 oacc[2][2] = {};
  const int st_ = t & 255;
  const int krow = st_ >> 2, kc8 = (st_ & 3) * 8;   // K stage (t<256): 64x32
  const int vrow = st_ >> 3, vc8 = (st_ & 7) * 8;   // V stage (t>=256): 32x64
  const __bf16* kvptr = (t < 256)
      ? &qkv[qbase + (size_t)krow * QKVD + INNER + h * DHEAD + kc8]
      : &vT[(((size_t)b * NHEAD + h) * DHEAD + vrow) * NTOK + vc8];
  const __bf16* bbase = &biasB[((size_t)h * NTOK + q0) * NTOK];
  bfx8 rkv, rbias[4];
  auto issue = [&](int k0) {
    rkv = (t < 256) ? *(const bfx8*)&kvptr[(size_t)k0 * QKVD]
                    : *(const bfx8*)&kvptr[k0];
    #pragma unroll
    for (int j = 0; j < 4; ++j) {
      int lin = j * 512 + t;                  // 2048 chunks: 256 rows x 128B
      int br = lin >> 3, bc8 = (lin & 7) * 8;
      rbias[j] = *(const bfx8*)&bbase[(size_t)br * NTOK + k0 + bc8];
    }
  };
  issue(0);
  for (int kt = 0; kt < 16; ++kt) {
    __syncthreads();
    if (t < 256) *(bfx8*)&Ks[krow][kc8] = rkv;
    else         *(bfx8*)&Vs[vrow][vc8] = rkv;
    #pragma unroll
    for (int j = 0; j < 4; ++j) {
      int lin = j * 512 + t;
      int br = lin >> 3, bc8 = (lin & 7) * 8;
      *(bfx8*)&Bls[br][bc8] = rbias[j];
    }
    __syncthreads();
    if (kt < 15) issue((kt + 1) * 64);
    bfx8 kf[4], vfr[4];
    #pragma unroll
    for (int f = 0; f < 4; ++f) {
      bfx4 klo = *(const bfx4*)&Ks[16 * f + lr][kb];
      bfx4 khi = *(const bfx4*)&Ks[16 * f + lr][kb + 16];
      kf[f] = __builtin_shufflevector(klo, khi, 0, 1, 2, 3, 4, 5, 6, 7);
    }
    #pragma unroll
    for (int s = 0; s < 2; ++s)
      #pragma unroll
      for (int df = 0; df < 2; ++df) {
        bfx4 vlo = *(const bfx4*)&Vs[16 * df + lr][s * 32 + kb];
        bfx4 vhi = *(const bfx4*)&Vs[16 * df + lr][s * 32 + kb + 16];
        vfr[s * 2 + df] = __builtin_shufflevector(vlo, vhi, 0, 1, 2, 3, 4, 5, 6, 7);
      }
    #pragma unroll
    for (int tq = 0; tq < 2; ++tq) {
      const int qrow_l = 32 * w + 16 * tq + lr;
      f32x4 st[4];
      #pragma unroll
      for (int f = 0; f < 4; ++f) {
        bfx4 bv = *(const bfx4*)&Bls[qrow_l][16 * f + kb];
        f32x4 c;
        c[0] = (float)bv[0]; c[1] = (float)bv[1];
        c[2] = (float)bv[2]; c[3] = (float)bv[3];
        st[f] = __builtin_amdgcn_mfma_f32_16x16x32_bf16(kf[f], qf[tq], c, 0, 0, 0);
      }
      float p[4][4], tsum = 0.f;
      #pragma unroll
      for (int f = 0; f < 4; ++f)
        #pragma unroll
        for (int r = 0; r < 4; ++r) {
          float e = EXP2(st[f][r]);
          p[f][r] = e;
          tsum += e;
        }
      l_run[tq] += tsum;
      bfx8 pa0, pa1;
      #pragma unroll
      for (int r = 0; r < 4; ++r) {
        pa0[r] = (__bf16)p[0][r];  pa0[r + 4] = (__bf16)p[1][r];
        pa1[r] = (__bf16)p[2][r];  pa1[r + 4] = (__bf16)p[3][r];
      }
      #pragma unroll
      for (int s = 0; s < 2; ++s) {
        bfx8 pa = s ? pa1 : pa0;
        #pragma unroll
        for (int df = 0; df < 2; ++df)
          oacc[tq][df] = __builtin_amdgcn_mfma_f32_16x16x32_bf16(pa, vfr[s * 2 + df],
                                                                 oacc[tq][df], 0, 0, 0);
      }
    }
  }
  #pragma unroll
  for (int tq = 0; tq < 2; ++tq) {
    float l = l_run[tq];
    l += __shfl_xor(l, 16);
    l += __shfl_xor(l, 32);
    float il[4];
    #pragma unroll
    for (int r = 0; r < 4; ++r) il[r] = 1.f / __shfl(l, kb + r);
    #pragma unroll
    for (int r = 0; r < 4; ++r) {
      size_t rowoff = (size_t)b * NTOK * CDIM +
                      (size_t)(q0 + 32 * w + 16 * tq + kb + r) * CDIM + h * DHEAD;
      outb[rowoff + lr]      = (__bf16)(oacc[tq][0][r] * il[r]);
      outb[rowoff + 16 + lr] = (__bf16)(oacc[tq][1][r] * il[r]);
    }
  }
}

// ---------------------------------------------------------------------------
extern "C" void kernel_launch(void* const* d_in, const int* in_sizes, int n_in,
                              void* d_out, int out_size, void* d_ws, size_t ws_size,
                              hipStream_t stream) {
  const float* x     = (const float*)d_in[0];
  const float* ln1_g = (const float*)d_in[2];
  const float* ln1_b = (const float*)d_in[3];
  const float* Wqkv  = (const float*)d_in[4];
  const float* table = (const float*)d_in[5];
  const float* Wo    = (const float*)d_in[6];
  const float* bo    = (const float*)d_in[7];
  const float* ln2_g = (const float*)d_in[8];
  const float* ln2_b = (const float*)d_in[9];
  const float* W1    = (const float*)d_in[10];
  const float* b1    = (const float*)d_in[11];
  const float* W2    = (const float*)d_in[12];
  const float* b2    = (const float*)d_in[13];

  char* ws = (char*)d_ws;
  __bf16* t_bf  = (__bf16*)(ws + 0);          // 8 MB residual 1 (bf16)
  __bf16* t2_bf = (__bf16*)(ws + 8388608);    // 8 MB residual 2 (bf16)
  __bf16* qkv   = (__bf16*)(ws + 33554432);   // 24 MB
  __bf16* hln   = (__bf16*)(ws + 58720256);   // 8 MB (ln1 out, reused for ln2)
  __bf16* aout  = (__bf16*)(ws + 67108864);   // 8 MB
  __bf16* hid   = (__bf16*)(ws + 75497472);   // 16 MB (aliased: vT during attention)
  __bf16* vT    = (__bf16*)(ws + 75497472);   // 8.4 MB, dead before hid is written
  __bf16* biasB = (__bf16*)(ws + 92274688);   // 16 MB
  __bf16* Wqkvt = (__bf16*)(ws + 109051904);
  __bf16* Wot   = (__bf16*)(ws + 109445120);
  __bf16* W1t   = (__bf16*)(ws + 109576192);
  __bf16* W2t   = (__bf16*)(ws + 109838336);  // ends 110100480
  if (ws_size < 110100480) return;            // visible failure instead of OOB

  prep_kernel<<<6144, 256, 0, stream>>>(Wqkv, Wo, W1, W2, Wqkvt, Wot, W1t, W2t,
                                        table, biasB);
  txln_kernel<<<dim3(32, 1, 16), 256, 0, stream>>>(x, ln1_g, ln1_b, t_bf, hln);
  gemm128_kernel<0><<<dim3(128, 6), 256, 0, stream>>>(hln, Wqkvt, nullptr, nullptr, qkv, vT, 768, 256);
  attn_kernel<<<dim3(4, 8, 16), 512, 0, stream>>>(qkv, vT, biasB, aout);
  gemmWoLn_kernel<<<256, 512, 0, stream>>>(aout, Wot, bo, t_bf, ln2_g, ln2_b, t2_bf, hln);
  gemm128_kernel<2><<<dim3(128, 4), 256, 0, stream>>>(hln, W1t, b1, nullptr, hid, nullptr, 512, 256);
  gemm128_kernel<4><<<dim3(128, 2), 256, 0, stream>>>(hid, W2t, b2, t2_bf, d_out, nullptr, 256, 512);
}

// Round 25
// 127.857 us; speedup vs baseline: 1.0963x; 1.0079x over previous
//
#include <hip/hip_runtime.h>
#include <hip/hip_bf16.h>
#include <math.h>

typedef __bf16 bfx4 __attribute__((ext_vector_type(4)));
typedef __bf16 bfx8 __attribute__((ext_vector_type(8)));
typedef float  f32x4 __attribute__((ext_vector_type(4)));

#define BATCH 16
#define NTOK  1024
#define CDIM  256
#define NHEAD 8
#define DHEAD 32
#define QKVD  768
#define INNER 256
#define SCALE 0.17677669529663687f
#define LOG2E 1.4426950408889634f

#if __has_builtin(__builtin_amdgcn_exp2f)
#define EXP2(x) __builtin_amdgcn_exp2f(x)
#else
#define EXP2(x) exp2f(x)
#endif

// ------- fused transpose + LN1: x[B][C][N] -> t_bf bf16 [tok][C], hln bf16 --
__launch_bounds__(256)
__global__ void txln_kernel(const float* __restrict__ x, const float* __restrict__ g,
                            const float* __restrict__ bb, __bf16* __restrict__ tb,
                            __bf16* __restrict__ hln) {
  __shared__ float tile[256][33];
  const int b = blockIdx.z, n0 = blockIdx.x * 32;
  const int tt = threadIdx.x;
  const float* src = x + (size_t)b * CDIM * NTOK;
  #pragma unroll
  for (int i = 0; i < 8; ++i) {
    int cid = i * 256 + tt;
    int c = cid >> 3, col4 = (cid & 7) * 4;
    *(float4*)&tile[c][col4] = *(const float4*)&src[(size_t)c * NTOK + n0 + col4];
  }
  __syncthreads();
  const int n = tt >> 3, c0 = (tt & 7) * 32;   // 8 threads per token
  float vals[32];
  float s = 0.f, s2 = 0.f;
  #pragma unroll
  for (int j = 0; j < 32; ++j) {
    float v = tile[c0 + j][n];
    vals[j] = v; s += v; s2 += v * v;
  }
  s  += __shfl_xor(s, 1);  s  += __shfl_xor(s, 2);  s  += __shfl_xor(s, 4);
  s2 += __shfl_xor(s2, 1); s2 += __shfl_xor(s2, 2); s2 += __shfl_xor(s2, 4);
  float mu = s * 0.00390625f;
  float var = s2 * 0.00390625f - mu * mu;
  float rs = rsqrtf(var + 1e-5f);
  size_t row = ((size_t)b * NTOK + n0 + n) * CDIM;
  #pragma unroll
  for (int j = 0; j < 32; j += 4) {
    const float4 gg = *(const float4*)&g[c0 + j];
    const float4 bv = *(const float4*)&bb[c0 + j];
    bfx4 tv;
    tv[0] = (__bf16)vals[j];     tv[1] = (__bf16)vals[j + 1];
    tv[2] = (__bf16)vals[j + 2]; tv[3] = (__bf16)vals[j + 3];
    *(bfx4*)&tb[row + c0 + j] = tv;
    bfx4 o;
    o[0] = (__bf16)((vals[j]     - mu) * rs * gg.x + bv.x);
    o[1] = (__bf16)((vals[j + 1] - mu) * rs * gg.y + bv.y);
    o[2] = (__bf16)((vals[j + 2] - mu) * rs * gg.z + bv.z);
    o[3] = (__bf16)((vals[j + 3] - mu) * rs * gg.w + bv.w);
    *(bfx4*)&hln[row + c0 + j] = o;
  }
}

// ---- merged prep: weight transpose+cast (blocks 0..2047) + bias (2048..6143)
__launch_bounds__(256)
__global__ void prep_kernel(const float* __restrict__ Wqkv, const float* __restrict__ Wo,
                            const float* __restrict__ W1, const float* __restrict__ W2,
                            __bf16* __restrict__ Wqkvt, __bf16* __restrict__ Wot,
                            __bf16* __restrict__ W1t, __bf16* __restrict__ W2t,
                            const float* __restrict__ table, __bf16* __restrict__ biasB) {
  if (blockIdx.x < 2048) {
    int idx = blockIdx.x * 256 + threadIdx.x;
    const float* W; __bf16* Wt; int lk, Nn, off;
    if (idx < 196608)      { W = Wqkv; Wt = Wqkvt; lk = 8; Nn = 768; off = idx; }
    else if (idx < 262144) { W = Wo;   Wt = Wot;   lk = 8; Nn = 256; off = idx - 196608; }
    else if (idx < 393216) { W = W1;   Wt = W1t;   lk = 8; Nn = 512; off = idx - 262144; }
    else                   { W = W2;   Wt = W2t;   lk = 9; Nn = 256; off = idx - 393216; }
    int n = off >> lk, k = off & ((1 << lk) - 1);
    Wt[off] = (__bf16)W[(size_t)k * Nn + n];
  } else {
    int idx = (blockIdx.x - 2048) * 256 + threadIdx.x;   // h*2^17 + q*2^7 + k8
    int k8 = (idx & 127) * 8, q = (idx >> 7) & 1023, h = idx >> 17;
    int qi = q >> 5, qj = q & 31;
    bfx8 o;
    #pragma unroll
    for (int j = 0; j < 8; ++j) {
      int k = k8 + j, ki = k >> 5, kj = k & 31;
      int r = (qi - ki + 31) * 63 + (qj - kj + 31);
      o[j] = (__bf16)(table[r * 8 + h] * LOG2E);
    }
    *(bfx8*)&biasB[((size_t)idx) * 8] = o;
  }
}

// ---------------- GEMM 128x128 tile, BK=64, k-permuted LDS (R13) ------------
// EPI 0: store bf16 (qkv: if vTout && n0>=512, scatter V into vT instead).
// EPI 2: +bias, GELU -> bf16.
template <int EPI>
__launch_bounds__(256)
__global__ void gemm128_kernel(const __bf16* __restrict__ A, const __bf16* __restrict__ Bt,
                               const float* __restrict__ bias,
                               const __bf16* __restrict__ residb,
                               void* __restrict__ outp, __bf16* __restrict__ vTout,
                               int Nn, int K) {
  __shared__ char smem[36864];
  __bf16 (*As)[72] = (__bf16(*)[72])smem;
  __bf16 (*Bs)[72] = (__bf16(*)[72])(smem + 18432);
  const int t = threadIdx.x, lane = t & 63, w = t >> 6;
  const int m0 = blockIdx.x * 128, n0 = blockIdx.y * 128;
  const int wr = w >> 1, wc = w & 1;
  const int lr = lane & 15, kb = (lane >> 4) * 4;
  int srow[4], sp0[4], sp1[4];
  #pragma unroll
  for (int i = 0; i < 4; ++i) {
    int cid = i * 256 + t, kb8 = (cid & 7) * 8;
    srow[i] = cid >> 3;
    int b0 = kb8, b1 = kb8 + 4;
    sp0[i] = (b0 & 32) + ((b0 & 12) << 1) + (((b0 >> 4) & 1) << 2) + (b0 & 3);
    sp1[i] = (b1 & 32) + ((b1 & 12) << 1) + (((b1 >> 4) & 1) << 2) + (b1 & 3);
  }
  f32x4 acc[4][4] = {};
  bfx8 ra[4], rb[4];
  auto gload = [&](int k0) {
    #pragma unroll
    for (int i = 0; i < 4; ++i) {
      int kc8 = ((i * 256 + t) & 7) * 8;
      ra[i] = *(const bfx8*)&A[(size_t)(m0 + srow[i]) * K + k0 + kc8];
      rb[i] = *(const bfx8*)&Bt[(size_t)(n0 + srow[i]) * K + k0 + kc8];
    }
  };
  gload(0);
  for (int k0 = 0; k0 < K; k0 += 64) {
    __syncthreads();
    #pragma unroll
    for (int i = 0; i < 4; ++i) {
      *(bfx4*)&As[srow[i]][sp0[i]] = __builtin_shufflevector(ra[i], ra[i], 0, 1, 2, 3);
      *(bfx4*)&As[srow[i]][sp1[i]] = __builtin_shufflevector(ra[i], ra[i], 4, 5, 6, 7);
      *(bfx4*)&Bs[srow[i]][sp0[i]] = __builtin_shufflevector(rb[i], rb[i], 0, 1, 2, 3);
      *(bfx4*)&Bs[srow[i]][sp1[i]] = __builtin_shufflevector(rb[i], rb[i], 4, 5, 6, 7);
    }
    __syncthreads();
    if (k0 + 64 < K) gload(k0 + 64);
    #pragma unroll
    for (int ks = 0; ks < 2; ++ks) {
      bfx8 af[4], bf[4];
      #pragma unroll
      for (int mi = 0; mi < 4; ++mi)
        af[mi] = *(const bfx8*)&As[wr * 64 + mi * 16 + lr][ks * 32 + kb * 2];
      #pragma unroll
      for (int ni = 0; ni < 4; ++ni)
        bf[ni] = *(const bfx8*)&Bs[wc * 64 + ni * 16 + lr][ks * 32 + kb * 2];
      #pragma unroll
      for (int mi = 0; mi < 4; ++mi)
        #pragma unroll
        for (int ni = 0; ni < 4; ++ni)
          acc[mi][ni] = __builtin_amdgcn_mfma_f32_16x16x32_bf16(af[mi], bf[ni],
                                                                acc[mi][ni], 0, 0, 0);
    }
  }
  if (EPI == 0 && vTout != nullptr && n0 >= 512) {
    #pragma unroll
    for (int mi = 0; mi < 4; ++mi)
      #pragma unroll
      for (int ni = 0; ni < 4; ++ni) {
        int n = n0 + wc * 64 + ni * 16 + lr;
        int cp = n - 512, hh = cp >> 5, dd = cp & 31;
        int m = m0 + wr * 64 + mi * 16 + kb;
        int bb_ = m >> 10, tok = m & 1023;
        bfx4 o;
        o[0] = (__bf16)acc[mi][ni][0]; o[1] = (__bf16)acc[mi][ni][1];
        o[2] = (__bf16)acc[mi][ni][2]; o[3] = (__bf16)acc[mi][ni][3];
        *(bfx4*)&vTout[(((size_t)bb_ * NHEAD + hh) * DHEAD + dd) * NTOK + tok] = o;
      }
    return;
  }
  #pragma unroll
  for (int mi = 0; mi < 4; ++mi)
    #pragma unroll
    for (int ni = 0; ni < 4; ++ni)
      #pragma unroll
      for (int r = 0; r < 4; ++r) {
        int m = m0 + wr * 64 + mi * 16 + kb + r;
        int n = n0 + wc * 64 + ni * 16 + lr;
        float v = acc[mi][ni][r];
        if (EPI == 0) {
          ((__bf16*)outp)[(size_t)m * Nn + n] = (__bf16)v;
        } else if (EPI == 2) {
          v += bias[n];
          v = 0.5f * v * (1.0f + erff(v * 0.70710678118f));
          ((__bf16*)outp)[(size_t)m * Nn + n] = (__bf16)v;
        }
      }
}

// ---- Wo GEMM (BM=64, BN=256 full width) + bias + resid + fused LN2 ---------
__launch_bounds__(512)
__global__ void gemmWoLn_kernel(const __bf16* __restrict__ A, const __bf16* __restrict__ Bt,
                                const float* __restrict__ bias,
                                const __bf16* __restrict__ residb,
                                const float* __restrict__ g2, const float* __restrict__ b2v,
                                __bf16* __restrict__ t2, __bf16* __restrict__ hln) {
  __shared__ char smem[46080];
  __bf16 (*As)[72] = (__bf16(*)[72])smem;             // 64 x 72
  __bf16 (*Bs)[72] = (__bf16(*)[72])(smem + 9216);    // 256 x 72
  const int t = threadIdx.x, lane = t & 63, w = t >> 6;
  const int m0 = blockIdx.x * 64;
  const int wr = w >> 2, wc = w & 3;
  const int lr = lane & 15, kb = (lane >> 4) * 4;
  const int K = 256;
  const int arow = t >> 3, ac8 = (t & 7) * 8;
  int ap0, ap1;
  {
    int b0 = ac8, b1 = ac8 + 4;
    ap0 = (b0 & 32) + ((b0 & 12) << 1) + (((b0 >> 4) & 1) << 2) + (b0 & 3);
    ap1 = (b1 & 32) + ((b1 & 12) << 1) + (((b1 >> 4) & 1) << 2) + (b1 & 3);
  }
  int brow[4], bp0[4], bp1[4], bc8[4];
  #pragma unroll
  for (int j = 0; j < 4; ++j) {
    int cid = j * 512 + t;
    brow[j] = cid >> 3;
    bc8[j] = (cid & 7) * 8;
    int b0 = bc8[j], b1 = bc8[j] + 4;
    bp0[j] = (b0 & 32) + ((b0 & 12) << 1) + (((b0 >> 4) & 1) << 2) + (b0 & 3);
    bp1[j] = (b1 & 32) + ((b1 & 12) << 1) + (((b1 >> 4) & 1) << 2) + (b1 & 3);
  }
  f32x4 acc[2][4] = {};
  bfx8 ra, rb[4];
  auto gload = [&](int k0) {
    ra = *(const bfx8*)&A[(size_t)(m0 + arow) * K + k0 + ac8];
    #pragma unroll
    for (int j = 0; j < 4; ++j)
      rb[j] = *(const bfx8*)&Bt[(size_t)brow[j] * K + k0 + bc8[j]];
  };
  gload(0);
  for (int k0 = 0; k0 < K; k0 += 64) {
    __syncthreads();
    *(bfx4*)&As[arow][ap0] = __builtin_shufflevector(ra, ra, 0, 1, 2, 3);
    *(bfx4*)&As[arow][ap1] = __builtin_shufflevector(ra, ra, 4, 5, 6, 7);
    #pragma unroll
    for (int j = 0; j < 4; ++j) {
      *(bfx4*)&Bs[brow[j]][bp0[j]] = __builtin_shufflevector(rb[j], rb[j], 0, 1, 2, 3);
      *(bfx4*)&Bs[brow[j]][bp1[j]] = __builtin_shufflevector(rb[j], rb[j], 4, 5, 6, 7);
    }
    __syncthreads();
    if (k0 + 64 < K) gload(k0 + 64);
    #pragma unroll
    for (int ks = 0; ks < 2; ++ks) {
      bfx8 af[2], bf[4];
      #pragma unroll
      for (int mi = 0; mi < 2; ++mi)
        af[mi] = *(const bfx8*)&As[wr * 32 + mi * 16 + lr][ks * 32 + kb * 2];
      #pragma unroll
      for (int ni = 0; ni < 4; ++ni)
        bf[ni] = *(const bfx8*)&Bs[wc * 64 + ni * 16 + lr][ks * 32 + kb * 2];
      #pragma unroll
      for (int mi = 0; mi < 2; ++mi)
        #pragma unroll
        for (int ni = 0; ni < 4; ++ni)
          acc[mi][ni] = __builtin_amdgcn_mfma_f32_16x16x32_bf16(af[mi], bf[ni],
                                                                acc[mi][ni], 0, 0, 0);
    }
  }
  float colg[4], colb[4];
  #pragma unroll
  for (int ni = 0; ni < 4; ++ni) {
    int colq = wc * 64 + ni * 16 + lr;
    float bn = bias[colq];
    colg[ni] = g2[colq];
    colb[ni] = b2v[colq];
    #pragma unroll
    for (int mi = 0; mi < 2; ++mi)
      #pragma unroll
      for (int r = 0; r < 4; ++r) {
        int m = m0 + wr * 32 + mi * 16 + kb + r;
        acc[mi][ni][r] += bn + (float)residb[(size_t)m * CDIM + colq];
      }
  }
  float ps[2][4], pq[2][4];
  #pragma unroll
  for (int mi = 0; mi < 2; ++mi)
    #pragma unroll
    for (int r = 0; r < 4; ++r) {
      float s = 0.f, q = 0.f;
      #pragma unroll
      for (int ni = 0; ni < 4; ++ni) {
        float v = acc[mi][ni][r];
        s += v; q += v * v;
      }
      #pragma unroll
      for (int o = 1; o < 16; o <<= 1) { s += __shfl_xor(s, o); q += __shfl_xor(q, o); }
      ps[mi][r] = s; pq[mi][r] = q;
    }
  __syncthreads();
  float* red = (float*)smem;              // [64][8]: sum[wc], sq[4+wc]
  if (lr == 0) {
    #pragma unroll
    for (int mi = 0; mi < 2; ++mi)
      #pragma unroll
      for (int r = 0; r < 4; ++r) {
        int rl = wr * 32 + mi * 16 + kb + r;
        red[rl * 8 + wc] = ps[mi][r];
        red[rl * 8 + 4 + wc] = pq[mi][r];
      }
  }
  __syncthreads();
  if (t < 64) {
    float s = red[t * 8] + red[t * 8 + 1] + red[t * 8 + 2] + red[t * 8 + 3];
    float q = red[t * 8 + 4] + red[t * 8 + 5] + red[t * 8 + 6] + red[t * 8 + 7];
    float mu = s * 0.00390625f;
    float var = q * 0.00390625f - mu * mu;
    red[t * 8] = mu;
    red[t * 8 + 1] = rsqrtf(var + 1e-5f);
  }
  __syncthreads();
  #pragma unroll
  for (int mi = 0; mi < 2; ++mi)
    #pragma unroll
    for (int r = 0; r < 4; ++r) {
      int rl = wr * 32 + mi * 16 + kb + r;
      float mu = red[rl * 8], rs = red[rl * 8 + 1];
      size_t rowoff = (size_t)(m0 + rl) * CDIM;
      #pragma unroll
      for (int ni = 0; ni < 4; ++ni) {
        int colq = wc * 64 + ni * 16 + lr;
        float v = acc[mi][ni][r];
        t2[rowoff + colq] = (__bf16)v;
        hln[rowoff + colq] = (__bf16)((v - mu) * rs * colg[ni] + colb[ni]);
      }
    }
}

// ---- W2 GEMM (BM=64, BN=256, K=512) + bias + resid, TRANSPOSED fp32 out ----
// 8 waves/CU (vs 4 for the old 128x128 shape). Output out[b][c][tok] via a
// [128][68] fp32 LDS retile (two channel-halves), coalesced 256B row writes.
__launch_bounds__(512)
__global__ void gemmW2T_kernel(const __bf16* __restrict__ A, const __bf16* __restrict__ Bt,
                               const float* __restrict__ bias,
                               const __bf16* __restrict__ residb,
                               float* __restrict__ outp) {
  __shared__ char smem[46080];
  __bf16 (*As)[72] = (__bf16(*)[72])smem;             // 64 x 72
  __bf16 (*Bs)[72] = (__bf16(*)[72])(smem + 9216);    // 256 x 72
  const int t = threadIdx.x, lane = t & 63, w = t >> 6;
  const int m0 = blockIdx.x * 64;
  const int wr = w >> 2, wc = w & 3;
  const int lr = lane & 15, kb = (lane >> 4) * 4;
  const int K = 512;
  const int arow = t >> 3, ac8 = (t & 7) * 8;
  int ap0, ap1;
  {
    int b0 = ac8, b1 = ac8 + 4;
    ap0 = (b0 & 32) + ((b0 & 12) << 1) + (((b0 >> 4) & 1) << 2) + (b0 & 3);
    ap1 = (b1 & 32) + ((b1 & 12) << 1) + (((b1 >> 4) & 1) << 2) + (b1 & 3);
  }
  int brow[4], bp0[4], bp1[4], bc8[4];
  #pragma unroll
  for (int j = 0; j < 4; ++j) {
    int cid = j * 512 + t;
    brow[j] = cid >> 3;
    bc8[j] = (cid & 7) * 8;
    int b0 = bc8[j], b1 = bc8[j] + 4;
    bp0[j] = (b0 & 32) + ((b0 & 12) << 1) + (((b0 >> 4) & 1) << 2) + (b0 & 3);
    bp1[j] = (b1 & 32) + ((b1 & 12) << 1) + (((b1 >> 4) & 1) << 2) + (b1 & 3);
  }
  f32x4 acc[2][4] = {};
  bfx8 ra, rb[4];
  auto gload = [&](int k0) {
    ra = *(const bfx8*)&A[(size_t)(m0 + arow) * K + k0 + ac8];
    #pragma unroll
    for (int j = 0; j < 4; ++j)
      rb[j] = *(const bfx8*)&Bt[(size_t)brow[j] * K + k0 + bc8[j]];
  };
  gload(0);
  for (int k0 = 0; k0 < K; k0 += 64) {
    __syncthreads();
    *(bfx4*)&As[arow][ap0] = __builtin_shufflevector(ra, ra, 0, 1, 2, 3);
    *(bfx4*)&As[arow][ap1] = __builtin_shufflevector(ra, ra, 4, 5, 6, 7);
    #pragma unroll
    for (int j = 0; j < 4; ++j) {
      *(bfx4*)&Bs[brow[j]][bp0[j]] = __builtin_shufflevector(rb[j], rb[j], 0, 1, 2, 3);
      *(bfx4*)&Bs[brow[j]][bp1[j]] = __builtin_shufflevector(rb[j], rb[j], 4, 5, 6, 7);
    }
    __syncthreads();
    if (k0 + 64 < K) gload(k0 + 64);
    #pragma unroll
    for (int ks = 0; ks < 2; ++ks) {
      bfx8 af[2], bf[4];
      #pragma unroll
      for (int mi = 0; mi < 2; ++mi)
        af[mi] = *(const bfx8*)&As[wr * 32 + mi * 16 + lr][ks * 32 + kb * 2];
      #pragma unroll
      for (int ni = 0; ni < 4; ++ni)
        bf[ni] = *(const bfx8*)&Bs[wc * 64 + ni * 16 + lr][ks * 32 + kb * 2];
      #pragma unroll
      for (int mi = 0; mi < 2; ++mi)
        #pragma unroll
        for (int ni = 0; ni < 4; ++ni)
          acc[mi][ni] = __builtin_amdgcn_mfma_f32_16x16x32_bf16(af[mi], bf[ni],
                                                                acc[mi][ni], 0, 0, 0);
    }
  }
  // epilogue: v = acc + bias + resid, transposed store via [128][68] LDS retile
  const int bb_ = m0 >> 10, tok0 = m0 & 1023;
  float* obase = outp + (size_t)bb_ * CDIM * NTOK + tok0;
  float* Ty = (float*)smem;
  #pragma unroll
  for (int h2 = 0; h2 < 2; ++h2) {
    __syncthreads();                    // staging (or prev half) reads done
    if ((wc >> 1) == h2) {
      #pragma unroll
      for (int ni = 0; ni < 4; ++ni) {
        int colq = wc * 64 + ni * 16 + lr;     // global channel
        int chl = colq - h2 * 128;             // 0..127 within half
        float bn = bias[colq];
        #pragma unroll
        for (int mi = 0; mi < 2; ++mi) {
          int tk = wr * 32 + mi * 16 + kb;
          float4 v4;
          #pragma unroll
          for (int r = 0; r < 4; ++r)
            ((float*)&v4)[r] = acc[mi][ni][r] + bn +
                (float)residb[(size_t)(m0 + tk + r) * CDIM + colq];
          *(float4*)&Ty[chl * 68 + tk] = v4;
        }
      }
    }
    __syncthreads();
    int row = t >> 2, quad = t & 3;
    #pragma unroll
    for (int j = 0; j < 4; ++j) {
      int p = quad + j * 4;                    // 16 float4 positions per row
      *(float4*)&obase[(size_t)(h2 * 128 + row) * NTOK + p * 4] =
          *(const float4*)&Ty[row * 68 + p * 4];
    }
  }
}

// -------- flash attention, QBLK=256, 8 waves (32 q-rows/wave) — R13 exact ---
__launch_bounds__(512)
__global__ void attn_kernel(const __bf16* __restrict__ qkv, const __bf16* __restrict__ vT,
                            const __bf16* __restrict__ biasB, __bf16* __restrict__ outb) {
  __shared__ __bf16 Ks[64][40];
  __shared__ __bf16 Vs[32][72];
  __shared__ __bf16 Bls[256][72];
  const int q0 = blockIdx.x * 256, h = blockIdx.y, b = blockIdx.z;
  const int t = threadIdx.x, lane = t & 63, w = t >> 6;     // 8 waves
  const int lr = lane & 15, kb = (lane >> 4) * 4;
  const size_t qbase = (size_t)b * NTOK * QKVD;
  const float qsc = SCALE * LOG2E;
  bfx8 qf[2];
  #pragma unroll
  for (int tq = 0; tq < 2; ++tq) {
    const __bf16* qp = &qkv[qbase + (size_t)(q0 + 32 * w + 16 * tq + lr) * QKVD + h * DHEAD];
    bfx4 lo = *(const bfx4*)&qp[kb];
    bfx4 hi = *(const bfx4*)&qp[kb + 16];
    #pragma unroll
    for (int j = 0; j < 4; ++j) {
      qf[tq][j]     = (__bf16)((float)lo[j] * qsc);
      qf[tq][j + 4] = (__bf16)((float)hi[j] * qsc);
    }
  }
  float l_run[2] = {0.f, 0.f};
  f32x4 oacc[2][2] = {};
  const int st_ = t & 255;
  const int krow = st_ >> 2, kc8 = (st_ & 3) * 8;   // K stage (t<256): 64x32
  const int vrow = st_ >> 3, vc8 = (st_ & 7) * 8;   // V stage (t>=256): 32x64
  const __bf16* kvptr = (t < 256)
      ? &qkv[qbase + (size_t)krow * QKVD + INNER + h * DHEAD + kc8]
      : &vT[(((size_t)b * NHEAD + h) * DHEAD + vrow) * NTOK + vc8];
  const __bf16* bbase = &biasB[((size_t)h * NTOK + q0) * NTOK];
  bfx8 rkv, rbias[4];
  auto issue = [&](int k0) {
    rkv = (t < 256) ? *(const bfx8*)&kvptr[(size_t)k0 * QKVD]
                    : *(const bfx8*)&kvptr[k0];
    #pragma unroll
    for (int j = 0; j < 4; ++j) {
      int lin = j * 512 + t;                  // 2048 chunks: 256 rows x 128B
      int br = lin >> 3, bc8 = (lin & 7) * 8;
      rbias[j] = *(const bfx8*)&bbase[(size_t)br * NTOK + k0 + bc8];
    }
  };
  issue(0);
  for (int kt = 0; kt < 16; ++kt) {
    __syncthreads();
    if (t < 256) *(bfx8*)&Ks[krow][kc8] = rkv;
    else         *(bfx8*)&Vs[vrow][vc8] = rkv;
    #pragma unroll
    for (int j = 0; j < 4; ++j) {
      int lin = j * 512 + t;
      int br = lin >> 3, bc8 = (lin & 7) * 8;
      *(bfx8*)&Bls[br][bc8] = rbias[j];
    }
    __syncthreads();
    if (kt < 15) issue((kt + 1) * 64);
    bfx8 kf[4], vfr[4];
    #pragma unroll
    for (int f = 0; f < 4; ++f) {
      bfx4 klo = *(const bfx4*)&Ks[16 * f + lr][kb];
      bfx4 khi = *(const bfx4*)&Ks[16 * f + lr][kb + 16];
      kf[f] = __builtin_shufflevector(klo, khi, 0, 1, 2, 3, 4, 5, 6, 7);
    }
    #pragma unroll
    for (int s = 0; s < 2; ++s)
      #pragma unroll
      for (int df = 0; df < 2; ++df) {
        bfx4 vlo = *(const bfx4*)&Vs[16 * df + lr][s * 32 + kb];
        bfx4 vhi = *(const bfx4*)&Vs[16 * df + lr][s * 32 + kb + 16];
        vfr[s * 2 + df] = __builtin_shufflevector(vlo, vhi, 0, 1, 2, 3, 4, 5, 6, 7);
      }
    #pragma unroll
    for (int tq = 0; tq < 2; ++tq) {
      const int qrow_l = 32 * w + 16 * tq + lr;
      f32x4 st[4];
      #pragma unroll
      for (int f = 0; f < 4; ++f) {
        bfx4 bv = *(const bfx4*)&Bls[qrow_l][16 * f + kb];
        f32x4 c;
        c[0] = (float)bv[0]; c[1] = (float)bv[1];
        c[2] = (float)bv[2]; c[3] = (float)bv[3];
        st[f] = __builtin_amdgcn_mfma_f32_16x16x32_bf16(kf[f], qf[tq], c, 0, 0, 0);
      }
      float p[4][4], tsum = 0.f;
      #pragma unroll
      for (int f = 0; f < 4; ++f)
        #pragma unroll
        for (int r = 0; r < 4; ++r) {
          float e = EXP2(st[f][r]);
          p[f][r] = e;
          tsum += e;
        }
      l_run[tq] += tsum;
      bfx8 pa0, pa1;
      #pragma unroll
      for (int r = 0; r < 4; ++r) {
        pa0[r] = (__bf16)p[0][r];  pa0[r + 4] = (__bf16)p[1][r];
        pa1[r] = (__bf16)p[2][r];  pa1[r + 4] = (__bf16)p[3][r];
      }
      #pragma unroll
      for (int s = 0; s < 2; ++s) {
        bfx8 pa = s ? pa1 : pa0;
        #pragma unroll
        for (int df = 0; df < 2; ++df)
          oacc[tq][df] = __builtin_amdgcn_mfma_f32_16x16x32_bf16(pa, vfr[s * 2 + df],
                                                                 oacc[tq][df], 0, 0, 0);
      }
    }
  }
  #pragma unroll
  for (int tq = 0; tq < 2; ++tq) {
    float l = l_run[tq];
    l += __shfl_xor(l, 16);
    l += __shfl_xor(l, 32);
    float il[4];
    #pragma unroll
    for (int r = 0; r < 4; ++r) il[r] = 1.f / __shfl(l, kb + r);
    #pragma unroll
    for (int r = 0; r < 4; ++r) {
      size_t rowoff = (size_t)b * NTOK * CDIM +
                      (size_t)(q0 + 32 * w + 16 * tq + kb + r) * CDIM + h * DHEAD;
      outb[rowoff + lr]      = (__bf16)(oacc[tq][0][r] * il[r]);
      outb[rowoff + 16 + lr] = (__bf16)(oacc[tq][1][r] * il[r]);
    }
  }
}

// ---------------------------------------------------------------------------
extern "C" void kernel_launch(void* const* d_in, const int* in_sizes, int n_in,
                              void* d_out, int out_size, void* d_ws, size_t ws_size,
                              hipStream_t stream) {
  const float* x     = (const float*)d_in[0];
  const float* ln1_g = (const float*)d_in[2];
  const float* ln1_b = (const float*)d_in[3];
  const float* Wqkv  = (const float*)d_in[4];
  const float* table = (const float*)d_in[5];
  const float* Wo    = (const float*)d_in[6];
  const float* bo    = (const float*)d_in[7];
  const float* ln2_g = (const float*)d_in[8];
  const float* ln2_b = (const float*)d_in[9];
  const float* W1    = (const float*)d_in[10];
  const float* b1    = (const float*)d_in[11];
  const float* W2    = (const float*)d_in[12];
  const float* b2    = (const float*)d_in[13];

  char* ws = (char*)d_ws;
  __bf16* t_bf  = (__bf16*)(ws + 0);          // 8 MB residual 1 (bf16)
  __bf16* t2_bf = (__bf16*)(ws + 8388608);    // 8 MB residual 2 (bf16)
  __bf16* qkv   = (__bf16*)(ws + 33554432);   // 24 MB
  __bf16* hln   = (__bf16*)(ws + 58720256);   // 8 MB (ln1 out, reused for ln2)
  __bf16* aout  = (__bf16*)(ws + 67108864);   // 8 MB
  __bf16* hid   = (__bf16*)(ws + 75497472);   // 16 MB (aliased: vT during attention)
  __bf16* vT    = (__bf16*)(ws + 75497472);   // 8.4 MB, dead before hid is written
  __bf16* biasB = (__bf16*)(ws + 92274688);   // 16 MB
  __bf16* Wqkvt = (__bf16*)(ws + 109051904);
  __bf16* Wot   = (__bf16*)(ws + 109445120);
  __bf16* W1t   = (__bf16*)(ws + 109576192);
  __bf16* W2t   = (__bf16*)(ws + 109838336);  // ends 110100480
  if (ws_size < 110100480) return;            // visible failure instead of OOB

  prep_kernel<<<6144, 256, 0, stream>>>(Wqkv, Wo, W1, W2, Wqkvt, Wot, W1t, W2t,
                                        table, biasB);
  txln_kernel<<<dim3(32, 1, 16), 256, 0, stream>>>(x, ln1_g, ln1_b, t_bf, hln);
  gemm128_kernel<0><<<dim3(128, 6), 256, 0, stream>>>(hln, Wqkvt, nullptr, nullptr, qkv, vT, 768, 256);
  attn_kernel<<<dim3(4, 8, 16), 512, 0, stream>>>(qkv, vT, biasB, aout);
  gemmWoLn_kernel<<<256, 512, 0, stream>>>(aout, Wot, bo, t_bf, ln2_g, ln2_b, t2_bf, hln);
  gemm128_kernel<2><<<dim3(128, 4), 256, 0, stream>>>(hln, W1t, b1, nullptr, hid, nullptr, 512, 256);
  gemmW2T_kernel<<<256, 512, 0, stream>>>(hid, W2t, b2, t2_bf, (float*)d_out);
}

// Round 26
// 125.990 us; speedup vs baseline: 1.1125x; 1.0148x over previous
//
#include <hip/hip_runtime.h>
#include <hip/hip_bf16.h>
#include <math.h>

typedef __bf16 bfx4 __attribute__((ext_vector_type(4)));
typedef __bf16 bfx8 __attribute__((ext_vector_type(8)));
typedef float  f32x4 __attribute__((ext_vector_type(4)));

#define BATCH 16
#define NTOK  1024
#define CDIM  256
#define NHEAD 8
#define DHEAD 32
#define QKVD  768
#define INNER 256
#define SCALE 0.17677669529663687f
#define LOG2E 1.4426950408889634f

#if __has_builtin(__builtin_amdgcn_exp2f)
#define EXP2(x) __builtin_amdgcn_exp2f(x)
#else
#define EXP2(x) exp2f(x)
#endif

// ------- fused transpose + LN1: x[B][C][N] -> t_bf bf16 [tok][C], hln bf16 --
__launch_bounds__(256)
__global__ void txln_kernel(const float* __restrict__ x, const float* __restrict__ g,
                            const float* __restrict__ bb, __bf16* __restrict__ tb,
                            __bf16* __restrict__ hln) {
  __shared__ float tile[256][33];
  const int b = blockIdx.z, n0 = blockIdx.x * 32;
  const int tt = threadIdx.x;
  const float* src = x + (size_t)b * CDIM * NTOK;
  #pragma unroll
  for (int i = 0; i < 8; ++i) {
    int cid = i * 256 + tt;
    int c = cid >> 3, col4 = (cid & 7) * 4;
    *(float4*)&tile[c][col4] = *(const float4*)&src[(size_t)c * NTOK + n0 + col4];
  }
  __syncthreads();
  const int n = tt >> 3, c0 = (tt & 7) * 32;   // 8 threads per token
  float vals[32];
  float s = 0.f, s2 = 0.f;
  #pragma unroll
  for (int j = 0; j < 32; ++j) {
    float v = tile[c0 + j][n];
    vals[j] = v; s += v; s2 += v * v;
  }
  s  += __shfl_xor(s, 1);  s  += __shfl_xor(s, 2);  s  += __shfl_xor(s, 4);
  s2 += __shfl_xor(s2, 1); s2 += __shfl_xor(s2, 2); s2 += __shfl_xor(s2, 4);
  float mu = s * 0.00390625f;
  float var = s2 * 0.00390625f - mu * mu;
  float rs = rsqrtf(var + 1e-5f);
  size_t row = ((size_t)b * NTOK + n0 + n) * CDIM;
  #pragma unroll
  for (int j = 0; j < 32; j += 4) {
    const float4 gg = *(const float4*)&g[c0 + j];
    const float4 bv = *(const float4*)&bb[c0 + j];
    bfx4 tv;
    tv[0] = (__bf16)vals[j];     tv[1] = (__bf16)vals[j + 1];
    tv[2] = (__bf16)vals[j + 2]; tv[3] = (__bf16)vals[j + 3];
    *(bfx4*)&tb[row + c0 + j] = tv;
    bfx4 o;
    o[0] = (__bf16)((vals[j]     - mu) * rs * gg.x + bv.x);
    o[1] = (__bf16)((vals[j + 1] - mu) * rs * gg.y + bv.y);
    o[2] = (__bf16)((vals[j + 2] - mu) * rs * gg.z + bv.z);
    o[3] = (__bf16)((vals[j + 3] - mu) * rs * gg.w + bv.w);
    *(bfx4*)&hln[row + c0 + j] = o;
  }
}

// ---- merged prep: weight transpose+cast (blocks 0..2047) + bias (2048..6143)
__launch_bounds__(256)
__global__ void prep_kernel(const float* __restrict__ Wqkv, const float* __restrict__ Wo,
                            const float* __restrict__ W1, const float* __restrict__ W2,
                            __bf16* __restrict__ Wqkvt, __bf16* __restrict__ Wot,
                            __bf16* __restrict__ W1t, __bf16* __restrict__ W2t,
                            const float* __restrict__ table, __bf16* __restrict__ biasB) {
  if (blockIdx.x < 2048) {
    int idx = blockIdx.x * 256 + threadIdx.x;
    const float* W; __bf16* Wt; int lk, Nn, off;
    if (idx < 196608)      { W = Wqkv; Wt = Wqkvt; lk = 8; Nn = 768; off = idx; }
    else if (idx < 262144) { W = Wo;   Wt = Wot;   lk = 8; Nn = 256; off = idx - 196608; }
    else if (idx < 393216) { W = W1;   Wt = W1t;   lk = 8; Nn = 512; off = idx - 262144; }
    else                   { W = W2;   Wt = W2t;   lk = 9; Nn = 256; off = idx - 393216; }
    int n = off >> lk, k = off & ((1 << lk) - 1);
    Wt[off] = (__bf16)W[(size_t)k * Nn + n];
  } else {
    int idx = (blockIdx.x - 2048) * 256 + threadIdx.x;   // h*2^17 + q*2^7 + k8
    int k8 = (idx & 127) * 8, q = (idx >> 7) & 1023, h = idx >> 17;
    int qi = q >> 5, qj = q & 31;
    bfx8 o;
    #pragma unroll
    for (int j = 0; j < 8; ++j) {
      int k = k8 + j, ki = k >> 5, kj = k & 31;
      int r = (qi - ki + 31) * 63 + (qj - kj + 31);
      o[j] = (__bf16)(table[r * 8 + h] * LOG2E);
    }
    *(bfx8*)&biasB[((size_t)idx) * 8] = o;
  }
}

// ---------------- GEMM 128x128 tile, BK=64, k-permuted LDS (R13) ------------
// EPI 0: store bf16 (qkv: if vTout && n0>=512, scatter V into vT instead).
// EPI 2: +bias, GELU -> bf16.
template <int EPI>
__launch_bounds__(256)
__global__ void gemm128_kernel(const __bf16* __restrict__ A, const __bf16* __restrict__ Bt,
                               const float* __restrict__ bias,
                               const __bf16* __restrict__ residb,
                               void* __restrict__ outp, __bf16* __restrict__ vTout,
                               int Nn, int K) {
  __shared__ char smem[36864];
  __bf16 (*As)[72] = (__bf16(*)[72])smem;
  __bf16 (*Bs)[72] = (__bf16(*)[72])(smem + 18432);
  const int t = threadIdx.x, lane = t & 63, w = t >> 6;
  const int m0 = blockIdx.x * 128, n0 = blockIdx.y * 128;
  const int wr = w >> 1, wc = w & 1;
  const int lr = lane & 15, kb = (lane >> 4) * 4;
  int srow[4], sp0[4], sp1[4];
  #pragma unroll
  for (int i = 0; i < 4; ++i) {
    int cid = i * 256 + t, kb8 = (cid & 7) * 8;
    srow[i] = cid >> 3;
    int b0 = kb8, b1 = kb8 + 4;
    sp0[i] = (b0 & 32) + ((b0 & 12) << 1) + (((b0 >> 4) & 1) << 2) + (b0 & 3);
    sp1[i] = (b1 & 32) + ((b1 & 12) << 1) + (((b1 >> 4) & 1) << 2) + (b1 & 3);
  }
  f32x4 acc[4][4] = {};
  bfx8 ra[4], rb[4];
  auto gload = [&](int k0) {
    #pragma unroll
    for (int i = 0; i < 4; ++i) {
      int kc8 = ((i * 256 + t) & 7) * 8;
      ra[i] = *(const bfx8*)&A[(size_t)(m0 + srow[i]) * K + k0 + kc8];
      rb[i] = *(const bfx8*)&Bt[(size_t)(n0 + srow[i]) * K + k0 + kc8];
    }
  };
  gload(0);
  for (int k0 = 0; k0 < K; k0 += 64) {
    __syncthreads();
    #pragma unroll
    for (int i = 0; i < 4; ++i) {
      *(bfx4*)&As[srow[i]][sp0[i]] = __builtin_shufflevector(ra[i], ra[i], 0, 1, 2, 3);
      *(bfx4*)&As[srow[i]][sp1[i]] = __builtin_shufflevector(ra[i], ra[i], 4, 5, 6, 7);
      *(bfx4*)&Bs[srow[i]][sp0[i]] = __builtin_shufflevector(rb[i], rb[i], 0, 1, 2, 3);
      *(bfx4*)&Bs[srow[i]][sp1[i]] = __builtin_shufflevector(rb[i], rb[i], 4, 5, 6, 7);
    }
    __syncthreads();
    if (k0 + 64 < K) gload(k0 + 64);
    #pragma unroll
    for (int ks = 0; ks < 2; ++ks) {
      bfx8 af[4], bf[4];
      #pragma unroll
      for (int mi = 0; mi < 4; ++mi)
        af[mi] = *(const bfx8*)&As[wr * 64 + mi * 16 + lr][ks * 32 + kb * 2];
      #pragma unroll
      for (int ni = 0; ni < 4; ++ni)
        bf[ni] = *(const bfx8*)&Bs[wc * 64 + ni * 16 + lr][ks * 32 + kb * 2];
      #pragma unroll
      for (int mi = 0; mi < 4; ++mi)
        #pragma unroll
        for (int ni = 0; ni < 4; ++ni)
          acc[mi][ni] = __builtin_amdgcn_mfma_f32_16x16x32_bf16(af[mi], bf[ni],
                                                                acc[mi][ni], 0, 0, 0);
    }
  }
  if (EPI == 0 && vTout != nullptr && n0 >= 512) {
    #pragma unroll
    for (int mi = 0; mi < 4; ++mi)
      #pragma unroll
      for (int ni = 0; ni < 4; ++ni) {
        int n = n0 + wc * 64 + ni * 16 + lr;
        int cp = n - 512, hh = cp >> 5, dd = cp & 31;
        int m = m0 + wr * 64 + mi * 16 + kb;
        int bb_ = m >> 10, tok = m & 1023;
        bfx4 o;
        o[0] = (__bf16)acc[mi][ni][0]; o[1] = (__bf16)acc[mi][ni][1];
        o[2] = (__bf16)acc[mi][ni][2]; o[3] = (__bf16)acc[mi][ni][3];
        *(bfx4*)&vTout[(((size_t)bb_ * NHEAD + hh) * DHEAD + dd) * NTOK + tok] = o;
      }
    return;
  }
  #pragma unroll
  for (int mi = 0; mi < 4; ++mi)
    #pragma unroll
    for (int ni = 0; ni < 4; ++ni)
      #pragma unroll
      for (int r = 0; r < 4; ++r) {
        int m = m0 + wr * 64 + mi * 16 + kb + r;
        int n = n0 + wc * 64 + ni * 16 + lr;
        float v = acc[mi][ni][r];
        if (EPI == 0) {
          ((__bf16*)outp)[(size_t)m * Nn + n] = (__bf16)v;
        } else if (EPI == 2) {
          v += bias[n];
          v = 0.5f * v * (1.0f + erff(v * 0.70710678118f));
          ((__bf16*)outp)[(size_t)m * Nn + n] = (__bf16)v;
        }
      }
}

// ---- Wo GEMM (BM=32, BN=256 full width, 256 thr) + bias + resid + LN2 ------
// 4 waves, each owns a 64-col strip (acc[2][4]); LDS 39.2 KB -> 4 blocks/CU.
__launch_bounds__(256)
__global__ void gemmWoLn_kernel(const __bf16* __restrict__ A, const __bf16* __restrict__ Bt,
                                const float* __restrict__ bias,
                                const __bf16* __restrict__ residb,
                                const float* __restrict__ g2, const float* __restrict__ b2v,
                                __bf16* __restrict__ t2, __bf16* __restrict__ hln) {
  __shared__ char smem[41472];
  __bf16 (*As)[72] = (__bf16(*)[72])smem;             // 32 x 72 (4.6 KB)
  __bf16 (*Bs)[72] = (__bf16(*)[72])(smem + 4608);    // 256 x 72 (36.9 KB)
  const int t = threadIdx.x, lane = t & 63, w = t >> 6;   // 4 waves
  const int m0 = blockIdx.x * 32;
  const int lr = lane & 15, kb = (lane >> 4) * 4;
  const int K = 256;
  const int arow = t >> 3, ac8 = (t & 7) * 8;             // A: 32 rows x 64
  int ap0, ap1;
  {
    int b0 = ac8, b1 = ac8 + 4;
    ap0 = (b0 & 32) + ((b0 & 12) << 1) + (((b0 >> 4) & 1) << 2) + (b0 & 3);
    ap1 = (b1 & 32) + ((b1 & 12) << 1) + (((b1 >> 4) & 1) << 2) + (b1 & 3);
  }
  int brow[8], bp0[8], bp1[8], bc8[8];
  #pragma unroll
  for (int j = 0; j < 8; ++j) {
    int cid = j * 256 + t;
    brow[j] = cid >> 3;
    bc8[j] = (cid & 7) * 8;
    int b0 = bc8[j], b1 = bc8[j] + 4;
    bp0[j] = (b0 & 32) + ((b0 & 12) << 1) + (((b0 >> 4) & 1) << 2) + (b0 & 3);
    bp1[j] = (b1 & 32) + ((b1 & 12) << 1) + (((b1 >> 4) & 1) << 2) + (b1 & 3);
  }
  f32x4 acc[2][4] = {};
  bfx8 ra, rb[8];
  auto gload = [&](int k0) {
    ra = *(const bfx8*)&A[(size_t)(m0 + arow) * K + k0 + ac8];
    #pragma unroll
    for (int j = 0; j < 8; ++j)
      rb[j] = *(const bfx8*)&Bt[(size_t)brow[j] * K + k0 + bc8[j]];
  };
  gload(0);
  for (int k0 = 0; k0 < K; k0 += 64) {
    __syncthreads();
    *(bfx4*)&As[arow][ap0] = __builtin_shufflevector(ra, ra, 0, 1, 2, 3);
    *(bfx4*)&As[arow][ap1] = __builtin_shufflevector(ra, ra, 4, 5, 6, 7);
    #pragma unroll
    for (int j = 0; j < 8; ++j) {
      *(bfx4*)&Bs[brow[j]][bp0[j]] = __builtin_shufflevector(rb[j], rb[j], 0, 1, 2, 3);
      *(bfx4*)&Bs[brow[j]][bp1[j]] = __builtin_shufflevector(rb[j], rb[j], 4, 5, 6, 7);
    }
    __syncthreads();
    if (k0 + 64 < K) gload(k0 + 64);
    #pragma unroll
    for (int ks = 0; ks < 2; ++ks) {
      bfx8 af[2], bf[4];
      #pragma unroll
      for (int mi = 0; mi < 2; ++mi)
        af[mi] = *(const bfx8*)&As[mi * 16 + lr][ks * 32 + kb * 2];
      #pragma unroll
      for (int ni = 0; ni < 4; ++ni)
        bf[ni] = *(const bfx8*)&Bs[w * 64 + ni * 16 + lr][ks * 32 + kb * 2];
      #pragma unroll
      for (int mi = 0; mi < 2; ++mi)
        #pragma unroll
        for (int ni = 0; ni < 4; ++ni)
          acc[mi][ni] = __builtin_amdgcn_mfma_f32_16x16x32_bf16(af[mi], bf[ni],
                                                                acc[mi][ni], 0, 0, 0);
    }
  }
  // epilogue: v = acc + bias + resid; fused LN2 row stats over 256 channels
  float colg[4], colb[4];
  #pragma unroll
  for (int ni = 0; ni < 4; ++ni) {
    int colq = w * 64 + ni * 16 + lr;
    float bn = bias[colq];
    colg[ni] = g2[colq];
    colb[ni] = b2v[colq];
    #pragma unroll
    for (int mi = 0; mi < 2; ++mi)
      #pragma unroll
      for (int r = 0; r < 4; ++r) {
        int m = m0 + mi * 16 + kb + r;
        acc[mi][ni][r] += bn + (float)residb[(size_t)m * CDIM + colq];
      }
  }
  float ps[2][4], pq[2][4];
  #pragma unroll
  for (int mi = 0; mi < 2; ++mi)
    #pragma unroll
    for (int r = 0; r < 4; ++r) {
      float s = 0.f, q = 0.f;
      #pragma unroll
      for (int ni = 0; ni < 4; ++ni) {
        float v = acc[mi][ni][r];
        s += v; q += v * v;
      }
      #pragma unroll
      for (int o = 1; o < 16; o <<= 1) { s += __shfl_xor(s, o); q += __shfl_xor(q, o); }
      ps[mi][r] = s; pq[mi][r] = q;
    }
  __syncthreads();                        // As/Bs reads complete; reuse as red
  float* red = (float*)smem;              // [32][8]: sum[w], sq[4+w]
  if (lr == 0) {
    #pragma unroll
    for (int mi = 0; mi < 2; ++mi)
      #pragma unroll
      for (int r = 0; r < 4; ++r) {
        int rl = mi * 16 + kb + r;
        red[rl * 8 + w] = ps[mi][r];
        red[rl * 8 + 4 + w] = pq[mi][r];
      }
  }
  __syncthreads();
  if (t < 32) {
    float s = red[t * 8] + red[t * 8 + 1] + red[t * 8 + 2] + red[t * 8 + 3];
    float q = red[t * 8 + 4] + red[t * 8 + 5] + red[t * 8 + 6] + red[t * 8 + 7];
    float mu = s * 0.00390625f;
    float var = q * 0.00390625f - mu * mu;
    red[t * 8] = mu;
    red[t * 8 + 1] = rsqrtf(var + 1e-5f);
  }
  __syncthreads();
  #pragma unroll
  for (int mi = 0; mi < 2; ++mi)
    #pragma unroll
    for (int r = 0; r < 4; ++r) {
      int rl = mi * 16 + kb + r;
      float mu = red[rl * 8], rs = red[rl * 8 + 1];
      size_t rowoff = (size_t)(m0 + rl) * CDIM;
      #pragma unroll
      for (int ni = 0; ni < 4; ++ni) {
        int colq = w * 64 + ni * 16 + lr;
        float v = acc[mi][ni][r];
        t2[rowoff + colq] = (__bf16)v;
        hln[rowoff + colq] = (__bf16)((v - mu) * rs * colg[ni] + colb[ni]);
      }
    }
}

// ---- W2 GEMM (BM=64, BN=256, K=512) + bias + resid, TRANSPOSED fp32 out ----
__launch_bounds__(512)
__global__ void gemmW2T_kernel(const __bf16* __restrict__ A, const __bf16* __restrict__ Bt,
                               const float* __restrict__ bias,
                               const __bf16* __restrict__ residb,
                               float* __restrict__ outp) {
  __shared__ char smem[46080];
  __bf16 (*As)[72] = (__bf16(*)[72])smem;             // 64 x 72
  __bf16 (*Bs)[72] = (__bf16(*)[72])(smem + 9216);    // 256 x 72
  const int t = threadIdx.x, lane = t & 63, w = t >> 6;
  const int m0 = blockIdx.x * 64;
  const int wr = w >> 2, wc = w & 3;
  const int lr = lane & 15, kb = (lane >> 4) * 4;
  const int K = 512;
  const int arow = t >> 3, ac8 = (t & 7) * 8;
  int ap0, ap1;
  {
    int b0 = ac8, b1 = ac8 + 4;
    ap0 = (b0 & 32) + ((b0 & 12) << 1) + (((b0 >> 4) & 1) << 2) + (b0 & 3);
    ap1 = (b1 & 32) + ((b1 & 12) << 1) + (((b1 >> 4) & 1) << 2) + (b1 & 3);
  }
  int brow[4], bp0[4], bp1[4], bc8[4];
  #pragma unroll
  for (int j = 0; j < 4; ++j) {
    int cid = j * 512 + t;
    brow[j] = cid >> 3;
    bc8[j] = (cid & 7) * 8;
    int b0 = bc8[j], b1 = bc8[j] + 4;
    bp0[j] = (b0 & 32) + ((b0 & 12) << 1) + (((b0 >> 4) & 1) << 2) + (b0 & 3);
    bp1[j] = (b1 & 32) + ((b1 & 12) << 1) + (((b1 >> 4) & 1) << 2) + (b1 & 3);
  }
  f32x4 acc[2][4] = {};
  bfx8 ra, rb[4];
  auto gload = [&](int k0) {
    ra = *(const bfx8*)&A[(size_t)(m0 + arow) * K + k0 + ac8];
    #pragma unroll
    for (int j = 0; j < 4; ++j)
      rb[j] = *(const bfx8*)&Bt[(size_t)brow[j] * K + k0 + bc8[j]];
  };
  gload(0);
  for (int k0 = 0; k0 < K; k0 += 64) {
    __syncthreads();
    *(bfx4*)&As[arow][ap0] = __builtin_shufflevector(ra, ra, 0, 1, 2, 3);
    *(bfx4*)&As[arow][ap1] = __builtin_shufflevector(ra, ra, 4, 5, 6, 7);
    #pragma unroll
    for (int j = 0; j < 4; ++j) {
      *(bfx4*)&Bs[brow[j]][bp0[j]] = __builtin_shufflevector(rb[j], rb[j], 0, 1, 2, 3);
      *(bfx4*)&Bs[brow[j]][bp1[j]] = __builtin_shufflevector(rb[j], rb[j], 4, 5, 6, 7);
    }
    __syncthreads();
    if (k0 + 64 < K) gload(k0 + 64);
    #pragma unroll
    for (int ks = 0; ks < 2; ++ks) {
      bfx8 af[2], bf[4];
      #pragma unroll
      for (int mi = 0; mi < 2; ++mi)
        af[mi] = *(const bfx8*)&As[wr * 32 + mi * 16 + lr][ks * 32 + kb * 2];
      #pragma unroll
      for (int ni = 0; ni < 4; ++ni)
        bf[ni] = *(const bfx8*)&Bs[wc * 64 + ni * 16 + lr][ks * 32 + kb * 2];
      #pragma unroll
      for (int mi = 0; mi < 2; ++mi)
        #pragma unroll
        for (int ni = 0; ni < 4; ++ni)
          acc[mi][ni] = __builtin_amdgcn_mfma_f32_16x16x32_bf16(af[mi], bf[ni],
                                                                acc[mi][ni], 0, 0, 0);
    }
  }
  const int bb_ = m0 >> 10, tok0 = m0 & 1023;
  float* obase = outp + (size_t)bb_ * CDIM * NTOK + tok0;
  float* Ty = (float*)smem;
  #pragma unroll
  for (int h2 = 0; h2 < 2; ++h2) {
    __syncthreads();
    if ((wc >> 1) == h2) {
      #pragma unroll
      for (int ni = 0; ni < 4; ++ni) {
        int colq = wc * 64 + ni * 16 + lr;
        int chl = colq - h2 * 128;
        float bn = bias[colq];
        #pragma unroll
        for (int mi = 0; mi < 2; ++mi) {
          int tk = wr * 32 + mi * 16 + kb;
          float4 v4;
          #pragma unroll
          for (int r = 0; r < 4; ++r)
            ((float*)&v4)[r] = acc[mi][ni][r] + bn +
                (float)residb[(size_t)(m0 + tk + r) * CDIM + colq];
          *(float4*)&Ty[chl * 68 + tk] = v4;
        }
      }
    }
    __syncthreads();
    int row = t >> 2, quad = t & 3;
    #pragma unroll
    for (int j = 0; j < 4; ++j) {
      int p = quad + j * 4;
      *(float4*)&obase[(size_t)(h2 * 128 + row) * NTOK + p * 4] =
          *(const float4*)&Ty[row * 68 + p * 4];
    }
  }
}

// -------- flash attention, QBLK=256, 8 waves (32 q-rows/wave) — R13 exact ---
__launch_bounds__(512)
__global__ void attn_kernel(const __bf16* __restrict__ qkv, const __bf16* __restrict__ vT,
                            const __bf16* __restrict__ biasB, __bf16* __restrict__ outb) {
  __shared__ __bf16 Ks[64][40];
  __shared__ __bf16 Vs[32][72];
  __shared__ __bf16 Bls[256][72];
  const int q0 = blockIdx.x * 256, h = blockIdx.y, b = blockIdx.z;
  const int t = threadIdx.x, lane = t & 63, w = t >> 6;     // 8 waves
  const int lr = lane & 15, kb = (lane >> 4) * 4;
  const size_t qbase = (size_t)b * NTOK * QKVD;
  const float qsc = SCALE * LOG2E;
  bfx8 qf[2];
  #pragma unroll
  for (int tq = 0; tq < 2; ++tq) {
    const __bf16* qp = &qkv[qbase + (size_t)(q0 + 32 * w + 16 * tq + lr) * QKVD + h * DHEAD];
    bfx4 lo = *(const bfx4*)&qp[kb];
    bfx4 hi = *(const bfx4*)&qp[kb + 16];
    #pragma unroll
    for (int j = 0; j < 4; ++j) {
      qf[tq][j]     = (__bf16)((float)lo[j] * qsc);
      qf[tq][j + 4] = (__bf16)((float)hi[j] * qsc);
    }
  }
  float l_run[2] = {0.f, 0.f};
  f32x4 oacc[2][2] = {};
  const int st_ = t & 255;
  const int krow = st_ >> 2, kc8 = (st_ & 3) * 8;   // K stage (t<256): 64x32
  const int vrow = st_ >> 3, vc8 = (st_ & 7) * 8;   // V stage (t>=256): 32x64
  const __bf16* kvptr = (t < 256)
      ? &qkv[qbase + (size_t)krow * QKVD + INNER + h * DHEAD + kc8]
      : &vT[(((size_t)b * NHEAD + h) * DHEAD + vrow) * NTOK + vc8];
  const __bf16* bbase = &biasB[((size_t)h * NTOK + q0) * NTOK];
  bfx8 rkv, rbias[4];
  auto issue = [&](int k0) {
    rkv = (t < 256) ? *(const bfx8*)&kvptr[(size_t)k0 * QKVD]
                    : *(const bfx8*)&kvptr[k0];
    #pragma unroll
    for (int j = 0; j < 4; ++j) {
      int lin = j * 512 + t;                  // 2048 chunks: 256 rows x 128B
      int br = lin >> 3, bc8 = (lin & 7) * 8;
      rbias[j] = *(const bfx8*)&bbase[(size_t)br * NTOK + k0 + bc8];
    }
  };
  issue(0);
  for (int kt = 0; kt < 16; ++kt) {
    __syncthreads();
    if (t < 256) *(bfx8*)&Ks[krow][kc8] = rkv;
    else         *(bfx8*)&Vs[vrow][vc8] = rkv;
    #pragma unroll
    for (int j = 0; j < 4; ++j) {
      int lin = j * 512 + t;
      int br = lin >> 3, bc8 = (lin & 7) * 8;
      *(bfx8*)&Bls[br][bc8] = rbias[j];
    }
    __syncthreads();
    if (kt < 15) issue((kt + 1) * 64);
    bfx8 kf[4], vfr[4];
    #pragma unroll
    for (int f = 0; f < 4; ++f) {
      bfx4 klo = *(const bfx4*)&Ks[16 * f + lr][kb];
      bfx4 khi = *(const bfx4*)&Ks[16 * f + lr][kb + 16];
      kf[f] = __builtin_shufflevector(klo, khi, 0, 1, 2, 3, 4, 5, 6, 7);
    }
    #pragma unroll
    for (int s = 0; s < 2; ++s)
      #pragma unroll
      for (int df = 0; df < 2; ++df) {
        bfx4 vlo = *(const bfx4*)&Vs[16 * df + lr][s * 32 + kb];
        bfx4 vhi = *(const bfx4*)&Vs[16 * df + lr][s * 32 + kb + 16];
        vfr[s * 2 + df] = __builtin_shufflevector(vlo, vhi, 0, 1, 2, 3, 4, 5, 6, 7);
      }
    #pragma unroll
    for (int tq = 0; tq < 2; ++tq) {
      const int qrow_l = 32 * w + 16 * tq + lr;
      f32x4 st[4];
      #pragma unroll
      for (int f = 0; f < 4; ++f) {
        bfx4 bv = *(const bfx4*)&Bls[qrow_l][16 * f + kb];
        f32x4 c;
        c[0] = (float)bv[0]; c[1] = (float)bv[1];
        c[2] = (float)bv[2]; c[3] = (float)bv[3];
        st[f] = __builtin_amdgcn_mfma_f32_16x16x32_bf16(kf[f], qf[tq], c, 0, 0, 0);
      }
      float p[4][4], tsum = 0.f;
      #pragma unroll
      for (int f = 0; f < 4; ++f)
        #pragma unroll
        for (int r = 0; r < 4; ++r) {
          float e = EXP2(st[f][r]);
          p[f][r] = e;
          tsum += e;
        }
      l_run[tq] += tsum;
      bfx8 pa0, pa1;
      #pragma unroll
      for (int r = 0; r < 4; ++r) {
        pa0[r] = (__bf16)p[0][r];  pa0[r + 4] = (__bf16)p[1][r];
        pa1[r] = (__bf16)p[2][r];  pa1[r + 4] = (__bf16)p[3][r];
      }
      #pragma unroll
      for (int s = 0; s < 2; ++s) {
        bfx8 pa = s ? pa1 : pa0;
        #pragma unroll
        for (int df = 0; df < 2; ++df)
          oacc[tq][df] = __builtin_amdgcn_mfma_f32_16x16x32_bf16(pa, vfr[s * 2 + df],
                                                                 oacc[tq][df], 0, 0, 0);
      }
    }
  }
  #pragma unroll
  for (int tq = 0; tq < 2; ++tq) {
    float l = l_run[tq];
    l += __shfl_xor(l, 16);
    l += __shfl_xor(l, 32);
    float il[4];
    #pragma unroll
    for (int r = 0; r < 4; ++r) il[r] = 1.f / __shfl(l, kb + r);
    #pragma unroll
    for (int r = 0; r < 4; ++r) {
      size_t rowoff = (size_t)b * NTOK * CDIM +
                      (size_t)(q0 + 32 * w + 16 * tq + kb + r) * CDIM + h * DHEAD;
      outb[rowoff + lr]      = (__bf16)(oacc[tq][0][r] * il[r]);
      outb[rowoff + 16 + lr] = (__bf16)(oacc[tq][1][r] * il[r]);
    }
  }
}

// ---------------------------------------------------------------------------
extern "C" void kernel_launch(void* const* d_in, const int* in_sizes, int n_in,
                              void* d_out, int out_size, void* d_ws, size_t ws_size,
                              hipStream_t stream) {
  const float* x     = (const float*)d_in[0];
  const float* ln1_g = (const float*)d_in[2];
  const float* ln1_b = (const float*)d_in[3];
  const float* Wqkv  = (const float*)d_in[4];
  const float* table = (const float*)d_in[5];
  const float* Wo    = (const float*)d_in[6];
  const float* bo    = (const float*)d_in[7];
  const float* ln2_g = (const float*)d_in[8];
  const float* ln2_b = (const float*)d_in[9];
  const float* W1    = (const float*)d_in[10];
  const float* b1    = (const float*)d_in[11];
  const float* W2    = (const float*)d_in[12];
  const float* b2    = (const float*)d_in[13];

  char* ws = (char*)d_ws;
  __bf16* t_bf  = (__bf16*)(ws + 0);          // 8 MB residual 1 (bf16)
  __bf16* t2_bf = (__bf16*)(ws + 8388608);    // 8 MB residual 2 (bf16)
  __bf16* qkv   = (__bf16*)(ws + 33554432);   // 24 MB
  __bf16* hln   = (__bf16*)(ws + 58720256);   // 8 MB (ln1 out, reused for ln2)
  __bf16* aout  = (__bf16*)(ws + 67108864);   // 8 MB
  __bf16* hid   = (__bf16*)(ws + 75497472);   // 16 MB (aliased: vT during attention)
  __bf16* vT    = (__bf16*)(ws + 75497472);   // 8.4 MB, dead before hid is written
  __bf16* biasB = (__bf16*)(ws + 92274688);   // 16 MB
  __bf16* Wqkvt = (__bf16*)(ws + 109051904);
  __bf16* Wot   = (__bf16*)(ws + 109445120);
  __bf16* W1t   = (__bf16*)(ws + 109576192);
  __bf16* W2t   = (__bf16*)(ws + 109838336);  // ends 110100480
  if (ws_size < 110100480) return;            // visible failure instead of OOB

  prep_kernel<<<6144, 256, 0, stream>>>(Wqkv, Wo, W1, W2, Wqkvt, Wot, W1t, W2t,
                                        table, biasB);
  txln_kernel<<<dim3(32, 1, 16), 256, 0, stream>>>(x, ln1_g, ln1_b, t_bf, hln);
  gemm128_kernel<0><<<dim3(128, 6), 256, 0, stream>>>(hln, Wqkvt, nullptr, nullptr, qkv, vT, 768, 256);
  attn_kernel<<<dim3(4, 8, 16), 512, 0, stream>>>(qkv, vT, biasB, aout);
  gemmWoLn_kernel<<<512, 256, 0, stream>>>(aout, Wot, bo, t_bf, ln2_g, ln2_b, t2_bf, hln);
  gemm128_kernel<2><<<dim3(128, 4), 256, 0, stream>>>(hln, W1t, b1, nullptr, hid, nullptr, 512, 256);
  gemmW2T_kernel<<<256, 512, 0, stream>>>(hid, W2t, b2, t2_bf, (float*)d_out);
}

// Round 27
// 124.409 us; speedup vs baseline: 1.1267x; 1.0127x over previous
//
#include <hip/hip_runtime.h>
#include <hip/hip_bf16.h>
#include <math.h>

typedef __bf16 bfx4 __attribute__((ext_vector_type(4)));
typedef __bf16 bfx8 __attribute__((ext_vector_type(8)));
typedef float  f32x4 __attribute__((ext_vector_type(4)));

#define BATCH 16
#define NTOK  1024
#define CDIM  256
#define NHEAD 8
#define DHEAD 32
#define QKVD  768
#define INNER 256
#define SCALE 0.17677669529663687f
#define LOG2E 1.4426950408889634f

#if __has_builtin(__builtin_amdgcn_exp2f)
#define EXP2(x) __builtin_amdgcn_exp2f(x)
#else
#define EXP2(x) exp2f(x)
#endif

// ------- fused transpose + LN1: x[B][C][N] -> t_bf bf16 [tok][C], hln bf16 --
__launch_bounds__(256)
__global__ void txln_kernel(const float* __restrict__ x, const float* __restrict__ g,
                            const float* __restrict__ bb, __bf16* __restrict__ tb,
                            __bf16* __restrict__ hln) {
  __shared__ float tile[256][33];
  const int b = blockIdx.z, n0 = blockIdx.x * 32;
  const int tt = threadIdx.x;
  const float* src = x + (size_t)b * CDIM * NTOK;
  #pragma unroll
  for (int i = 0; i < 8; ++i) {
    int cid = i * 256 + tt;
    int c = cid >> 3, col4 = (cid & 7) * 4;
    *(float4*)&tile[c][col4] = *(const float4*)&src[(size_t)c * NTOK + n0 + col4];
  }
  __syncthreads();
  const int n = tt >> 3, c0 = (tt & 7) * 32;   // 8 threads per token
  float vals[32];
  float s = 0.f, s2 = 0.f;
  #pragma unroll
  for (int j = 0; j < 32; ++j) {
    float v = tile[c0 + j][n];
    vals[j] = v; s += v; s2 += v * v;
  }
  s  += __shfl_xor(s, 1);  s  += __shfl_xor(s, 2);  s  += __shfl_xor(s, 4);
  s2 += __shfl_xor(s2, 1); s2 += __shfl_xor(s2, 2); s2 += __shfl_xor(s2, 4);
  float mu = s * 0.00390625f;
  float var = s2 * 0.00390625f - mu * mu;
  float rs = rsqrtf(var + 1e-5f);
  size_t row = ((size_t)b * NTOK + n0 + n) * CDIM;
  #pragma unroll
  for (int j = 0; j < 32; j += 4) {
    const float4 gg = *(const float4*)&g[c0 + j];
    const float4 bv = *(const float4*)&bb[c0 + j];
    bfx4 tv;
    tv[0] = (__bf16)vals[j];     tv[1] = (__bf16)vals[j + 1];
    tv[2] = (__bf16)vals[j + 2]; tv[3] = (__bf16)vals[j + 3];
    *(bfx4*)&tb[row + c0 + j] = tv;
    bfx4 o;
    o[0] = (__bf16)((vals[j]     - mu) * rs * gg.x + bv.x);
    o[1] = (__bf16)((vals[j + 1] - mu) * rs * gg.y + bv.y);
    o[2] = (__bf16)((vals[j + 2] - mu) * rs * gg.z + bv.z);
    o[3] = (__bf16)((vals[j + 3] - mu) * rs * gg.w + bv.w);
    *(bfx4*)&hln[row + c0 + j] = o;
  }
}

// ---- merged prep: weight transpose+cast (blocks 0..2047) + bias (2048..6143)
__launch_bounds__(256)
__global__ void prep_kernel(const float* __restrict__ Wqkv, const float* __restrict__ Wo,
                            const float* __restrict__ W1, const float* __restrict__ W2,
                            __bf16* __restrict__ Wqkvt, __bf16* __restrict__ Wot,
                            __bf16* __restrict__ W1t, __bf16* __restrict__ W2t,
                            const float* __restrict__ table, __bf16* __restrict__ biasB) {
  if (blockIdx.x < 2048) {
    int idx = blockIdx.x * 256 + threadIdx.x;
    const float* W; __bf16* Wt; int lk, Nn, off;
    if (idx < 196608)      { W = Wqkv; Wt = Wqkvt; lk = 8; Nn = 768; off = idx; }
    else if (idx < 262144) { W = Wo;   Wt = Wot;   lk = 8; Nn = 256; off = idx - 196608; }
    else if (idx < 393216) { W = W1;   Wt = W1t;   lk = 8; Nn = 512; off = idx - 262144; }
    else                   { W = W2;   Wt = W2t;   lk = 9; Nn = 256; off = idx - 393216; }
    int n = off >> lk, k = off & ((1 << lk) - 1);
    Wt[off] = (__bf16)W[(size_t)k * Nn + n];
  } else {
    int idx = (blockIdx.x - 2048) * 256 + threadIdx.x;   // h*2^17 + q*2^7 + k8
    int k8 = (idx & 127) * 8, q = (idx >> 7) & 1023, h = idx >> 17;
    int qi = q >> 5, qj = q & 31;
    bfx8 o;
    #pragma unroll
    for (int j = 0; j < 8; ++j) {
      int k = k8 + j, ki = k >> 5, kj = k & 31;
      int r = (qi - ki + 31) * 63 + (qj - kj + 31);
      o[j] = (__bf16)(table[r * 8 + h] * LOG2E);
    }
    *(bfx8*)&biasB[((size_t)idx) * 8] = o;
  }
}

// ---------------- GEMM 128x128 tile, BK=64, k-permuted LDS (R13) ------------
// EPI 0: store bf16 (qkv: if vTout && n0>=512, scatter V into vT instead).
template <int EPI>
__launch_bounds__(256)
__global__ void gemm128_kernel(const __bf16* __restrict__ A, const __bf16* __restrict__ Bt,
                               const float* __restrict__ bias,
                               const __bf16* __restrict__ residb,
                               void* __restrict__ outp, __bf16* __restrict__ vTout,
                               int Nn, int K) {
  __shared__ char smem[36864];
  __bf16 (*As)[72] = (__bf16(*)[72])smem;
  __bf16 (*Bs)[72] = (__bf16(*)[72])(smem + 18432);
  const int t = threadIdx.x, lane = t & 63, w = t >> 6;
  const int m0 = blockIdx.x * 128, n0 = blockIdx.y * 128;
  const int wr = w >> 1, wc = w & 1;
  const int lr = lane & 15, kb = (lane >> 4) * 4;
  int srow[4], sp0[4], sp1[4];
  #pragma unroll
  for (int i = 0; i < 4; ++i) {
    int cid = i * 256 + t, kb8 = (cid & 7) * 8;
    srow[i] = cid >> 3;
    int b0 = kb8, b1 = kb8 + 4;
    sp0[i] = (b0 & 32) + ((b0 & 12) << 1) + (((b0 >> 4) & 1) << 2) + (b0 & 3);
    sp1[i] = (b1 & 32) + ((b1 & 12) << 1) + (((b1 >> 4) & 1) << 2) + (b1 & 3);
  }
  f32x4 acc[4][4] = {};
  bfx8 ra[4], rb[4];
  auto gload = [&](int k0) {
    #pragma unroll
    for (int i = 0; i < 4; ++i) {
      int kc8 = ((i * 256 + t) & 7) * 8;
      ra[i] = *(const bfx8*)&A[(size_t)(m0 + srow[i]) * K + k0 + kc8];
      rb[i] = *(const bfx8*)&Bt[(size_t)(n0 + srow[i]) * K + k0 + kc8];
    }
  };
  gload(0);
  for (int k0 = 0; k0 < K; k0 += 64) {
    __syncthreads();
    #pragma unroll
    for (int i = 0; i < 4; ++i) {
      *(bfx4*)&As[srow[i]][sp0[i]] = __builtin_shufflevector(ra[i], ra[i], 0, 1, 2, 3);
      *(bfx4*)&As[srow[i]][sp1[i]] = __builtin_shufflevector(ra[i], ra[i], 4, 5, 6, 7);
      *(bfx4*)&Bs[srow[i]][sp0[i]] = __builtin_shufflevector(rb[i], rb[i], 0, 1, 2, 3);
      *(bfx4*)&Bs[srow[i]][sp1[i]] = __builtin_shufflevector(rb[i], rb[i], 4, 5, 6, 7);
    }
    __syncthreads();
    if (k0 + 64 < K) gload(k0 + 64);
    #pragma unroll
    for (int ks = 0; ks < 2; ++ks) {
      bfx8 af[4], bf[4];
      #pragma unroll
      for (int mi = 0; mi < 4; ++mi)
        af[mi] = *(const bfx8*)&As[wr * 64 + mi * 16 + lr][ks * 32 + kb * 2];
      #pragma unroll
      for (int ni = 0; ni < 4; ++ni)
        bf[ni] = *(const bfx8*)&Bs[wc * 64 + ni * 16 + lr][ks * 32 + kb * 2];
      #pragma unroll
      for (int mi = 0; mi < 4; ++mi)
        #pragma unroll
        for (int ni = 0; ni < 4; ++ni)
          acc[mi][ni] = __builtin_amdgcn_mfma_f32_16x16x32_bf16(af[mi], bf[ni],
                                                                acc[mi][ni], 0, 0, 0);
    }
  }
  if (EPI == 0 && vTout != nullptr && n0 >= 512) {
    #pragma unroll
    for (int mi = 0; mi < 4; ++mi)
      #pragma unroll
      for (int ni = 0; ni < 4; ++ni) {
        int n = n0 + wc * 64 + ni * 16 + lr;
        int cp = n - 512, hh = cp >> 5, dd = cp & 31;
        int m = m0 + wr * 64 + mi * 16 + kb;
        int bb_ = m >> 10, tok = m & 1023;
        bfx4 o;
        o[0] = (__bf16)acc[mi][ni][0]; o[1] = (__bf16)acc[mi][ni][1];
        o[2] = (__bf16)acc[mi][ni][2]; o[3] = (__bf16)acc[mi][ni][3];
        *(bfx4*)&vTout[(((size_t)bb_ * NHEAD + hh) * DHEAD + dd) * NTOK + tok] = o;
      }
    return;
  }
  #pragma unroll
  for (int mi = 0; mi < 4; ++mi)
    #pragma unroll
    for (int ni = 0; ni < 4; ++ni)
      #pragma unroll
      for (int r = 0; r < 4; ++r) {
        int m = m0 + wr * 64 + mi * 16 + kb + r;
        int n = n0 + wc * 64 + ni * 16 + lr;
        ((__bf16*)outp)[(size_t)m * Nn + n] = (__bf16)acc[mi][ni][r];
      }
}

// ---- W1 GEMM (BM=64, BN=128, 256 thr) + bias + GELU -> bf16 ----------------
// LDS 27.6 KB -> 4 blocks/CU at grid 1024 (16 waves/CU vs old 8).
__launch_bounds__(256)
__global__ void gemmW1G_kernel(const __bf16* __restrict__ A, const __bf16* __restrict__ Bt,
                               const float* __restrict__ bias, __bf16* __restrict__ outp) {
  __shared__ char smem[27648];
  __bf16 (*As)[72] = (__bf16(*)[72])smem;             // 64 x 72 (9.2 KB)
  __bf16 (*Bs)[72] = (__bf16(*)[72])(smem + 9216);    // 128 x 72 (18.4 KB)
  const int t = threadIdx.x, lane = t & 63, w = t >> 6;
  const int m0 = blockIdx.x * 64, n0 = blockIdx.y * 128;
  const int wr = w >> 1, wc = w & 1;
  const int lr = lane & 15, kb = (lane >> 4) * 4;
  const int K = 256, Nn = 512;
  int arow[2], ap0[2], ap1[2];
  #pragma unroll
  for (int i = 0; i < 2; ++i) {
    int cid = i * 256 + t, kb8 = (cid & 7) * 8;
    arow[i] = cid >> 3;
    int b0 = kb8, b1 = kb8 + 4;
    ap0[i] = (b0 & 32) + ((b0 & 12) << 1) + (((b0 >> 4) & 1) << 2) + (b0 & 3);
    ap1[i] = (b1 & 32) + ((b1 & 12) << 1) + (((b1 >> 4) & 1) << 2) + (b1 & 3);
  }
  int brow[4], bp0[4], bp1[4], bc8[4];
  #pragma unroll
  for (int j = 0; j < 4; ++j) {
    int cid = j * 256 + t;
    brow[j] = cid >> 3;
    bc8[j] = (cid & 7) * 8;
    int b0 = bc8[j], b1 = bc8[j] + 4;
    bp0[j] = (b0 & 32) + ((b0 & 12) << 1) + (((b0 >> 4) & 1) << 2) + (b0 & 3);
    bp1[j] = (b1 & 32) + ((b1 & 12) << 1) + (((b1 >> 4) & 1) << 2) + (b1 & 3);
  }
  f32x4 acc[2][4] = {};
  bfx8 ra[2], rb[4];
  auto gload = [&](int k0) {
    #pragma unroll
    for (int i = 0; i < 2; ++i) {
      int kc8 = ((i * 256 + t) & 7) * 8;
      ra[i] = *(const bfx8*)&A[(size_t)(m0 + arow[i]) * K + k0 + kc8];
    }
    #pragma unroll
    for (int j = 0; j < 4; ++j)
      rb[j] = *(const bfx8*)&Bt[(size_t)(n0 + brow[j]) * K + k0 + bc8[j]];
  };
  gload(0);
  for (int k0 = 0; k0 < K; k0 += 64) {
    __syncthreads();
    #pragma unroll
    for (int i = 0; i < 2; ++i) {
      *(bfx4*)&As[arow[i]][ap0[i]] = __builtin_shufflevector(ra[i], ra[i], 0, 1, 2, 3);
      *(bfx4*)&As[arow[i]][ap1[i]] = __builtin_shufflevector(ra[i], ra[i], 4, 5, 6, 7);
    }
    #pragma unroll
    for (int j = 0; j < 4; ++j) {
      *(bfx4*)&Bs[brow[j]][bp0[j]] = __builtin_shufflevector(rb[j], rb[j], 0, 1, 2, 3);
      *(bfx4*)&Bs[brow[j]][bp1[j]] = __builtin_shufflevector(rb[j], rb[j], 4, 5, 6, 7);
    }
    __syncthreads();
    if (k0 + 64 < K) gload(k0 + 64);
    #pragma unroll
    for (int ks = 0; ks < 2; ++ks) {
      bfx8 af[2], bf[4];
      #pragma unroll
      for (int mi = 0; mi < 2; ++mi)
        af[mi] = *(const bfx8*)&As[wr * 32 + mi * 16 + lr][ks * 32 + kb * 2];
      #pragma unroll
      for (int ni = 0; ni < 4; ++ni)
        bf[ni] = *(const bfx8*)&Bs[wc * 64 + ni * 16 + lr][ks * 32 + kb * 2];
      #pragma unroll
      for (int mi = 0; mi < 2; ++mi)
        #pragma unroll
        for (int ni = 0; ni < 4; ++ni)
          acc[mi][ni] = __builtin_amdgcn_mfma_f32_16x16x32_bf16(af[mi], bf[ni],
                                                                acc[mi][ni], 0, 0, 0);
    }
  }
  #pragma unroll
  for (int mi = 0; mi < 2; ++mi)
    #pragma unroll
    for (int ni = 0; ni < 4; ++ni) {
      int n = n0 + wc * 64 + ni * 16 + lr;
      float bn = bias[n];
      #pragma unroll
      for (int r = 0; r < 4; ++r) {
        int m = m0 + wr * 32 + mi * 16 + kb + r;
        float v = acc[mi][ni][r] + bn;
        v = 0.5f * v * (1.0f + erff(v * 0.70710678118f));
        outp[(size_t)m * Nn + n] = (__bf16)v;
      }
    }
}

// ---- Wo GEMM (BM=32, BN=256 full width, 256 thr) + bias + resid + LN2 ------
__launch_bounds__(256)
__global__ void gemmWoLn_kernel(const __bf16* __restrict__ A, const __bf16* __restrict__ Bt,
                                const float* __restrict__ bias,
                                const __bf16* __restrict__ residb,
                                const float* __restrict__ g2, const float* __restrict__ b2v,
                                __bf16* __restrict__ t2, __bf16* __restrict__ hln) {
  __shared__ char smem[41472];
  __bf16 (*As)[72] = (__bf16(*)[72])smem;             // 32 x 72 (4.6 KB)
  __bf16 (*Bs)[72] = (__bf16(*)[72])(smem + 4608);    // 256 x 72 (36.9 KB)
  const int t = threadIdx.x, lane = t & 63, w = t >> 6;   // 4 waves
  const int m0 = blockIdx.x * 32;
  const int lr = lane & 15, kb = (lane >> 4) * 4;
  const int K = 256;
  const int arow = t >> 3, ac8 = (t & 7) * 8;             // A: 32 rows x 64
  int ap0, ap1;
  {
    int b0 = ac8, b1 = ac8 + 4;
    ap0 = (b0 & 32) + ((b0 & 12) << 1) + (((b0 >> 4) & 1) << 2) + (b0 & 3);
    ap1 = (b1 & 32) + ((b1 & 12) << 1) + (((b1 >> 4) & 1) << 2) + (b1 & 3);
  }
  int brow[8], bp0[8], bp1[8], bc8[8];
  #pragma unroll
  for (int j = 0; j < 8; ++j) {
    int cid = j * 256 + t;
    brow[j] = cid >> 3;
    bc8[j] = (cid & 7) * 8;
    int b0 = bc8[j], b1 = bc8[j] + 4;
    bp0[j] = (b0 & 32) + ((b0 & 12) << 1) + (((b0 >> 4) & 1) << 2) + (b0 & 3);
    bp1[j] = (b1 & 32) + ((b1 & 12) << 1) + (((b1 >> 4) & 1) << 2) + (b1 & 3);
  }
  f32x4 acc[2][4] = {};
  bfx8 ra, rb[8];
  auto gload = [&](int k0) {
    ra = *(const bfx8*)&A[(size_t)(m0 + arow) * K + k0 + ac8];
    #pragma unroll
    for (int j = 0; j < 8; ++j)
      rb[j] = *(const bfx8*)&Bt[(size_t)brow[j] * K + k0 + bc8[j]];
  };
  gload(0);
  for (int k0 = 0; k0 < K; k0 += 64) {
    __syncthreads();
    *(bfx4*)&As[arow][ap0] = __builtin_shufflevector(ra, ra, 0, 1, 2, 3);
    *(bfx4*)&As[arow][ap1] = __builtin_shufflevector(ra, ra, 4, 5, 6, 7);
    #pragma unroll
    for (int j = 0; j < 8; ++j) {
      *(bfx4*)&Bs[brow[j]][bp0[j]] = __builtin_shufflevector(rb[j], rb[j], 0, 1, 2, 3);
      *(bfx4*)&Bs[brow[j]][bp1[j]] = __builtin_shufflevector(rb[j], rb[j], 4, 5, 6, 7);
    }
    __syncthreads();
    if (k0 + 64 < K) gload(k0 + 64);
    #pragma unroll
    for (int ks = 0; ks < 2; ++ks) {
      bfx8 af[2], bf[4];
      #pragma unroll
      for (int mi = 0; mi < 2; ++mi)
        af[mi] = *(const bfx8*)&As[mi * 16 + lr][ks * 32 + kb * 2];
      #pragma unroll
      for (int ni = 0; ni < 4; ++ni)
        bf[ni] = *(const bfx8*)&Bs[w * 64 + ni * 16 + lr][ks * 32 + kb * 2];
      #pragma unroll
      for (int mi = 0; mi < 2; ++mi)
        #pragma unroll
        for (int ni = 0; ni < 4; ++ni)
          acc[mi][ni] = __builtin_amdgcn_mfma_f32_16x16x32_bf16(af[mi], bf[ni],
                                                                acc[mi][ni], 0, 0, 0);
    }
  }
  float colg[4], colb[4];
  #pragma unroll
  for (int ni = 0; ni < 4; ++ni) {
    int colq = w * 64 + ni * 16 + lr;
    float bn = bias[colq];
    colg[ni] = g2[colq];
    colb[ni] = b2v[colq];
    #pragma unroll
    for (int mi = 0; mi < 2; ++mi)
      #pragma unroll
      for (int r = 0; r < 4; ++r) {
        int m = m0 + mi * 16 + kb + r;
        acc[mi][ni][r] += bn + (float)residb[(size_t)m * CDIM + colq];
      }
  }
  float ps[2][4], pq[2][4];
  #pragma unroll
  for (int mi = 0; mi < 2; ++mi)
    #pragma unroll
    for (int r = 0; r < 4; ++r) {
      float s = 0.f, q = 0.f;
      #pragma unroll
      for (int ni = 0; ni < 4; ++ni) {
        float v = acc[mi][ni][r];
        s += v; q += v * v;
      }
      #pragma unroll
      for (int o = 1; o < 16; o <<= 1) { s += __shfl_xor(s, o); q += __shfl_xor(q, o); }
      ps[mi][r] = s; pq[mi][r] = q;
    }
  __syncthreads();
  float* red = (float*)smem;              // [32][8]
  if (lr == 0) {
    #pragma unroll
    for (int mi = 0; mi < 2; ++mi)
      #pragma unroll
      for (int r = 0; r < 4; ++r) {
        int rl = mi * 16 + kb + r;
        red[rl * 8 + w] = ps[mi][r];
        red[rl * 8 + 4 + w] = pq[mi][r];
      }
  }
  __syncthreads();
  if (t < 32) {
    float s = red[t * 8] + red[t * 8 + 1] + red[t * 8 + 2] + red[t * 8 + 3];
    float q = red[t * 8 + 4] + red[t * 8 + 5] + red[t * 8 + 6] + red[t * 8 + 7];
    float mu = s * 0.00390625f;
    float var = q * 0.00390625f - mu * mu;
    red[t * 8] = mu;
    red[t * 8 + 1] = rsqrtf(var + 1e-5f);
  }
  __syncthreads();
  #pragma unroll
  for (int mi = 0; mi < 2; ++mi)
    #pragma unroll
    for (int r = 0; r < 4; ++r) {
      int rl = mi * 16 + kb + r;
      float mu = red[rl * 8], rs = red[rl * 8 + 1];
      size_t rowoff = (size_t)(m0 + rl) * CDIM;
      #pragma unroll
      for (int ni = 0; ni < 4; ++ni) {
        int colq = w * 64 + ni * 16 + lr;
        float v = acc[mi][ni][r];
        t2[rowoff + colq] = (__bf16)v;
        hln[rowoff + colq] = (__bf16)((v - mu) * rs * colg[ni] + colb[ni]);
      }
    }
}

// ---- W2 GEMM (BM=64, BN=256, K=512) + bias + resid, TRANSPOSED fp32 out ----
__launch_bounds__(512)
__global__ void gemmW2T_kernel(const __bf16* __restrict__ A, const __bf16* __restrict__ Bt,
                               const float* __restrict__ bias,
                               const __bf16* __restrict__ residb,
                               float* __restrict__ outp) {
  __shared__ char smem[46080];
  __bf16 (*As)[72] = (__bf16(*)[72])smem;             // 64 x 72
  __bf16 (*Bs)[72] = (__bf16(*)[72])(smem + 9216);    // 256 x 72
  const int t = threadIdx.x, lane = t & 63, w = t >> 6;
  const int m0 = blockIdx.x * 64;
  const int wr = w >> 2, wc = w & 3;
  const int lr = lane & 15, kb = (lane >> 4) * 4;
  const int K = 512;
  const int arow = t >> 3, ac8 = (t & 7) * 8;
  int ap0, ap1;
  {
    int b0 = ac8, b1 = ac8 + 4;
    ap0 = (b0 & 32) + ((b0 & 12) << 1) + (((b0 >> 4) & 1) << 2) + (b0 & 3);
    ap1 = (b1 & 32) + ((b1 & 12) << 1) + (((b1 >> 4) & 1) << 2) + (b1 & 3);
  }
  int brow[4], bp0[4], bp1[4], bc8[4];
  #pragma unroll
  for (int j = 0; j < 4; ++j) {
    int cid = j * 512 + t;
    brow[j] = cid >> 3;
    bc8[j] = (cid & 7) * 8;
    int b0 = bc8[j], b1 = bc8[j] + 4;
    bp0[j] = (b0 & 32) + ((b0 & 12) << 1) + (((b0 >> 4) & 1) << 2) + (b0 & 3);
    bp1[j] = (b1 & 32) + ((b1 & 12) << 1) + (((b1 >> 4) & 1) << 2) + (b1 & 3);
  }
  f32x4 acc[2][4] = {};
  bfx8 ra, rb[4];
  auto gload = [&](int k0) {
    ra = *(const bfx8*)&A[(size_t)(m0 + arow) * K + k0 + ac8];
    #pragma unroll
    for (int j = 0; j < 4; ++j)
      rb[j] = *(const bfx8*)&Bt[(size_t)brow[j] * K + k0 + bc8[j]];
  };
  gload(0);
  for (int k0 = 0; k0 < K; k0 += 64) {
    __syncthreads();
    *(bfx4*)&As[arow][ap0] = __builtin_shufflevector(ra, ra, 0, 1, 2, 3);
    *(bfx4*)&As[arow][ap1] = __builtin_shufflevector(ra, ra, 4, 5, 6, 7);
    #pragma unroll
    for (int j = 0; j < 4; ++j) {
      *(bfx4*)&Bs[brow[j]][bp0[j]] = __builtin_shufflevector(rb[j], rb[j], 0, 1, 2, 3);
      *(bfx4*)&Bs[brow[j]][bp1[j]] = __builtin_shufflevector(rb[j], rb[j], 4, 5, 6, 7);
    }
    __syncthreads();
    if (k0 + 64 < K) gload(k0 + 64);
    #pragma unroll
    for (int ks = 0; ks < 2; ++ks) {
      bfx8 af[2], bf[4];
      #pragma unroll
      for (int mi = 0; mi < 2; ++mi)
        af[mi] = *(const bfx8*)&As[wr * 32 + mi * 16 + lr][ks * 32 + kb * 2];
      #pragma unroll
      for (int ni = 0; ni < 4; ++ni)
        bf[ni] = *(const bfx8*)&Bs[wc * 64 + ni * 16 + lr][ks * 32 + kb * 2];
      #pragma unroll
      for (int mi = 0; mi < 2; ++mi)
        #pragma unroll
        for (int ni = 0; ni < 4; ++ni)
          acc[mi][ni] = __builtin_amdgcn_mfma_f32_16x16x32_bf16(af[mi], bf[ni],
                                                                acc[mi][ni], 0, 0, 0);
    }
  }
  const int bb_ = m0 >> 10, tok0 = m0 & 1023;
  float* obase = outp + (size_t)bb_ * CDIM * NTOK + tok0;
  float* Ty = (float*)smem;
  #pragma unroll
  for (int h2 = 0; h2 < 2; ++h2) {
    __syncthreads();
    if ((wc >> 1) == h2) {
      #pragma unroll
      for (int ni = 0; ni < 4; ++ni) {
        int colq = wc * 64 + ni * 16 + lr;
        int chl = colq - h2 * 128;
        float bn = bias[colq];
        #pragma unroll
        for (int mi = 0; mi < 2; ++mi) {
          int tk = wr * 32 + mi * 16 + kb;
          float4 v4;
          #pragma unroll
          for (int r = 0; r < 4; ++r)
            ((float*)&v4)[r] = acc[mi][ni][r] + bn +
                (float)residb[(size_t)(m0 + tk + r) * CDIM + colq];
          *(float4*)&Ty[chl * 68 + tk] = v4;
        }
      }
    }
    __syncthreads();
    int row = t >> 2, quad = t & 3;
    #pragma unroll
    for (int j = 0; j < 4; ++j) {
      int p = quad + j * 4;
      *(float4*)&obase[(size_t)(h2 * 128 + row) * NTOK + p * 4] =
          *(const float4*)&Ty[row * 68 + p * 4];
    }
  }
}

// -------- flash attention, QBLK=256, 8 waves (32 q-rows/wave) — R13 exact ---
__launch_bounds__(512)
__global__ void attn_kernel(const __bf16* __restrict__ qkv, const __bf16* __restrict__ vT,
                            const __bf16* __restrict__ biasB, __bf16* __restrict__ outb) {
  __shared__ __bf16 Ks[64][40];
  __shared__ __bf16 Vs[32][72];
  __shared__ __bf16 Bls[256][72];
  const int q0 = blockIdx.x * 256, h = blockIdx.y, b = blockIdx.z;
  const int t = threadIdx.x, lane = t & 63, w = t >> 6;     // 8 waves
  const int lr = lane & 15, kb = (lane >> 4) * 4;
  const size_t qbase = (size_t)b * NTOK * QKVD;
  const float qsc = SCALE * LOG2E;
  bfx8 qf[2];
  #pragma unroll
  for (int tq = 0; tq < 2; ++tq) {
    const __bf16* qp = &qkv[qbase + (size_t)(q0 + 32 * w + 16 * tq + lr) * QKVD + h * DHEAD];
    bfx4 lo = *(const bfx4*)&qp[kb];
    bfx4 hi = *(const bfx4*)&qp[kb + 16];
    #pragma unroll
    for (int j = 0; j < 4; ++j) {
      qf[tq][j]     = (__bf16)((float)lo[j] * qsc);
      qf[tq][j + 4] = (__bf16)((float)hi[j] * qsc);
    }
  }
  float l_run[2] = {0.f, 0.f};
  f32x4 oacc[2][2] = {};
  const int st_ = t & 255;
  const int krow = st_ >> 2, kc8 = (st_ & 3) * 8;   // K stage (t<256): 64x32
  const int vrow = st_ >> 3, vc8 = (st_ & 7) * 8;   // V stage (t>=256): 32x64
  const __bf16* kvptr = (t < 256)
      ? &qkv[qbase + (size_t)krow * QKVD + INNER + h * DHEAD + kc8]
      : &vT[(((size_t)b * NHEAD + h) * DHEAD + vrow) * NTOK + vc8];
  const __bf16* bbase = &biasB[((size_t)h * NTOK + q0) * NTOK];
  bfx8 rkv, rbias[4];
  auto issue = [&](int k0) {
    rkv = (t < 256) ? *(const bfx8*)&kvptr[(size_t)k0 * QKVD]
                    : *(const bfx8*)&kvptr[k0];
    #pragma unroll
    for (int j = 0; j < 4; ++j) {
      int lin = j * 512 + t;                  // 2048 chunks: 256 rows x 128B
      int br = lin >> 3, bc8 = (lin & 7) * 8;
      rbias[j] = *(const bfx8*)&bbase[(size_t)br * NTOK + k0 + bc8];
    }
  };
  issue(0);
  for (int kt = 0; kt < 16; ++kt) {
    __syncthreads();
    if (t < 256) *(bfx8*)&Ks[krow][kc8] = rkv;
    else         *(bfx8*)&Vs[vrow][vc8] = rkv;
    #pragma unroll
    for (int j = 0; j < 4; ++j) {
      int lin = j * 512 + t;
      int br = lin >> 3, bc8 = (lin & 7) * 8;
      *(bfx8*)&Bls[br][bc8] = rbias[j];
    }
    __syncthreads();
    if (kt < 15) issue((kt + 1) * 64);
    bfx8 kf[4], vfr[4];
    #pragma unroll
    for (int f = 0; f < 4; ++f) {
      bfx4 klo = *(const bfx4*)&Ks[16 * f + lr][kb];
      bfx4 khi = *(const bfx4*)&Ks[16 * f + lr][kb + 16];
      kf[f] = __builtin_shufflevector(klo, khi, 0, 1, 2, 3, 4, 5, 6, 7);
    }
    #pragma unroll
    for (int s = 0; s < 2; ++s)
      #pragma unroll
      for (int df = 0; df < 2; ++df) {
        bfx4 vlo = *(const bfx4*)&Vs[16 * df + lr][s * 32 + kb];
        bfx4 vhi = *(const bfx4*)&Vs[16 * df + lr][s * 32 + kb + 16];
        vfr[s * 2 + df] = __builtin_shufflevector(vlo, vhi, 0, 1, 2, 3, 4, 5, 6, 7);
      }
    #pragma unroll
    for (int tq = 0; tq < 2; ++tq) {
      const int qrow_l = 32 * w + 16 * tq + lr;
      f32x4 st[4];
      #pragma unroll
      for (int f = 0; f < 4; ++f) {
        bfx4 bv = *(const bfx4*)&Bls[qrow_l][16 * f + kb];
        f32x4 c;
        c[0] = (float)bv[0]; c[1] = (float)bv[1];
        c[2] = (float)bv[2]; c[3] = (float)bv[3];
        st[f] = __builtin_amdgcn_mfma_f32_16x16x32_bf16(kf[f], qf[tq], c, 0, 0, 0);
      }
      float p[4][4], tsum = 0.f;
      #pragma unroll
      for (int f = 0; f < 4; ++f)
        #pragma unroll
        for (int r = 0; r < 4; ++r) {
          float e = EXP2(st[f][r]);
          p[f][r] = e;
          tsum += e;
        }
      l_run[tq] += tsum;
      bfx8 pa0, pa1;
      #pragma unroll
      for (int r = 0; r < 4; ++r) {
        pa0[r] = (__bf16)p[0][r];  pa0[r + 4] = (__bf16)p[1][r];
        pa1[r] = (__bf16)p[2][r];  pa1[r + 4] = (__bf16)p[3][r];
      }
      #pragma unroll
      for (int s = 0; s < 2; ++s) {
        bfx8 pa = s ? pa1 : pa0;
        #pragma unroll
        for (int df = 0; df < 2; ++df)
          oacc[tq][df] = __builtin_amdgcn_mfma_f32_16x16x32_bf16(pa, vfr[s * 2 + df],
                                                                 oacc[tq][df], 0, 0, 0);
      }
    }
  }
  #pragma unroll
  for (int tq = 0; tq < 2; ++tq) {
    float l = l_run[tq];
    l += __shfl_xor(l, 16);
    l += __shfl_xor(l, 32);
    float il[4];
    #pragma unroll
    for (int r = 0; r < 4; ++r) il[r] = 1.f / __shfl(l, kb + r);
    #pragma unroll
    for (int r = 0; r < 4; ++r) {
      size_t rowoff = (size_t)b * NTOK * CDIM +
                      (size_t)(q0 + 32 * w + 16 * tq + kb + r) * CDIM + h * DHEAD;
      outb[rowoff + lr]      = (__bf16)(oacc[tq][0][r] * il[r]);
      outb[rowoff + 16 + lr] = (__bf16)(oacc[tq][1][r] * il[r]);
    }
  }
}

// ---------------------------------------------------------------------------
extern "C" void kernel_launch(void* const* d_in, const int* in_sizes, int n_in,
                              void* d_out, int out_size, void* d_ws, size_t ws_size,
                              hipStream_t stream) {
  const float* x     = (const float*)d_in[0];
  const float* ln1_g = (const float*)d_in[2];
  const float* ln1_b = (const float*)d_in[3];
  const float* Wqkv  = (const float*)d_in[4];
  const float* table = (const float*)d_in[5];
  const float* Wo    = (const float*)d_in[6];
  const float* bo    = (const float*)d_in[7];
  const float* ln2_g = (const float*)d_in[8];
  const float* ln2_b = (const float*)d_in[9];
  const float* W1    = (const float*)d_in[10];
  const float* b1    = (const float*)d_in[11];
  const float* W2    = (const float*)d_in[12];
  const float* b2    = (const float*)d_in[13];

  char* ws = (char*)d_ws;
  __bf16* t_bf  = (__bf16*)(ws + 0);          // 8 MB residual 1 (bf16)
  __bf16* t2_bf = (__bf16*)(ws + 8388608);    // 8 MB residual 2 (bf16)
  __bf16* qkv   = (__bf16*)(ws + 33554432);   // 24 MB
  __bf16* hln   = (__bf16*)(ws + 58720256);   // 8 MB (ln1 out, reused for ln2)
  __bf16* aout  = (__bf16*)(ws + 67108864);   // 8 MB
  __bf16* hid   = (__bf16*)(ws + 75497472);   // 16 MB (aliased: vT during attention)
  __bf16* vT    = (__bf16*)(ws + 75497472);   // 8.4 MB, dead before hid is written
  __bf16* biasB = (__bf16*)(ws + 92274688);   // 16 MB
  __bf16* Wqkvt = (__bf16*)(ws + 109051904);
  __bf16* Wot   = (__bf16*)(ws + 109445120);
  __bf16* W1t   = (__bf16*)(ws + 109576192);
  __bf16* W2t   = (__bf16*)(ws + 109838336);  // ends 110100480
  if (ws_size < 110100480) return;            // visible failure instead of OOB

  prep_kernel<<<6144, 256, 0, stream>>>(Wqkv, Wo, W1, W2, Wqkvt, Wot, W1t, W2t,
                                        table, biasB);
  txln_kernel<<<dim3(32, 1, 16), 256, 0, stream>>>(x, ln1_g, ln1_b, t_bf, hln);
  gemm128_kernel<0><<<dim3(128, 6), 256, 0, stream>>>(hln, Wqkvt, nullptr, nullptr, qkv, vT, 768, 256);
  attn_kernel<<<dim3(4, 8, 16), 512, 0, stream>>>(qkv, vT, biasB, aout);
  gemmWoLn_kernel<<<512, 256, 0, stream>>>(aout, Wot, bo, t_bf, ln2_g, ln2_b, t2_bf, hln);
  gemmW1G_kernel<<<dim3(256, 4), 256, 0, stream>>>(hln, W1t, b1, hid);
  gemmW2T_kernel<<<256, 512, 0, stream>>>(hid, W2t, b2, t2_bf, (float*)d_out);
}

// Round 28
// 124.015 us; speedup vs baseline: 1.1303x; 1.0032x over previous
//
#include <hip/hip_runtime.h>
#include <hip/hip_bf16.h>
#include <math.h>

typedef __bf16 bfx4 __attribute__((ext_vector_type(4)));
typedef __bf16 bfx8 __attribute__((ext_vector_type(8)));
typedef float  f32x4 __attribute__((ext_vector_type(4)));

#define BATCH 16
#define NTOK  1024
#define CDIM  256
#define NHEAD 8
#define DHEAD 32
#define QKVD  768
#define INNER 256
#define SCALE 0.17677669529663687f
#define LOG2E 1.4426950408889634f

#if __has_builtin(__builtin_amdgcn_exp2f)
#define EXP2(x) __builtin_amdgcn_exp2f(x)
#else
#define EXP2(x) exp2f(x)
#endif

// ------- fused transpose + LN1: x[B][C][N] -> t_bf bf16 [tok][C], hln bf16 --
__launch_bounds__(256)
__global__ void txln_kernel(const float* __restrict__ x, const float* __restrict__ g,
                            const float* __restrict__ bb, __bf16* __restrict__ tb,
                            __bf16* __restrict__ hln) {
  __shared__ float tile[256][33];
  const int b = blockIdx.z, n0 = blockIdx.x * 32;
  const int tt = threadIdx.x;
  const float* src = x + (size_t)b * CDIM * NTOK;
  #pragma unroll
  for (int i = 0; i < 8; ++i) {
    int cid = i * 256 + tt;
    int c = cid >> 3, col4 = (cid & 7) * 4;
    *(float4*)&tile[c][col4] = *(const float4*)&src[(size_t)c * NTOK + n0 + col4];
  }
  __syncthreads();
  const int n = tt >> 3, c0 = (tt & 7) * 32;   // 8 threads per token
  float vals[32];
  float s = 0.f, s2 = 0.f;
  #pragma unroll
  for (int j = 0; j < 32; ++j) {
    float v = tile[c0 + j][n];
    vals[j] = v; s += v; s2 += v * v;
  }
  s  += __shfl_xor(s, 1);  s  += __shfl_xor(s, 2);  s  += __shfl_xor(s, 4);
  s2 += __shfl_xor(s2, 1); s2 += __shfl_xor(s2, 2); s2 += __shfl_xor(s2, 4);
  float mu = s * 0.00390625f;
  float var = s2 * 0.00390625f - mu * mu;
  float rs = rsqrtf(var + 1e-5f);
  size_t row = ((size_t)b * NTOK + n0 + n) * CDIM;
  #pragma unroll
  for (int j = 0; j < 32; j += 4) {
    const float4 gg = *(const float4*)&g[c0 + j];
    const float4 bv = *(const float4*)&bb[c0 + j];
    bfx4 tv;
    tv[0] = (__bf16)vals[j];     tv[1] = (__bf16)vals[j + 1];
    tv[2] = (__bf16)vals[j + 2]; tv[3] = (__bf16)vals[j + 3];
    *(bfx4*)&tb[row + c0 + j] = tv;
    bfx4 o;
    o[0] = (__bf16)((vals[j]     - mu) * rs * gg.x + bv.x);
    o[1] = (__bf16)((vals[j + 1] - mu) * rs * gg.y + bv.y);
    o[2] = (__bf16)((vals[j + 2] - mu) * rs * gg.z + bv.z);
    o[3] = (__bf16)((vals[j + 3] - mu) * rs * gg.w + bv.w);
    *(bfx4*)&hln[row + c0 + j] = o;
  }
}

// ---- merged prep: weight transpose+cast (blocks 0..2047) + bias (2048..6143)
__launch_bounds__(256)
__global__ void prep_kernel(const float* __restrict__ Wqkv, const float* __restrict__ Wo,
                            const float* __restrict__ W1, const float* __restrict__ W2,
                            __bf16* __restrict__ Wqkvt, __bf16* __restrict__ Wot,
                            __bf16* __restrict__ W1t, __bf16* __restrict__ W2t,
                            const float* __restrict__ table, __bf16* __restrict__ biasB) {
  if (blockIdx.x < 2048) {
    int idx = blockIdx.x * 256 + threadIdx.x;
    const float* W; __bf16* Wt; int lk, Nn, off;
    if (idx < 196608)      { W = Wqkv; Wt = Wqkvt; lk = 8; Nn = 768; off = idx; }
    else if (idx < 262144) { W = Wo;   Wt = Wot;   lk = 8; Nn = 256; off = idx - 196608; }
    else if (idx < 393216) { W = W1;   Wt = W1t;   lk = 8; Nn = 512; off = idx - 262144; }
    else                   { W = W2;   Wt = W2t;   lk = 9; Nn = 256; off = idx - 393216; }
    int n = off >> lk, k = off & ((1 << lk) - 1);
    Wt[off] = (__bf16)W[(size_t)k * Nn + n];
  } else {
    int idx = (blockIdx.x - 2048) * 256 + threadIdx.x;   // h*2^17 + q*2^7 + k8
    int k8 = (idx & 127) * 8, q = (idx >> 7) & 1023, h = idx >> 17;
    int qi = q >> 5, qj = q & 31;
    bfx8 o;
    #pragma unroll
    for (int j = 0; j < 8; ++j) {
      int k = k8 + j, ki = k >> 5, kj = k & 31;
      int r = (qi - ki + 31) * 63 + (qj - kj + 31);
      o[j] = (__bf16)(table[r * 8 + h] * LOG2E);
    }
    *(bfx8*)&biasB[((size_t)idx) * 8] = o;
  }
}

// ---- QKV GEMM (BM=64, BN=128, 256 thr): q/k -> qkv bf16, V -> vT scatter ---
// LDS 27.6 KB -> 5 blocks/CU at grid 1536 (20 waves/CU vs old 12).
__launch_bounds__(256)
__global__ void gemmQKV_kernel(const __bf16* __restrict__ A, const __bf16* __restrict__ Bt,
                               __bf16* __restrict__ outp, __bf16* __restrict__ vTout) {
  __shared__ char smem[27648];
  __bf16 (*As)[72] = (__bf16(*)[72])smem;             // 64 x 72
  __bf16 (*Bs)[72] = (__bf16(*)[72])(smem + 9216);    // 128 x 72
  const int t = threadIdx.x, lane = t & 63, w = t >> 6;
  const int m0 = blockIdx.x * 64, n0 = blockIdx.y * 128;
  const int wr = w >> 1, wc = w & 1;
  const int lr = lane & 15, kb = (lane >> 4) * 4;
  const int K = 256;
  int arow[2], ap0[2], ap1[2];
  #pragma unroll
  for (int i = 0; i < 2; ++i) {
    int cid = i * 256 + t, kb8 = (cid & 7) * 8;
    arow[i] = cid >> 3;
    int b0 = kb8, b1 = kb8 + 4;
    ap0[i] = (b0 & 32) + ((b0 & 12) << 1) + (((b0 >> 4) & 1) << 2) + (b0 & 3);
    ap1[i] = (b1 & 32) + ((b1 & 12) << 1) + (((b1 >> 4) & 1) << 2) + (b1 & 3);
  }
  int brow[4], bp0[4], bp1[4], bc8[4];
  #pragma unroll
  for (int j = 0; j < 4; ++j) {
    int cid = j * 256 + t;
    brow[j] = cid >> 3;
    bc8[j] = (cid & 7) * 8;
    int b0 = bc8[j], b1 = bc8[j] + 4;
    bp0[j] = (b0 & 32) + ((b0 & 12) << 1) + (((b0 >> 4) & 1) << 2) + (b0 & 3);
    bp1[j] = (b1 & 32) + ((b1 & 12) << 1) + (((b1 >> 4) & 1) << 2) + (b1 & 3);
  }
  f32x4 acc[2][4] = {};
  bfx8 ra[2], rb[4];
  auto gload = [&](int k0) {
    #pragma unroll
    for (int i = 0; i < 2; ++i) {
      int kc8 = ((i * 256 + t) & 7) * 8;
      ra[i] = *(const bfx8*)&A[(size_t)(m0 + arow[i]) * K + k0 + kc8];
    }
    #pragma unroll
    for (int j = 0; j < 4; ++j)
      rb[j] = *(const bfx8*)&Bt[(size_t)(n0 + brow[j]) * K + k0 + bc8[j]];
  };
  gload(0);
  for (int k0 = 0; k0 < K; k0 += 64) {
    __syncthreads();
    #pragma unroll
    for (int i = 0; i < 2; ++i) {
      *(bfx4*)&As[arow[i]][ap0[i]] = __builtin_shufflevector(ra[i], ra[i], 0, 1, 2, 3);
      *(bfx4*)&As[arow[i]][ap1[i]] = __builtin_shufflevector(ra[i], ra[i], 4, 5, 6, 7);
    }
    #pragma unroll
    for (int j = 0; j < 4; ++j) {
      *(bfx4*)&Bs[brow[j]][bp0[j]] = __builtin_shufflevector(rb[j], rb[j], 0, 1, 2, 3);
      *(bfx4*)&Bs[brow[j]][bp1[j]] = __builtin_shufflevector(rb[j], rb[j], 4, 5, 6, 7);
    }
    __syncthreads();
    if (k0 + 64 < K) gload(k0 + 64);
    #pragma unroll
    for (int ks = 0; ks < 2; ++ks) {
      bfx8 af[2], bf[4];
      #pragma unroll
      for (int mi = 0; mi < 2; ++mi)
        af[mi] = *(const bfx8*)&As[wr * 32 + mi * 16 + lr][ks * 32 + kb * 2];
      #pragma unroll
      for (int ni = 0; ni < 4; ++ni)
        bf[ni] = *(const bfx8*)&Bs[wc * 64 + ni * 16 + lr][ks * 32 + kb * 2];
      #pragma unroll
      for (int mi = 0; mi < 2; ++mi)
        #pragma unroll
        for (int ni = 0; ni < 4; ++ni)
          acc[mi][ni] = __builtin_amdgcn_mfma_f32_16x16x32_bf16(af[mi], bf[ni],
                                                                acc[mi][ni], 0, 0, 0);
    }
  }
  if (n0 >= 512) {
    // V columns: scatter into vT[b][h][d][tok], 4 consecutive tokens per lane
    #pragma unroll
    for (int mi = 0; mi < 2; ++mi)
      #pragma unroll
      for (int ni = 0; ni < 4; ++ni) {
        int n = n0 + wc * 64 + ni * 16 + lr;
        int cp = n - 512, hh = cp >> 5, dd = cp & 31;
        int m = m0 + wr * 32 + mi * 16 + kb;
        int bb_ = m >> 10, tok = m & 1023;
        bfx4 o;
        o[0] = (__bf16)acc[mi][ni][0]; o[1] = (__bf16)acc[mi][ni][1];
        o[2] = (__bf16)acc[mi][ni][2]; o[3] = (__bf16)acc[mi][ni][3];
        *(bfx4*)&vTout[(((size_t)bb_ * NHEAD + hh) * DHEAD + dd) * NTOK + tok] = o;
      }
    return;
  }
  #pragma unroll
  for (int mi = 0; mi < 2; ++mi)
    #pragma unroll
    for (int ni = 0; ni < 4; ++ni)
      #pragma unroll
      for (int r = 0; r < 4; ++r) {
        int m = m0 + wr * 32 + mi * 16 + kb + r;
        int n = n0 + wc * 64 + ni * 16 + lr;
        outp[(size_t)m * QKVD + n] = (__bf16)acc[mi][ni][r];
      }
}

// ---- W1 GEMM (BM=64, BN=128, 256 thr) + bias + GELU -> bf16 ----------------
__launch_bounds__(256)
__global__ void gemmW1G_kernel(const __bf16* __restrict__ A, const __bf16* __restrict__ Bt,
                               const float* __restrict__ bias, __bf16* __restrict__ outp) {
  __shared__ char smem[27648];
  __bf16 (*As)[72] = (__bf16(*)[72])smem;             // 64 x 72 (9.2 KB)
  __bf16 (*Bs)[72] = (__bf16(*)[72])(smem + 9216);    // 128 x 72 (18.4 KB)
  const int t = threadIdx.x, lane = t & 63, w = t >> 6;
  const int m0 = blockIdx.x * 64, n0 = blockIdx.y * 128;
  const int wr = w >> 1, wc = w & 1;
  const int lr = lane & 15, kb = (lane >> 4) * 4;
  const int K = 256, Nn = 512;
  int arow[2], ap0[2], ap1[2];
  #pragma unroll
  for (int i = 0; i < 2; ++i) {
    int cid = i * 256 + t, kb8 = (cid & 7) * 8;
    arow[i] = cid >> 3;
    int b0 = kb8, b1 = kb8 + 4;
    ap0[i] = (b0 & 32) + ((b0 & 12) << 1) + (((b0 >> 4) & 1) << 2) + (b0 & 3);
    ap1[i] = (b1 & 32) + ((b1 & 12) << 1) + (((b1 >> 4) & 1) << 2) + (b1 & 3);
  }
  int brow[4], bp0[4], bp1[4], bc8[4];
  #pragma unroll
  for (int j = 0; j < 4; ++j) {
    int cid = j * 256 + t;
    brow[j] = cid >> 3;
    bc8[j] = (cid & 7) * 8;
    int b0 = bc8[j], b1 = bc8[j] + 4;
    bp0[j] = (b0 & 32) + ((b0 & 12) << 1) + (((b0 >> 4) & 1) << 2) + (b0 & 3);
    bp1[j] = (b1 & 32) + ((b1 & 12) << 1) + (((b1 >> 4) & 1) << 2) + (b1 & 3);
  }
  f32x4 acc[2][4] = {};
  bfx8 ra[2], rb[4];
  auto gload = [&](int k0) {
    #pragma unroll
    for (int i = 0; i < 2; ++i) {
      int kc8 = ((i * 256 + t) & 7) * 8;
      ra[i] = *(const bfx8*)&A[(size_t)(m0 + arow[i]) * K + k0 + kc8];
    }
    #pragma unroll
    for (int j = 0; j < 4; ++j)
      rb[j] = *(const bfx8*)&Bt[(size_t)(n0 + brow[j]) * K + k0 + bc8[j]];
  };
  gload(0);
  for (int k0 = 0; k0 < K; k0 += 64) {
    __syncthreads();
    #pragma unroll
    for (int i = 0; i < 2; ++i) {
      *(bfx4*)&As[arow[i]][ap0[i]] = __builtin_shufflevector(ra[i], ra[i], 0, 1, 2, 3);
      *(bfx4*)&As[arow[i]][ap1[i]] = __builtin_shufflevector(ra[i], ra[i], 4, 5, 6, 7);
    }
    #pragma unroll
    for (int j = 0; j < 4; ++j) {
      *(bfx4*)&Bs[brow[j]][bp0[j]] = __builtin_shufflevector(rb[j], rb[j], 0, 1, 2, 3);
      *(bfx4*)&Bs[brow[j]][bp1[j]] = __builtin_shufflevector(rb[j], rb[j], 4, 5, 6, 7);
    }
    __syncthreads();
    if (k0 + 64 < K) gload(k0 + 64);
    #pragma unroll
    for (int ks = 0; ks < 2; ++ks) {
      bfx8 af[2], bf[4];
      #pragma unroll
      for (int mi = 0; mi < 2; ++mi)
        af[mi] = *(const bfx8*)&As[wr * 32 + mi * 16 + lr][ks * 32 + kb * 2];
      #pragma unroll
      for (int ni = 0; ni < 4; ++ni)
        bf[ni] = *(const bfx8*)&Bs[wc * 64 + ni * 16 + lr][ks * 32 + kb * 2];
      #pragma unroll
      for (int mi = 0; mi < 2; ++mi)
        #pragma unroll
        for (int ni = 0; ni < 4; ++ni)
          acc[mi][ni] = __builtin_amdgcn_mfma_f32_16x16x32_bf16(af[mi], bf[ni],
                                                                acc[mi][ni], 0, 0, 0);
    }
  }
  #pragma unroll
  for (int mi = 0; mi < 2; ++mi)
    #pragma unroll
    for (int ni = 0; ni < 4; ++ni) {
      int n = n0 + wc * 64 + ni * 16 + lr;
      float bn = bias[n];
      #pragma unroll
      for (int r = 0; r < 4; ++r) {
        int m = m0 + wr * 32 + mi * 16 + kb + r;
        float v = acc[mi][ni][r] + bn;
        v = 0.5f * v * (1.0f + erff(v * 0.70710678118f));
        outp[(size_t)m * Nn + n] = (__bf16)v;
      }
    }
}

// ---- Wo GEMM (BM=32, BN=256 full width, 256 thr) + bias + resid + LN2 ------
__launch_bounds__(256)
__global__ void gemmWoLn_kernel(const __bf16* __restrict__ A, const __bf16* __restrict__ Bt,
                                const float* __restrict__ bias,
                                const __bf16* __restrict__ residb,
                                const float* __restrict__ g2, const float* __restrict__ b2v,
                                __bf16* __restrict__ t2, __bf16* __restrict__ hln) {
  __shared__ char smem[41472];
  __bf16 (*As)[72] = (__bf16(*)[72])smem;             // 32 x 72 (4.6 KB)
  __bf16 (*Bs)[72] = (__bf16(*)[72])(smem + 4608);    // 256 x 72 (36.9 KB)
  const int t = threadIdx.x, lane = t & 63, w = t >> 6;   // 4 waves
  const int m0 = blockIdx.x * 32;
  const int lr = lane & 15, kb = (lane >> 4) * 4;
  const int K = 256;
  const int arow = t >> 3, ac8 = (t & 7) * 8;             // A: 32 rows x 64
  int ap0, ap1;
  {
    int b0 = ac8, b1 = ac8 + 4;
    ap0 = (b0 & 32) + ((b0 & 12) << 1) + (((b0 >> 4) & 1) << 2) + (b0 & 3);
    ap1 = (b1 & 32) + ((b1 & 12) << 1) + (((b1 >> 4) & 1) << 2) + (b1 & 3);
  }
  int brow[8], bp0[8], bp1[8], bc8[8];
  #pragma unroll
  for (int j = 0; j < 8; ++j) {
    int cid = j * 256 + t;
    brow[j] = cid >> 3;
    bc8[j] = (cid & 7) * 8;
    int b0 = bc8[j], b1 = bc8[j] + 4;
    bp0[j] = (b0 & 32) + ((b0 & 12) << 1) + (((b0 >> 4) & 1) << 2) + (b0 & 3);
    bp1[j] = (b1 & 32) + ((b1 & 12) << 1) + (((b1 >> 4) & 1) << 2) + (b1 & 3);
  }
  f32x4 acc[2][4] = {};
  bfx8 ra, rb[8];
  auto gload = [&](int k0) {
    ra = *(const bfx8*)&A[(size_t)(m0 + arow) * K + k0 + ac8];
    #pragma unroll
    for (int j = 0; j < 8; ++j)
      rb[j] = *(const bfx8*)&Bt[(size_t)brow[j] * K + k0 + bc8[j]];
  };
  gload(0);
  for (int k0 = 0; k0 < K; k0 += 64) {
    __syncthreads();
    *(bfx4*)&As[arow][ap0] = __builtin_shufflevector(ra, ra, 0, 1, 2, 3);
    *(bfx4*)&As[arow][ap1] = __builtin_shufflevector(ra, ra, 4, 5, 6, 7);
    #pragma unroll
    for (int j = 0; j < 8; ++j) {
      *(bfx4*)&Bs[brow[j]][bp0[j]] = __builtin_shufflevector(rb[j], rb[j], 0, 1, 2, 3);
      *(bfx4*)&Bs[brow[j]][bp1[j]] = __builtin_shufflevector(rb[j], rb[j], 4, 5, 6, 7);
    }
    __syncthreads();
    if (k0 + 64 < K) gload(k0 + 64);
    #pragma unroll
    for (int ks = 0; ks < 2; ++ks) {
      bfx8 af[2], bf[4];
      #pragma unroll
      for (int mi = 0; mi < 2; ++mi)
        af[mi] = *(const bfx8*)&As[mi * 16 + lr][ks * 32 + kb * 2];
      #pragma unroll
      for (int ni = 0; ni < 4; ++ni)
        bf[ni] = *(const bfx8*)&Bs[w * 64 + ni * 16 + lr][ks * 32 + kb * 2];
      #pragma unroll
      for (int mi = 0; mi < 2; ++mi)
        #pragma unroll
        for (int ni = 0; ni < 4; ++ni)
          acc[mi][ni] = __builtin_amdgcn_mfma_f32_16x16x32_bf16(af[mi], bf[ni],
                                                                acc[mi][ni], 0, 0, 0);
    }
  }
  float colg[4], colb[4];
  #pragma unroll
  for (int ni = 0; ni < 4; ++ni) {
    int colq = w * 64 + ni * 16 + lr;
    float bn = bias[colq];
    colg[ni] = g2[colq];
    colb[ni] = b2v[colq];
    #pragma unroll
    for (int mi = 0; mi < 2; ++mi)
      #pragma unroll
      for (int r = 0; r < 4; ++r) {
        int m = m0 + mi * 16 + kb + r;
        acc[mi][ni][r] += bn + (float)residb[(size_t)m * CDIM + colq];
      }
  }
  float ps[2][4], pq[2][4];
  #pragma unroll
  for (int mi = 0; mi < 2; ++mi)
    #pragma unroll
    for (int r = 0; r < 4; ++r) {
      float s = 0.f, q = 0.f;
      #pragma unroll
      for (int ni = 0; ni < 4; ++ni) {
        float v = acc[mi][ni][r];
        s += v; q += v * v;
      }
      #pragma unroll
      for (int o = 1; o < 16; o <<= 1) { s += __shfl_xor(s, o); q += __shfl_xor(q, o); }
      ps[mi][r] = s; pq[mi][r] = q;
    }
  __syncthreads();
  float* red = (float*)smem;              // [32][8]
  if (lr == 0) {
    #pragma unroll
    for (int mi = 0; mi < 2; ++mi)
      #pragma unroll
      for (int r = 0; r < 4; ++r) {
        int rl = mi * 16 + kb + r;
        red[rl * 8 + w] = ps[mi][r];
        red[rl * 8 + 4 + w] = pq[mi][r];
      }
  }
  __syncthreads();
  if (t < 32) {
    float s = red[t * 8] + red[t * 8 + 1] + red[t * 8 + 2] + red[t * 8 + 3];
    float q = red[t * 8 + 4] + red[t * 8 + 5] + red[t * 8 + 6] + red[t * 8 + 7];
    float mu = s * 0.00390625f;
    float var = q * 0.00390625f - mu * mu;
    red[t * 8] = mu;
    red[t * 8 + 1] = rsqrtf(var + 1e-5f);
  }
  __syncthreads();
  #pragma unroll
  for (int mi = 0; mi < 2; ++mi)
    #pragma unroll
    for (int r = 0; r < 4; ++r) {
      int rl = mi * 16 + kb + r;
      float mu = red[rl * 8], rs = red[rl * 8 + 1];
      size_t rowoff = (size_t)(m0 + rl) * CDIM;
      #pragma unroll
      for (int ni = 0; ni < 4; ++ni) {
        int colq = w * 64 + ni * 16 + lr;
        float v = acc[mi][ni][r];
        t2[rowoff + colq] = (__bf16)v;
        hln[rowoff + colq] = (__bf16)((v - mu) * rs * colg[ni] + colb[ni]);
      }
    }
}

// ---- W2 GEMM (BM=64, BN=256, K=512) + bias + resid, TRANSPOSED fp32 out ----
__launch_bounds__(512)
__global__ void gemmW2T_kernel(const __bf16* __restrict__ A, const __bf16* __restrict__ Bt,
                               const float* __restrict__ bias,
                               const __bf16* __restrict__ residb,
                               float* __restrict__ outp) {
  __shared__ char smem[46080];
  __bf16 (*As)[72] = (__bf16(*)[72])smem;             // 64 x 72
  __bf16 (*Bs)[72] = (__bf16(*)[72])(smem + 9216);    // 256 x 72
  const int t = threadIdx.x, lane = t & 63, w = t >> 6;
  const int m0 = blockIdx.x * 64;
  const int wr = w >> 2, wc = w & 3;
  const int lr = lane & 15, kb = (lane >> 4) * 4;
  const int K = 512;
  const int arow = t >> 3, ac8 = (t & 7) * 8;
  int ap0, ap1;
  {
    int b0 = ac8, b1 = ac8 + 4;
    ap0 = (b0 & 32) + ((b0 & 12) << 1) + (((b0 >> 4) & 1) << 2) + (b0 & 3);
    ap1 = (b1 & 32) + ((b1 & 12) << 1) + (((b1 >> 4) & 1) << 2) + (b1 & 3);
  }
  int brow[4], bp0[4], bp1[4], bc8[4];
  #pragma unroll
  for (int j = 0; j < 4; ++j) {
    int cid = j * 512 + t;
    brow[j] = cid >> 3;
    bc8[j] = (cid & 7) * 8;
    int b0 = bc8[j], b1 = bc8[j] + 4;
    bp0[j] = (b0 & 32) + ((b0 & 12) << 1) + (((b0 >> 4) & 1) << 2) + (b0 & 3);
    bp1[j] = (b1 & 32) + ((b1 & 12) << 1) + (((b1 >> 4) & 1) << 2) + (b1 & 3);
  }
  f32x4 acc[2][4] = {};
  bfx8 ra, rb[4];
  auto gload = [&](int k0) {
    ra = *(const bfx8*)&A[(size_t)(m0 + arow) * K + k0 + ac8];
    #pragma unroll
    for (int j = 0; j < 4; ++j)
      rb[j] = *(const bfx8*)&Bt[(size_t)brow[j] * K + k0 + bc8[j]];
  };
  gload(0);
  for (int k0 = 0; k0 < K; k0 += 64) {
    __syncthreads();
    *(bfx4*)&As[arow][ap0] = __builtin_shufflevector(ra, ra, 0, 1, 2, 3);
    *(bfx4*)&As[arow][ap1] = __builtin_shufflevector(ra, ra, 4, 5, 6, 7);
    #pragma unroll
    for (int j = 0; j < 4; ++j) {
      *(bfx4*)&Bs[brow[j]][bp0[j]] = __builtin_shufflevector(rb[j], rb[j], 0, 1, 2, 3);
      *(bfx4*)&Bs[brow[j]][bp1[j]] = __builtin_shufflevector(rb[j], rb[j], 4, 5, 6, 7);
    }
    __syncthreads();
    if (k0 + 64 < K) gload(k0 + 64);
    #pragma unroll
    for (int ks = 0; ks < 2; ++ks) {
      bfx8 af[2], bf[4];
      #pragma unroll
      for (int mi = 0; mi < 2; ++mi)
        af[mi] = *(const bfx8*)&As[wr * 32 + mi * 16 + lr][ks * 32 + kb * 2];
      #pragma unroll
      for (int ni = 0; ni < 4; ++ni)
        bf[ni] = *(const bfx8*)&Bs[wc * 64 + ni * 16 + lr][ks * 32 + kb * 2];
      #pragma unroll
      for (int mi = 0; mi < 2; ++mi)
        #pragma unroll
        for (int ni = 0; ni < 4; ++ni)
          acc[mi][ni] = __builtin_amdgcn_mfma_f32_16x16x32_bf16(af[mi], bf[ni],
                                                                acc[mi][ni], 0, 0, 0);
    }
  }
  const int bb_ = m0 >> 10, tok0 = m0 & 1023;
  float* obase = outp + (size_t)bb_ * CDIM * NTOK + tok0;
  float* Ty = (float*)smem;
  #pragma unroll
  for (int h2 = 0; h2 < 2; ++h2) {
    __syncthreads();
    if ((wc >> 1) == h2) {
      #pragma unroll
      for (int ni = 0; ni < 4; ++ni) {
        int colq = wc * 64 + ni * 16 + lr;
        int chl = colq - h2 * 128;
        float bn = bias[colq];
        #pragma unroll
        for (int mi = 0; mi < 2; ++mi) {
          int tk = wr * 32 + mi * 16 + kb;
          float4 v4;
          #pragma unroll
          for (int r = 0; r < 4; ++r)
            ((float*)&v4)[r] = acc[mi][ni][r] + bn +
                (float)residb[(size_t)(m0 + tk + r) * CDIM + colq];
          *(float4*)&Ty[chl * 68 + tk] = v4;
        }
      }
    }
    __syncthreads();
    int row = t >> 2, quad = t & 3;
    #pragma unroll
    for (int j = 0; j < 4; ++j) {
      int p = quad + j * 4;
      *(float4*)&obase[(size_t)(h2 * 128 + row) * NTOK + p * 4] =
          *(const float4*)&Ty[row * 68 + p * 4];
    }
  }
}

// -------- flash attention, QBLK=256, 8 waves (32 q-rows/wave) — R13 exact ---
__launch_bounds__(512)
__global__ void attn_kernel(const __bf16* __restrict__ qkv, const __bf16* __restrict__ vT,
                            const __bf16* __restrict__ biasB, __bf16* __restrict__ outb) {
  __shared__ __bf16 Ks[64][40];
  __shared__ __bf16 Vs[32][72];
  __shared__ __bf16 Bls[256][72];
  const int q0 = blockIdx.x * 256, h = blockIdx.y, b = blockIdx.z;
  const int t = threadIdx.x, lane = t & 63, w = t >> 6;     // 8 waves
  const int lr = lane & 15, kb = (lane >> 4) * 4;
  const size_t qbase = (size_t)b * NTOK * QKVD;
  const float qsc = SCALE * LOG2E;
  bfx8 qf[2];
  #pragma unroll
  for (int tq = 0; tq < 2; ++tq) {
    const __bf16* qp = &qkv[qbase + (size_t)(q0 + 32 * w + 16 * tq + lr) * QKVD + h * DHEAD];
    bfx4 lo = *(const bfx4*)&qp[kb];
    bfx4 hi = *(const bfx4*)&qp[kb + 16];
    #pragma unroll
    for (int j = 0; j < 4; ++j) {
      qf[tq][j]     = (__bf16)((float)lo[j] * qsc);
      qf[tq][j + 4] = (__bf16)((float)hi[j] * qsc);
    }
  }
  float l_run[2] = {0.f, 0.f};
  f32x4 oacc[2][2] = {};
  const int st_ = t & 255;
  const int krow = st_ >> 2, kc8 = (st_ & 3) * 8;   // K stage (t<256): 64x32
  const int vrow = st_ >> 3, vc8 = (st_ & 7) * 8;   // V stage (t>=256): 32x64
  const __bf16* kvptr = (t < 256)
      ? &qkv[qbase + (size_t)krow * QKVD + INNER + h * DHEAD + kc8]
      : &vT[(((size_t)b * NHEAD + h) * DHEAD + vrow) * NTOK + vc8];
  const __bf16* bbase = &biasB[((size_t)h * NTOK + q0) * NTOK];
  bfx8 rkv, rbias[4];
  auto issue = [&](int k0) {
    rkv = (t < 256) ? *(const bfx8*)&kvptr[(size_t)k0 * QKVD]
                    : *(const bfx8*)&kvptr[k0];
    #pragma unroll
    for (int j = 0; j < 4; ++j) {
      int lin = j * 512 + t;                  // 2048 chunks: 256 rows x 128B
      int br = lin >> 3, bc8 = (lin & 7) * 8;
      rbias[j] = *(const bfx8*)&bbase[(size_t)br * NTOK + k0 + bc8];
    }
  };
  issue(0);
  for (int kt = 0; kt < 16; ++kt) {
    __syncthreads();
    if (t < 256) *(bfx8*)&Ks[krow][kc8] = rkv;
    else         *(bfx8*)&Vs[vrow][vc8] = rkv;
    #pragma unroll
    for (int j = 0; j < 4; ++j) {
      int lin = j * 512 + t;
      int br = lin >> 3, bc8 = (lin & 7) * 8;
      *(bfx8*)&Bls[br][bc8] = rbias[j];
    }
    __syncthreads();
    if (kt < 15) issue((kt + 1) * 64);
    bfx8 kf[4], vfr[4];
    #pragma unroll
    for (int f = 0; f < 4; ++f) {
      bfx4 klo = *(const bfx4*)&Ks[16 * f + lr][kb];
      bfx4 khi = *(const bfx4*)&Ks[16 * f + lr][kb + 16];
      kf[f] = __builtin_shufflevector(klo, khi, 0, 1, 2, 3, 4, 5, 6, 7);
    }
    #pragma unroll
    for (int s = 0; s < 2; ++s)
      #pragma unroll
      for (int df = 0; df < 2; ++df) {
        bfx4 vlo = *(const bfx4*)&Vs[16 * df + lr][s * 32 + kb];
        bfx4 vhi = *(const bfx4*)&Vs[16 * df + lr][s * 32 + kb + 16];
        vfr[s * 2 + df] = __builtin_shufflevector(vlo, vhi, 0, 1, 2, 3, 4, 5, 6, 7);
      }
    #pragma unroll
    for (int tq = 0; tq < 2; ++tq) {
      const int qrow_l = 32 * w + 16 * tq + lr;
      f32x4 st[4];
      #pragma unroll
      for (int f = 0; f < 4; ++f) {
        bfx4 bv = *(const bfx4*)&Bls[qrow_l][16 * f + kb];
        f32x4 c;
        c[0] = (float)bv[0]; c[1] = (float)bv[1];
        c[2] = (float)bv[2]; c[3] = (float)bv[3];
        st[f] = __builtin_amdgcn_mfma_f32_16x16x32_bf16(kf[f], qf[tq], c, 0, 0, 0);
      }
      float p[4][4], tsum = 0.f;
      #pragma unroll
      for (int f = 0; f < 4; ++f)
        #pragma unroll
        for (int r = 0; r < 4; ++r) {
          float e = EXP2(st[f][r]);
          p[f][r] = e;
          tsum += e;
        }
      l_run[tq] += tsum;
      bfx8 pa0, pa1;
      #pragma unroll
      for (int r = 0; r < 4; ++r) {
        pa0[r] = (__bf16)p[0][r];  pa0[r + 4] = (__bf16)p[1][r];
        pa1[r] = (__bf16)p[2][r];  pa1[r + 4] = (__bf16)p[3][r];
      }
      #pragma unroll
      for (int s = 0; s < 2; ++s) {
        bfx8 pa = s ? pa1 : pa0;
        #pragma unroll
        for (int df = 0; df < 2; ++df)
          oacc[tq][df] = __builtin_amdgcn_mfma_f32_16x16x32_bf16(pa, vfr[s * 2 + df],
                                                                 oacc[tq][df], 0, 0, 0);
      }
    }
  }
  #pragma unroll
  for (int tq = 0; tq < 2; ++tq) {
    float l = l_run[tq];
    l += __shfl_xor(l, 16);
    l += __shfl_xor(l, 32);
    float il[4];
    #pragma unroll
    for (int r = 0; r < 4; ++r) il[r] = 1.f / __shfl(l, kb + r);
    #pragma unroll
    for (int r = 0; r < 4; ++r) {
      size_t rowoff = (size_t)b * NTOK * CDIM +
                      (size_t)(q0 + 32 * w + 16 * tq + kb + r) * CDIM + h * DHEAD;
      outb[rowoff + lr]      = (__bf16)(oacc[tq][0][r] * il[r]);
      outb[rowoff + 16 + lr] = (__bf16)(oacc[tq][1][r] * il[r]);
    }
  }
}

// ---------------------------------------------------------------------------
extern "C" void kernel_launch(void* const* d_in, const int* in_sizes, int n_in,
                              void* d_out, int out_size, void* d_ws, size_t ws_size,
                              hipStream_t stream) {
  const float* x     = (const float*)d_in[0];
  const float* ln1_g = (const float*)d_in[2];
  const float* ln1_b = (const float*)d_in[3];
  const float* Wqkv  = (const float*)d_in[4];
  const float* table = (const float*)d_in[5];
  const float* Wo    = (const float*)d_in[6];
  const float* bo    = (const float*)d_in[7];
  const float* ln2_g = (const float*)d_in[8];
  const float* ln2_b = (const float*)d_in[9];
  const float* W1    = (const float*)d_in[10];
  const float* b1    = (const float*)d_in[11];
  const float* W2    = (const float*)d_in[12];
  const float* b2    = (const float*)d_in[13];

  char* ws = (char*)d_ws;
  __bf16* t_bf  = (__bf16*)(ws + 0);          // 8 MB residual 1 (bf16)
  __bf16* t2_bf = (__bf16*)(ws + 8388608);    // 8 MB residual 2 (bf16)
  __bf16* qkv   = (__bf16*)(ws + 33554432);   // 24 MB
  __bf16* hln   = (__bf16*)(ws + 58720256);   // 8 MB (ln1 out, reused for ln2)
  __bf16* aout  = (__bf16*)(ws + 67108864);   // 8 MB
  __bf16* hid   = (__bf16*)(ws + 75497472);   // 16 MB (aliased: vT during attention)
  __bf16* vT    = (__bf16*)(ws + 75497472);   // 8.4 MB, dead before hid is written
  __bf16* biasB = (__bf16*)(ws + 92274688);   // 16 MB
  __bf16* Wqkvt = (__bf16*)(ws + 109051904);
  __bf16* Wot   = (__bf16*)(ws + 109445120);
  __bf16* W1t   = (__bf16*)(ws + 109576192);
  __bf16* W2t   = (__bf16*)(ws + 109838336);  // ends 110100480
  if (ws_size < 110100480) return;            // visible failure instead of OOB

  prep_kernel<<<6144, 256, 0, stream>>>(Wqkv, Wo, W1, W2, Wqkvt, Wot, W1t, W2t,
                                        table, biasB);
  txln_kernel<<<dim3(32, 1, 16), 256, 0, stream>>>(x, ln1_g, ln1_b, t_bf, hln);
  gemmQKV_kernel<<<dim3(256, 6), 256, 0, stream>>>(hln, Wqkvt, qkv, vT);
  attn_kernel<<<dim3(4, 8, 16), 512, 0, stream>>>(qkv, vT, biasB, aout);
  gemmWoLn_kernel<<<512, 256, 0, stream>>>(aout, Wot, bo, t_bf, ln2_g, ln2_b, t2_bf, hln);
  gemmW1G_kernel<<<dim3(256, 4), 256, 0, stream>>>(hln, W1t, b1, hid);
  gemmW2T_kernel<<<256, 512, 0, stream>>>(hid, W2t, b2, t2_bf, (float*)d_out);
}

// Round 29
// 123.326 us; speedup vs baseline: 1.1366x; 1.0056x over previous
//
#include <hip/hip_runtime.h>
#include <hip/hip_bf16.h>
#include <math.h>

typedef __bf16 bfx4 __attribute__((ext_vector_type(4)));
typedef __bf16 bfx8 __attribute__((ext_vector_type(8)));
typedef float  f32x4 __attribute__((ext_vector_type(4)));

#define BATCH 16
#define NTOK  1024
#define CDIM  256
#define NHEAD 8
#define DHEAD 32
#define QKVD  768
#define INNER 256
#define SCALE 0.17677669529663687f
#define LOG2E 1.4426950408889634f

#if __has_builtin(__builtin_amdgcn_exp2f)
#define EXP2(x) __builtin_amdgcn_exp2f(x)
#else
#define EXP2(x) exp2f(x)
#endif

// ---- merged prep + txln: blocks 0..2047 weight cast, 2048..6143 bias gen,
// ---- 6144..6655 fused transpose+LN1 (independent work, co-scheduled).
__launch_bounds__(256)
__global__ void prepTx_kernel(const float* __restrict__ Wqkv, const float* __restrict__ Wo,
                              const float* __restrict__ W1, const float* __restrict__ W2,
                              __bf16* __restrict__ Wqkvt, __bf16* __restrict__ Wot,
                              __bf16* __restrict__ W1t, __bf16* __restrict__ W2t,
                              const float* __restrict__ table, __bf16* __restrict__ biasB,
                              const float* __restrict__ x, const float* __restrict__ g,
                              const float* __restrict__ bb, __bf16* __restrict__ tb,
                              __bf16* __restrict__ hln) {
  __shared__ float tile[256][33];
  const int bx = blockIdx.x, tt = threadIdx.x;
  if (bx < 2048) {
    int idx = bx * 256 + tt;
    const float* W; __bf16* Wt; int lk, Nn, off;
    if (idx < 196608)      { W = Wqkv; Wt = Wqkvt; lk = 8; Nn = 768; off = idx; }
    else if (idx < 262144) { W = Wo;   Wt = Wot;   lk = 8; Nn = 256; off = idx - 196608; }
    else if (idx < 393216) { W = W1;   Wt = W1t;   lk = 8; Nn = 512; off = idx - 262144; }
    else                   { W = W2;   Wt = W2t;   lk = 9; Nn = 256; off = idx - 393216; }
    int n = off >> lk, k = off & ((1 << lk) - 1);
    Wt[off] = (__bf16)W[(size_t)k * Nn + n];
    return;
  }
  if (bx < 6144) {
    int idx = (bx - 2048) * 256 + tt;            // h*2^17 + q*2^7 + k8
    int k8 = (idx & 127) * 8, q = (idx >> 7) & 1023, h = idx >> 17;
    int qi = q >> 5, qj = q & 31;
    bfx8 o;
    #pragma unroll
    for (int j = 0; j < 8; ++j) {
      int k = k8 + j, ki = k >> 5, kj = k & 31;
      int r = (qi - ki + 31) * 63 + (qj - kj + 31);
      o[j] = (__bf16)(table[r * 8 + h] * LOG2E);
    }
    *(bfx8*)&biasB[((size_t)idx) * 8] = o;
    return;
  }
  // ---- txln path ----
  const int bid2 = bx - 6144;
  const int b = bid2 >> 5, n0 = (bid2 & 31) * 32;
  const float* src = x + (size_t)b * CDIM * NTOK;
  #pragma unroll
  for (int i = 0; i < 8; ++i) {
    int cid = i * 256 + tt;
    int c = cid >> 3, col4 = (cid & 7) * 4;
    *(float4*)&tile[c][col4] = *(const float4*)&src[(size_t)c * NTOK + n0 + col4];
  }
  __syncthreads();
  const int n = tt >> 3, c0 = (tt & 7) * 32;     // 8 threads per token
  float vals[32];
  float s = 0.f, s2 = 0.f;
  #pragma unroll
  for (int j = 0; j < 32; ++j) {
    float v = tile[c0 + j][n];
    vals[j] = v; s += v; s2 += v * v;
  }
  s  += __shfl_xor(s, 1);  s  += __shfl_xor(s, 2);  s  += __shfl_xor(s, 4);
  s2 += __shfl_xor(s2, 1); s2 += __shfl_xor(s2, 2); s2 += __shfl_xor(s2, 4);
  float mu = s * 0.00390625f;
  float var = s2 * 0.00390625f - mu * mu;
  float rs = rsqrtf(var + 1e-5f);
  size_t row = ((size_t)b * NTOK + n0 + n) * CDIM;
  #pragma unroll
  for (int j = 0; j < 32; j += 4) {
    const float4 gg = *(const float4*)&g[c0 + j];
    const float4 bv = *(const float4*)&bb[c0 + j];
    bfx4 tv;
    tv[0] = (__bf16)vals[j];     tv[1] = (__bf16)vals[j + 1];
    tv[2] = (__bf16)vals[j + 2]; tv[3] = (__bf16)vals[j + 3];
    *(bfx4*)&tb[row + c0 + j] = tv;
    bfx4 o;
    o[0] = (__bf16)((vals[j]     - mu) * rs * gg.x + bv.x);
    o[1] = (__bf16)((vals[j + 1] - mu) * rs * gg.y + bv.y);
    o[2] = (__bf16)((vals[j + 2] - mu) * rs * gg.z + bv.z);
    o[3] = (__bf16)((vals[j + 3] - mu) * rs * gg.w + bv.w);
    *(bfx4*)&hln[row + c0 + j] = o;
  }
}

// ---- QKV GEMM (BM=64, BN=128, 256 thr): q/k -> qkv bf16, V -> vT scatter ---
__launch_bounds__(256)
__global__ void gemmQKV_kernel(const __bf16* __restrict__ A, const __bf16* __restrict__ Bt,
                               __bf16* __restrict__ outp, __bf16* __restrict__ vTout) {
  __shared__ char smem[27648];
  __bf16 (*As)[72] = (__bf16(*)[72])smem;             // 64 x 72
  __bf16 (*Bs)[72] = (__bf16(*)[72])(smem + 9216);    // 128 x 72
  const int t = threadIdx.x, lane = t & 63, w = t >> 6;
  const int m0 = blockIdx.x * 64, n0 = blockIdx.y * 128;
  const int wr = w >> 1, wc = w & 1;
  const int lr = lane & 15, kb = (lane >> 4) * 4;
  const int K = 256;
  int arow[2], ap0[2], ap1[2];
  #pragma unroll
  for (int i = 0; i < 2; ++i) {
    int cid = i * 256 + t, kb8 = (cid & 7) * 8;
    arow[i] = cid >> 3;
    int b0 = kb8, b1 = kb8 + 4;
    ap0[i] = (b0 & 32) + ((b0 & 12) << 1) + (((b0 >> 4) & 1) << 2) + (b0 & 3);
    ap1[i] = (b1 & 32) + ((b1 & 12) << 1) + (((b1 >> 4) & 1) << 2) + (b1 & 3);
  }
  int brow[4], bp0[4], bp1[4], bc8[4];
  #pragma unroll
  for (int j = 0; j < 4; ++j) {
    int cid = j * 256 + t;
    brow[j] = cid >> 3;
    bc8[j] = (cid & 7) * 8;
    int b0 = bc8[j], b1 = bc8[j] + 4;
    bp0[j] = (b0 & 32) + ((b0 & 12) << 1) + (((b0 >> 4) & 1) << 2) + (b0 & 3);
    bp1[j] = (b1 & 32) + ((b1 & 12) << 1) + (((b1 >> 4) & 1) << 2) + (b1 & 3);
  }
  f32x4 acc[2][4] = {};
  bfx8 ra[2], rb[4];
  auto gload = [&](int k0) {
    #pragma unroll
    for (int i = 0; i < 2; ++i) {
      int kc8 = ((i * 256 + t) & 7) * 8;
      ra[i] = *(const bfx8*)&A[(size_t)(m0 + arow[i]) * K + k0 + kc8];
    }
    #pragma unroll
    for (int j = 0; j < 4; ++j)
      rb[j] = *(const bfx8*)&Bt[(size_t)(n0 + brow[j]) * K + k0 + bc8[j]];
  };
  gload(0);
  for (int k0 = 0; k0 < K; k0 += 64) {
    __syncthreads();
    #pragma unroll
    for (int i = 0; i < 2; ++i) {
      *(bfx4*)&As[arow[i]][ap0[i]] = __builtin_shufflevector(ra[i], ra[i], 0, 1, 2, 3);
      *(bfx4*)&As[arow[i]][ap1[i]] = __builtin_shufflevector(ra[i], ra[i], 4, 5, 6, 7);
    }
    #pragma unroll
    for (int j = 0; j < 4; ++j) {
      *(bfx4*)&Bs[brow[j]][bp0[j]] = __builtin_shufflevector(rb[j], rb[j], 0, 1, 2, 3);
      *(bfx4*)&Bs[brow[j]][bp1[j]] = __builtin_shufflevector(rb[j], rb[j], 4, 5, 6, 7);
    }
    __syncthreads();
    if (k0 + 64 < K) gload(k0 + 64);
    #pragma unroll
    for (int ks = 0; ks < 2; ++ks) {
      bfx8 af[2], bf[4];
      #pragma unroll
      for (int mi = 0; mi < 2; ++mi)
        af[mi] = *(const bfx8*)&As[wr * 32 + mi * 16 + lr][ks * 32 + kb * 2];
      #pragma unroll
      for (int ni = 0; ni < 4; ++ni)
        bf[ni] = *(const bfx8*)&Bs[wc * 64 + ni * 16 + lr][ks * 32 + kb * 2];
      #pragma unroll
      for (int mi = 0; mi < 2; ++mi)
        #pragma unroll
        for (int ni = 0; ni < 4; ++ni)
          acc[mi][ni] = __builtin_amdgcn_mfma_f32_16x16x32_bf16(af[mi], bf[ni],
                                                                acc[mi][ni], 0, 0, 0);
    }
  }
  if (n0 >= 512) {
    #pragma unroll
    for (int mi = 0; mi < 2; ++mi)
      #pragma unroll
      for (int ni = 0; ni < 4; ++ni) {
        int n = n0 + wc * 64 + ni * 16 + lr;
        int cp = n - 512, hh = cp >> 5, dd = cp & 31;
        int m = m0 + wr * 32 + mi * 16 + kb;
        int bb_ = m >> 10, tok = m & 1023;
        bfx4 o;
        o[0] = (__bf16)acc[mi][ni][0]; o[1] = (__bf16)acc[mi][ni][1];
        o[2] = (__bf16)acc[mi][ni][2]; o[3] = (__bf16)acc[mi][ni][3];
        *(bfx4*)&vTout[(((size_t)bb_ * NHEAD + hh) * DHEAD + dd) * NTOK + tok] = o;
      }
    return;
  }
  #pragma unroll
  for (int mi = 0; mi < 2; ++mi)
    #pragma unroll
    for (int ni = 0; ni < 4; ++ni)
      #pragma unroll
      for (int r = 0; r < 4; ++r) {
        int m = m0 + wr * 32 + mi * 16 + kb + r;
        int n = n0 + wc * 64 + ni * 16 + lr;
        outp[(size_t)m * QKVD + n] = (__bf16)acc[mi][ni][r];
      }
}

// ---- W1 GEMM (BM=64, BN=128, 256 thr) + bias + GELU -> bf16 ----------------
__launch_bounds__(256)
__global__ void gemmW1G_kernel(const __bf16* __restrict__ A, const __bf16* __restrict__ Bt,
                               const float* __restrict__ bias, __bf16* __restrict__ outp) {
  __shared__ char smem[27648];
  __bf16 (*As)[72] = (__bf16(*)[72])smem;             // 64 x 72 (9.2 KB)
  __bf16 (*Bs)[72] = (__bf16(*)[72])(smem + 9216);    // 128 x 72 (18.4 KB)
  const int t = threadIdx.x, lane = t & 63, w = t >> 6;
  const int m0 = blockIdx.x * 64, n0 = blockIdx.y * 128;
  const int wr = w >> 1, wc = w & 1;
  const int lr = lane & 15, kb = (lane >> 4) * 4;
  const int K = 256, Nn = 512;
  int arow[2], ap0[2], ap1[2];
  #pragma unroll
  for (int i = 0; i < 2; ++i) {
    int cid = i * 256 + t, kb8 = (cid & 7) * 8;
    arow[i] = cid >> 3;
    int b0 = kb8, b1 = kb8 + 4;
    ap0[i] = (b0 & 32) + ((b0 & 12) << 1) + (((b0 >> 4) & 1) << 2) + (b0 & 3);
    ap1[i] = (b1 & 32) + ((b1 & 12) << 1) + (((b1 >> 4) & 1) << 2) + (b1 & 3);
  }
  int brow[4], bp0[4], bp1[4], bc8[4];
  #pragma unroll
  for (int j = 0; j < 4; ++j) {
    int cid = j * 256 + t;
    brow[j] = cid >> 3;
    bc8[j] = (cid & 7) * 8;
    int b0 = bc8[j], b1 = bc8[j] + 4;
    bp0[j] = (b0 & 32) + ((b0 & 12) << 1) + (((b0 >> 4) & 1) << 2) + (b0 & 3);
    bp1[j] = (b1 & 32) + ((b1 & 12) << 1) + (((b1 >> 4) & 1) << 2) + (b1 & 3);
  }
  f32x4 acc[2][4] = {};
  bfx8 ra[2], rb[4];
  auto gload = [&](int k0) {
    #pragma unroll
    for (int i = 0; i < 2; ++i) {
      int kc8 = ((i * 256 + t) & 7) * 8;
      ra[i] = *(const bfx8*)&A[(size_t)(m0 + arow[i]) * K + k0 + kc8];
    }
    #pragma unroll
    for (int j = 0; j < 4; ++j)
      rb[j] = *(const bfx8*)&Bt[(size_t)(n0 + brow[j]) * K + k0 + bc8[j]];
  };
  gload(0);
  for (int k0 = 0; k0 < K; k0 += 64) {
    __syncthreads();
    #pragma unroll
    for (int i = 0; i < 2; ++i) {
      *(bfx4*)&As[arow[i]][ap0[i]] = __builtin_shufflevector(ra[i], ra[i], 0, 1, 2, 3);
      *(bfx4*)&As[arow[i]][ap1[i]] = __builtin_shufflevector(ra[i], ra[i], 4, 5, 6, 7);
    }
    #pragma unroll
    for (int j = 0; j < 4; ++j) {
      *(bfx4*)&Bs[brow[j]][bp0[j]] = __builtin_shufflevector(rb[j], rb[j], 0, 1, 2, 3);
      *(bfx4*)&Bs[brow[j]][bp1[j]] = __builtin_shufflevector(rb[j], rb[j], 4, 5, 6, 7);
    }
    __syncthreads();
    if (k0 + 64 < K) gload(k0 + 64);
    #pragma unroll
    for (int ks = 0; ks < 2; ++ks) {
      bfx8 af[2], bf[4];
      #pragma unroll
      for (int mi = 0; mi < 2; ++mi)
        af[mi] = *(const bfx8*)&As[wr * 32 + mi * 16 + lr][ks * 32 + kb * 2];
      #pragma unroll
      for (int ni = 0; ni < 4; ++ni)
        bf[ni] = *(const bfx8*)&Bs[wc * 64 + ni * 16 + lr][ks * 32 + kb * 2];
      #pragma unroll
      for (int mi = 0; mi < 2; ++mi)
        #pragma unroll
        for (int ni = 0; ni < 4; ++ni)
          acc[mi][ni] = __builtin_amdgcn_mfma_f32_16x16x32_bf16(af[mi], bf[ni],
                                                                acc[mi][ni], 0, 0, 0);
    }
  }
  #pragma unroll
  for (int mi = 0; mi < 2; ++mi)
    #pragma unroll
    for (int ni = 0; ni < 4; ++ni) {
      int n = n0 + wc * 64 + ni * 16 + lr;
      float bn = bias[n];
      #pragma unroll
      for (int r = 0; r < 4; ++r) {
        int m = m0 + wr * 32 + mi * 16 + kb + r;
        float v = acc[mi][ni][r] + bn;
        v = 0.5f * v * (1.0f + erff(v * 0.70710678118f));
        outp[(size_t)m * Nn + n] = (__bf16)v;
      }
    }
}

// ---- Wo GEMM (BM=32, BN=256 full width, 256 thr) + bias + resid + LN2 ------
__launch_bounds__(256)
__global__ void gemmWoLn_kernel(const __bf16* __restrict__ A, const __bf16* __restrict__ Bt,
                                const float* __restrict__ bias,
                                const __bf16* __restrict__ residb,
                                const float* __restrict__ g2, const float* __restrict__ b2v,
                                __bf16* __restrict__ t2, __bf16* __restrict__ hln) {
  __shared__ char smem[41472];
  __bf16 (*As)[72] = (__bf16(*)[72])smem;             // 32 x 72 (4.6 KB)
  __bf16 (*Bs)[72] = (__bf16(*)[72])(smem + 4608);    // 256 x 72 (36.9 KB)
  const int t = threadIdx.x, lane = t & 63, w = t >> 6;   // 4 waves
  const int m0 = blockIdx.x * 32;
  const int lr = lane & 15, kb = (lane >> 4) * 4;
  const int K = 256;
  const int arow = t >> 3, ac8 = (t & 7) * 8;             // A: 32 rows x 64
  int ap0, ap1;
  {
    int b0 = ac8, b1 = ac8 + 4;
    ap0 = (b0 & 32) + ((b0 & 12) << 1) + (((b0 >> 4) & 1) << 2) + (b0 & 3);
    ap1 = (b1 & 32) + ((b1 & 12) << 1) + (((b1 >> 4) & 1) << 2) + (b1 & 3);
  }
  int brow[8], bp0[8], bp1[8], bc8[8];
  #pragma unroll
  for (int j = 0; j < 8; ++j) {
    int cid = j * 256 + t;
    brow[j] = cid >> 3;
    bc8[j] = (cid & 7) * 8;
    int b0 = bc8[j], b1 = bc8[j] + 4;
    bp0[j] = (b0 & 32) + ((b0 & 12) << 1) + (((b0 >> 4) & 1) << 2) + (b0 & 3);
    bp1[j] = (b1 & 32) + ((b1 & 12) << 1) + (((b1 >> 4) & 1) << 2) + (b1 & 3);
  }
  f32x4 acc[2][4] = {};
  bfx8 ra, rb[8];
  auto gload = [&](int k0) {
    ra = *(const bfx8*)&A[(size_t)(m0 + arow) * K + k0 + ac8];
    #pragma unroll
    for (int j = 0; j < 8; ++j)
      rb[j] = *(const bfx8*)&Bt[(size_t)brow[j] * K + k0 + bc8[j]];
  };
  gload(0);
  for (int k0 = 0; k0 < K; k0 += 64) {
    __syncthreads();
    *(bfx4*)&As[arow][ap0] = __builtin_shufflevector(ra, ra, 0, 1, 2, 3);
    *(bfx4*)&As[arow][ap1] = __builtin_shufflevector(ra, ra, 4, 5, 6, 7);
    #pragma unroll
    for (int j = 0; j < 8; ++j) {
      *(bfx4*)&Bs[brow[j]][bp0[j]] = __builtin_shufflevector(rb[j], rb[j], 0, 1, 2, 3);
      *(bfx4*)&Bs[brow[j]][bp1[j]] = __builtin_shufflevector(rb[j], rb[j], 4, 5, 6, 7);
    }
    __syncthreads();
    if (k0 + 64 < K) gload(k0 + 64);
    #pragma unroll
    for (int ks = 0; ks < 2; ++ks) {
      bfx8 af[2], bf[4];
      #pragma unroll
      for (int mi = 0; mi < 2; ++mi)
        af[mi] = *(const bfx8*)&As[mi * 16 + lr][ks * 32 + kb * 2];
      #pragma unroll
      for (int ni = 0; ni < 4; ++ni)
        bf[ni] = *(const bfx8*)&Bs[w * 64 + ni * 16 + lr][ks * 32 + kb * 2];
      #pragma unroll
      for (int mi = 0; mi < 2; ++mi)
        #pragma unroll
        for (int ni = 0; ni < 4; ++ni)
          acc[mi][ni] = __builtin_amdgcn_mfma_f32_16x16x32_bf16(af[mi], bf[ni],
                                                                acc[mi][ni], 0, 0, 0);
    }
  }
  float colg[4], colb[4];
  #pragma unroll
  for (int ni = 0; ni < 4; ++ni) {
    int colq = w * 64 + ni * 16 + lr;
    float bn = bias[colq];
    colg[ni] = g2[colq];
    colb[ni] = b2v[colq];
    #pragma unroll
    for (int mi = 0; mi < 2; ++mi)
      #pragma unroll
      for (int r = 0; r < 4; ++r) {
        int m = m0 + mi * 16 + kb + r;
        acc[mi][ni][r] += bn + (float)residb[(size_t)m * CDIM + colq];
      }
  }
  float ps[2][4], pq[2][4];
  #pragma unroll
  for (int mi = 0; mi < 2; ++mi)
    #pragma unroll
    for (int r = 0; r < 4; ++r) {
      float s = 0.f, q = 0.f;
      #pragma unroll
      for (int ni = 0; ni < 4; ++ni) {
        float v = acc[mi][ni][r];
        s += v; q += v * v;
      }
      #pragma unroll
      for (int o = 1; o < 16; o <<= 1) { s += __shfl_xor(s, o); q += __shfl_xor(q, o); }
      ps[mi][r] = s; pq[mi][r] = q;
    }
  __syncthreads();
  float* red = (float*)smem;              // [32][8]
  if (lr == 0) {
    #pragma unroll
    for (int mi = 0; mi < 2; ++mi)
      #pragma unroll
      for (int r = 0; r < 4; ++r) {
        int rl = mi * 16 + kb + r;
        red[rl * 8 + w] = ps[mi][r];
        red[rl * 8 + 4 + w] = pq[mi][r];
      }
  }
  __syncthreads();
  if (t < 32) {
    float s = red[t * 8] + red[t * 8 + 1] + red[t * 8 + 2] + red[t * 8 + 3];
    float q = red[t * 8 + 4] + red[t * 8 + 5] + red[t * 8 + 6] + red[t * 8 + 7];
    float mu = s * 0.00390625f;
    float var = q * 0.00390625f - mu * mu;
    red[t * 8] = mu;
    red[t * 8 + 1] = rsqrtf(var + 1e-5f);
  }
  __syncthreads();
  #pragma unroll
  for (int mi = 0; mi < 2; ++mi)
    #pragma unroll
    for (int r = 0; r < 4; ++r) {
      int rl = mi * 16 + kb + r;
      float mu = red[rl * 8], rs = red[rl * 8 + 1];
      size_t rowoff = (size_t)(m0 + rl) * CDIM;
      #pragma unroll
      for (int ni = 0; ni < 4; ++ni) {
        int colq = w * 64 + ni * 16 + lr;
        float v = acc[mi][ni][r];
        t2[rowoff + colq] = (__bf16)v;
        hln[rowoff + colq] = (__bf16)((v - mu) * rs * colg[ni] + colb[ni]);
      }
    }
}

// ---- W2 GEMM (BM=64, BN=256, K=512) + bias + resid, TRANSPOSED fp32 out ----
__launch_bounds__(512)
__global__ void gemmW2T_kernel(const __bf16* __restrict__ A, const __bf16* __restrict__ Bt,
                               const float* __restrict__ bias,
                               const __bf16* __restrict__ residb,
                               float* __restrict__ outp) {
  __shared__ char smem[46080];
  __bf16 (*As)[72] = (__bf16(*)[72])smem;             // 64 x 72
  __bf16 (*Bs)[72] = (__bf16(*)[72])(smem + 9216);    // 256 x 72
  const int t = threadIdx.x, lane = t & 63, w = t >> 6;
  const int m0 = blockIdx.x * 64;
  const int wr = w >> 2, wc = w & 3;
  const int lr = lane & 15, kb = (lane >> 4) * 4;
  const int K = 512;
  const int arow = t >> 3, ac8 = (t & 7) * 8;
  int ap0, ap1;
  {
    int b0 = ac8, b1 = ac8 + 4;
    ap0 = (b0 & 32) + ((b0 & 12) << 1) + (((b0 >> 4) & 1) << 2) + (b0 & 3);
    ap1 = (b1 & 32) + ((b1 & 12) << 1) + (((b1 >> 4) & 1) << 2) + (b1 & 3);
  }
  int brow[4], bp0[4], bp1[4], bc8[4];
  #pragma unroll
  for (int j = 0; j < 4; ++j) {
    int cid = j * 512 + t;
    brow[j] = cid >> 3;
    bc8[j] = (cid & 7) * 8;
    int b0 = bc8[j], b1 = bc8[j] + 4;
    bp0[j] = (b0 & 32) + ((b0 & 12) << 1) + (((b0 >> 4) & 1) << 2) + (b0 & 3);
    bp1[j] = (b1 & 32) + ((b1 & 12) << 1) + (((b1 >> 4) & 1) << 2) + (b1 & 3);
  }
  f32x4 acc[2][4] = {};
  bfx8 ra, rb[4];
  auto gload = [&](int k0) {
    ra = *(const bfx8*)&A[(size_t)(m0 + arow) * K + k0 + ac8];
    #pragma unroll
    for (int j = 0; j < 4; ++j)
      rb[j] = *(const bfx8*)&Bt[(size_t)brow[j] * K + k0 + bc8[j]];
  };
  gload(0);
  for (int k0 = 0; k0 < K; k0 += 64) {
    __syncthreads();
    *(bfx4*)&As[arow][ap0] = __builtin_shufflevector(ra, ra, 0, 1, 2, 3);
    *(bfx4*)&As[arow][ap1] = __builtin_shufflevector(ra, ra, 4, 5, 6, 7);
    #pragma unroll
    for (int j = 0; j < 4; ++j) {
      *(bfx4*)&Bs[brow[j]][bp0[j]] = __builtin_shufflevector(rb[j], rb[j], 0, 1, 2, 3);
      *(bfx4*)&Bs[brow[j]][bp1[j]] = __builtin_shufflevector(rb[j], rb[j], 4, 5, 6, 7);
    }
    __syncthreads();
    if (k0 + 64 < K) gload(k0 + 64);
    #pragma unroll
    for (int ks = 0; ks < 2; ++ks) {
      bfx8 af[2], bf[4];
      #pragma unroll
      for (int mi = 0; mi < 2; ++mi)
        af[mi] = *(const bfx8*)&As[wr * 32 + mi * 16 + lr][ks * 32 + kb * 2];
      #pragma unroll
      for (int ni = 0; ni < 4; ++ni)
        bf[ni] = *(const bfx8*)&Bs[wc * 64 + ni * 16 + lr][ks * 32 + kb * 2];
      #pragma unroll
      for (int mi = 0; mi < 2; ++mi)
        #pragma unroll
        for (int ni = 0; ni < 4; ++ni)
          acc[mi][ni] = __builtin_amdgcn_mfma_f32_16x16x32_bf16(af[mi], bf[ni],
                                                                acc[mi][ni], 0, 0, 0);
    }
  }
  const int bb_ = m0 >> 10, tok0 = m0 & 1023;
  float* obase = outp + (size_t)bb_ * CDIM * NTOK + tok0;
  float* Ty = (float*)smem;
  #pragma unroll
  for (int h2 = 0; h2 < 2; ++h2) {
    __syncthreads();
    if ((wc >> 1) == h2) {
      #pragma unroll
      for (int ni = 0; ni < 4; ++ni) {
        int colq = wc * 64 + ni * 16 + lr;
        int chl = colq - h2 * 128;
        float bn = bias[colq];
        #pragma unroll
        for (int mi = 0; mi < 2; ++mi) {
          int tk = wr * 32 + mi * 16 + kb;
          float4 v4;
          #pragma unroll
          for (int r = 0; r < 4; ++r)
            ((float*)&v4)[r] = acc[mi][ni][r] + bn +
                (float)residb[(size_t)(m0 + tk + r) * CDIM + colq];
          *(float4*)&Ty[chl * 68 + tk] = v4;
        }
      }
    }
    __syncthreads();
    int row = t >> 2, quad = t & 3;
    #pragma unroll
    for (int j = 0; j < 4; ++j) {
      int p = quad + j * 4;
      *(float4*)&obase[(size_t)(h2 * 128 + row) * NTOK + p * 4] =
          *(const float4*)&Ty[row * 68 + p * 4];
    }
  }
}

// -------- flash attention, QBLK=256, 8 waves (32 q-rows/wave) — R13 exact ---
__launch_bounds__(512)
__global__ void attn_kernel(const __bf16* __restrict__ qkv, const __bf16* __restrict__ vT,
                            const __bf16* __restrict__ biasB, __bf16* __restrict__ outb) {
  __shared__ __bf16 Ks[64][40];
  __shared__ __bf16 Vs[32][72];
  __shared__ __bf16 Bls[256][72];
  const int q0 = blockIdx.x * 256, h = blockIdx.y, b = blockIdx.z;
  const int t = threadIdx.x, lane = t & 63, w = t >> 6;     // 8 waves
  const int lr = lane & 15, kb = (lane >> 4) * 4;
  const size_t qbase = (size_t)b * NTOK * QKVD;
  const float qsc = SCALE * LOG2E;
  bfx8 qf[2];
  #pragma unroll
  for (int tq = 0; tq < 2; ++tq) {
    const __bf16* qp = &qkv[qbase + (size_t)(q0 + 32 * w + 16 * tq + lr) * QKVD + h * DHEAD];
    bfx4 lo = *(const bfx4*)&qp[kb];
    bfx4 hi = *(const bfx4*)&qp[kb + 16];
    #pragma unroll
    for (int j = 0; j < 4; ++j) {
      qf[tq][j]     = (__bf16)((float)lo[j] * qsc);
      qf[tq][j + 4] = (__bf16)((float)hi[j] * qsc);
    }
  }
  float l_run[2] = {0.f, 0.f};
  f32x4 oacc[2][2] = {};
  const int st_ = t & 255;
  const int krow = st_ >> 2, kc8 = (st_ & 3) * 8;   // K stage (t<256): 64x32
  const int vrow = st_ >> 3, vc8 = (st_ & 7) * 8;   // V stage (t>=256): 32x64
  const __bf16* kvptr = (t < 256)
      ? &qkv[qbase + (size_t)krow * QKVD + INNER + h * DHEAD + kc8]
      : &vT[(((size_t)b * NHEAD + h) * DHEAD + vrow) * NTOK + vc8];
  const __bf16* bbase = &biasB[((size_t)h * NTOK + q0) * NTOK];
  bfx8 rkv, rbias[4];
  auto issue = [&](int k0) {
    rkv = (t < 256) ? *(const bfx8*)&kvptr[(size_t)k0 * QKVD]
                    : *(const bfx8*)&kvptr[k0];
    #pragma unroll
    for (int j = 0; j < 4; ++j) {
      int lin = j * 512 + t;                  // 2048 chunks: 256 rows x 128B
      int br = lin >> 3, bc8 = (lin & 7) * 8;
      rbias[j] = *(const bfx8*)&bbase[(size_t)br * NTOK + k0 + bc8];
    }
  };
  issue(0);
  for (int kt = 0; kt < 16; ++kt) {
    __syncthreads();
    if (t < 256) *(bfx8*)&Ks[krow][kc8] = rkv;
    else         *(bfx8*)&Vs[vrow][vc8] = rkv;
    #pragma unroll
    for (int j = 0; j < 4; ++j) {
      int lin = j * 512 + t;
      int br = lin >> 3, bc8 = (lin & 7) * 8;
      *(bfx8*)&Bls[br][bc8] = rbias[j];
    }
    __syncthreads();
    if (kt < 15) issue((kt + 1) * 64);
    bfx8 kf[4], vfr[4];
    #pragma unroll
    for (int f = 0; f < 4; ++f) {
      bfx4 klo = *(const bfx4*)&Ks[16 * f + lr][kb];
      bfx4 khi = *(const bfx4*)&Ks[16 * f + lr][kb + 16];
      kf[f] = __builtin_shufflevector(klo, khi, 0, 1, 2, 3, 4, 5, 6, 7);
    }
    #pragma unroll
    for (int s = 0; s < 2; ++s)
      #pragma unroll
      for (int df = 0; df < 2; ++df) {
        bfx4 vlo = *(const bfx4*)&Vs[16 * df + lr][s * 32 + kb];
        bfx4 vhi = *(const bfx4*)&Vs[16 * df + lr][s * 32 + kb + 16];
        vfr[s * 2 + df] = __builtin_shufflevector(vlo, vhi, 0, 1, 2, 3, 4, 5, 6, 7);
      }
    #pragma unroll
    for (int tq = 0; tq < 2; ++tq) {
      const int qrow_l = 32 * w + 16 * tq + lr;
      f32x4 st[4];
      #pragma unroll
      for (int f = 0; f < 4; ++f) {
        bfx4 bv = *(const bfx4*)&Bls[qrow_l][16 * f + kb];
        f32x4 c;
        c[0] = (float)bv[0]; c[1] = (float)bv[1];
        c[2] = (float)bv[2]; c[3] = (float)bv[3];
        st[f] = __builtin_amdgcn_mfma_f32_16x16x32_bf16(kf[f], qf[tq], c, 0, 0, 0);
      }
      float p[4][4], tsum = 0.f;
      #pragma unroll
      for (int f = 0; f < 4; ++f)
        #pragma unroll
        for (int r = 0; r < 4; ++r) {
          float e = EXP2(st[f][r]);
          p[f][r] = e;
          tsum += e;
        }
      l_run[tq] += tsum;
      bfx8 pa0, pa1;
      #pragma unroll
      for (int r = 0; r < 4; ++r) {
        pa0[r] = (__bf16)p[0][r];  pa0[r + 4] = (__bf16)p[1][r];
        pa1[r] = (__bf16)p[2][r];  pa1[r + 4] = (__bf16)p[3][r];
      }
      #pragma unroll
      for (int s = 0; s < 2; ++s) {
        bfx8 pa = s ? pa1 : pa0;
        #pragma unroll
        for (int df = 0; df < 2; ++df)
          oacc[tq][df] = __builtin_amdgcn_mfma_f32_16x16x32_bf16(pa, vfr[s * 2 + df],
                                                                 oacc[tq][df], 0, 0, 0);
      }
    }
  }
  #pragma unroll
  for (int tq = 0; tq < 2; ++tq) {
    float l = l_run[tq];
    l += __shfl_xor(l, 16);
    l += __shfl_xor(l, 32);
    float il[4];
    #pragma unroll
    for (int r = 0; r < 4; ++r) il[r] = 1.f / __shfl(l, kb + r);
    #pragma unroll
    for (int r = 0; r < 4; ++r) {
      size_t rowoff = (size_t)b * NTOK * CDIM +
                      (size_t)(q0 + 32 * w + 16 * tq + kb + r) * CDIM + h * DHEAD;
      outb[rowoff + lr]      = (__bf16)(oacc[tq][0][r] * il[r]);
      outb[rowoff + 16 + lr] = (__bf16)(oacc[tq][1][r] * il[r]);
    }
  }
}

// ---------------------------------------------------------------------------
extern "C" void kernel_launch(void* const* d_in, const int* in_sizes, int n_in,
                              void* d_out, int out_size, void* d_ws, size_t ws_size,
                              hipStream_t stream) {
  const float* x     = (const float*)d_in[0];
  const float* ln1_g = (const float*)d_in[2];
  const float* ln1_b = (const float*)d_in[3];
  const float* Wqkv  = (const float*)d_in[4];
  const float* table = (const float*)d_in[5];
  const float* Wo    = (const float*)d_in[6];
  const float* bo    = (const float*)d_in[7];
  const float* ln2_g = (const float*)d_in[8];
  const float* ln2_b = (const float*)d_in[9];
  const float* W1    = (const float*)d_in[10];
  const float* b1    = (const float*)d_in[11];
  const float* W2    = (const float*)d_in[12];
  const float* b2    = (const float*)d_in[13];

  char* ws = (char*)d_ws;
  __bf16* t_bf  = (__bf16*)(ws + 0);          // 8 MB residual 1 (bf16)
  __bf16* t2_bf = (__bf16*)(ws + 8388608);    // 8 MB residual 2 (bf16)
  __bf16* qkv   = (__bf16*)(ws + 33554432);   // 24 MB
  __bf16* hln   = (__bf16*)(ws + 58720256);   // 8 MB (ln1 out, reused for ln2)
  __bf16* aout  = (__bf16*)(ws + 67108864);   // 8 MB
  __bf16* hid   = (__bf16*)(ws + 75497472);   // 16 MB (aliased: vT during attention)
  __bf16* vT    = (__bf16*)(ws + 75497472);   // 8.4 MB, dead before hid is written
  __bf16* biasB = (__bf16*)(ws + 92274688);   // 16 MB
  __bf16* Wqkvt = (__bf16*)(ws + 109051904);
  __bf16* Wot   = (__bf16*)(ws + 109445120);
  __bf16* W1t   = (__bf16*)(ws + 109576192);
  __bf16* W2t   = (__bf16*)(ws + 109838336);  // ends 110100480
  if (ws_size < 110100480) return;            // visible failure instead of OOB

  prepTx_kernel<<<6656, 256, 0, stream>>>(Wqkv, Wo, W1, W2, Wqkvt, Wot, W1t, W2t,
                                          table, biasB, x, ln1_g, ln1_b, t_bf, hln);
  gemmQKV_kernel<<<dim3(256, 6), 256, 0, stream>>>(hln, Wqkvt, qkv, vT);
  attn_kernel<<<dim3(4, 8, 16), 512, 0, stream>>>(qkv, vT, biasB, aout);
  gemmWoLn_kernel<<<512, 256, 0, stream>>>(aout, Wot, bo, t_bf, ln2_g, ln2_b, t2_bf, hln);
  gemmW1G_kernel<<<dim3(256, 4), 256, 0, stream>>>(hln, W1t, b1, hid);
  gemmW2T_kernel<<<256, 512, 0, stream>>>(hid, W2t, b2, t2_bf, (float*)d_out);
}

// Round 30
// 122.933 us; speedup vs baseline: 1.1402x; 1.0032x over previous
//
#include <hip/hip_runtime.h>
#include <hip/hip_bf16.h>
#include <math.h>

typedef __bf16 bfx4 __attribute__((ext_vector_type(4)));
typedef __bf16 bfx8 __attribute__((ext_vector_type(8)));
typedef float  f32x4 __attribute__((ext_vector_type(4)));

#define BATCH 16
#define NTOK  1024
#define CDIM  256
#define NHEAD 8
#define DHEAD 32
#define QKVD  768
#define INNER 256
#define SCALE 0.17677669529663687f
#define LOG2E 1.4426950408889634f

#if __has_builtin(__builtin_amdgcn_exp2f)
#define EXP2(x) __builtin_amdgcn_exp2f(x)
#else
#define EXP2(x) exp2f(x)
#endif

// ---- merged prep + txln: blocks 0..2047 weight cast, 2048..6143 bias gen,
// ---- 6144..6655 fused transpose+LN1 (independent work, co-scheduled).
__launch_bounds__(256)
__global__ void prepTx_kernel(const float* __restrict__ Wqkv, const float* __restrict__ Wo,
                              const float* __restrict__ W1, const float* __restrict__ W2,
                              __bf16* __restrict__ Wqkvt, __bf16* __restrict__ Wot,
                              __bf16* __restrict__ W1t, __bf16* __restrict__ W2t,
                              const float* __restrict__ table, __bf16* __restrict__ biasB,
                              const float* __restrict__ x, const float* __restrict__ g,
                              const float* __restrict__ bb, __bf16* __restrict__ tb,
                              __bf16* __restrict__ hln) {
  __shared__ float tile[256][33];
  const int bx = blockIdx.x, tt = threadIdx.x;
  if (bx < 2048) {
    int idx = bx * 256 + tt;
    const float* W; __bf16* Wt; int lk, Nn, off;
    if (idx < 196608)      { W = Wqkv; Wt = Wqkvt; lk = 8; Nn = 768; off = idx; }
    else if (idx < 262144) { W = Wo;   Wt = Wot;   lk = 8; Nn = 256; off = idx - 196608; }
    else if (idx < 393216) { W = W1;   Wt = W1t;   lk = 8; Nn = 512; off = idx - 262144; }
    else                   { W = W2;   Wt = W2t;   lk = 9; Nn = 256; off = idx - 393216; }
    int n = off >> lk, k = off & ((1 << lk) - 1);
    Wt[off] = (__bf16)W[(size_t)k * Nn + n];
    return;
  }
  if (bx < 6144) {
    int idx = (bx - 2048) * 256 + tt;            // h*2^17 + q*2^7 + k8
    int k8 = (idx & 127) * 8, q = (idx >> 7) & 1023, h = idx >> 17;
    int qi = q >> 5, qj = q & 31;
    bfx8 o;
    #pragma unroll
    for (int j = 0; j < 8; ++j) {
      int k = k8 + j, ki = k >> 5, kj = k & 31;
      int r = (qi - ki + 31) * 63 + (qj - kj + 31);
      o[j] = (__bf16)(table[r * 8 + h] * LOG2E);
    }
    *(bfx8*)&biasB[((size_t)idx) * 8] = o;
    return;
  }
  // ---- txln path ----
  const int bid2 = bx - 6144;
  const int b = bid2 >> 5, n0 = (bid2 & 31) * 32;
  const float* src = x + (size_t)b * CDIM * NTOK;
  #pragma unroll
  for (int i = 0; i < 8; ++i) {
    int cid = i * 256 + tt;
    int c = cid >> 3, col4 = (cid & 7) * 4;
    *(float4*)&tile[c][col4] = *(const float4*)&src[(size_t)c * NTOK + n0 + col4];
  }
  __syncthreads();
  const int n = tt >> 3, c0 = (tt & 7) * 32;     // 8 threads per token
  float vals[32];
  float s = 0.f, s2 = 0.f;
  #pragma unroll
  for (int j = 0; j < 32; ++j) {
    float v = tile[c0 + j][n];
    vals[j] = v; s += v; s2 += v * v;
  }
  s  += __shfl_xor(s, 1);  s  += __shfl_xor(s, 2);  s  += __shfl_xor(s, 4);
  s2 += __shfl_xor(s2, 1); s2 += __shfl_xor(s2, 2); s2 += __shfl_xor(s2, 4);
  float mu = s * 0.00390625f;
  float var = s2 * 0.00390625f - mu * mu;
  float rs = rsqrtf(var + 1e-5f);
  size_t row = ((size_t)b * NTOK + n0 + n) * CDIM;
  #pragma unroll
  for (int j = 0; j < 32; j += 4) {
    const float4 gg = *(const float4*)&g[c0 + j];
    const float4 bv = *(const float4*)&bb[c0 + j];
    bfx4 tv;
    tv[0] = (__bf16)vals[j];     tv[1] = (__bf16)vals[j + 1];
    tv[2] = (__bf16)vals[j + 2]; tv[3] = (__bf16)vals[j + 3];
    *(bfx4*)&tb[row + c0 + j] = tv;
    bfx4 o;
    o[0] = (__bf16)((vals[j]     - mu) * rs * gg.x + bv.x);
    o[1] = (__bf16)((vals[j + 1] - mu) * rs * gg.y + bv.y);
    o[2] = (__bf16)((vals[j + 2] - mu) * rs * gg.z + bv.z);
    o[3] = (__bf16)((vals[j + 3] - mu) * rs * gg.w + bv.w);
    *(bfx4*)&hln[row + c0 + j] = o;
  }
}

// ---- QKV GEMM (BM=64, BN=128, 256 thr): q/k -> qkv bf16, V -> vT scatter ---
__launch_bounds__(256)
__global__ void gemmQKV_kernel(const __bf16* __restrict__ A, const __bf16* __restrict__ Bt,
                               __bf16* __restrict__ outp, __bf16* __restrict__ vTout) {
  __shared__ char smem[27648];
  __bf16 (*As)[72] = (__bf16(*)[72])smem;             // 64 x 72
  __bf16 (*Bs)[72] = (__bf16(*)[72])(smem + 9216);    // 128 x 72
  const int t = threadIdx.x, lane = t & 63, w = t >> 6;
  const int m0 = blockIdx.x * 64, n0 = blockIdx.y * 128;
  const int wr = w >> 1, wc = w & 1;
  const int lr = lane & 15, kb = (lane >> 4) * 4;
  const int K = 256;
  int arow[2], ap0[2], ap1[2];
  #pragma unroll
  for (int i = 0; i < 2; ++i) {
    int cid = i * 256 + t, kb8 = (cid & 7) * 8;
    arow[i] = cid >> 3;
    int b0 = kb8, b1 = kb8 + 4;
    ap0[i] = (b0 & 32) + ((b0 & 12) << 1) + (((b0 >> 4) & 1) << 2) + (b0 & 3);
    ap1[i] = (b1 & 32) + ((b1 & 12) << 1) + (((b1 >> 4) & 1) << 2) + (b1 & 3);
  }
  int brow[4], bp0[4], bp1[4], bc8[4];
  #pragma unroll
  for (int j = 0; j < 4; ++j) {
    int cid = j * 256 + t;
    brow[j] = cid >> 3;
    bc8[j] = (cid & 7) * 8;
    int b0 = bc8[j], b1 = bc8[j] + 4;
    bp0[j] = (b0 & 32) + ((b0 & 12) << 1) + (((b0 >> 4) & 1) << 2) + (b0 & 3);
    bp1[j] = (b1 & 32) + ((b1 & 12) << 1) + (((b1 >> 4) & 1) << 2) + (b1 & 3);
  }
  f32x4 acc[2][4] = {};
  bfx8 ra[2], rb[4];
  auto gload = [&](int k0) {
    #pragma unroll
    for (int i = 0; i < 2; ++i) {
      int kc8 = ((i * 256 + t) & 7) * 8;
      ra[i] = *(const bfx8*)&A[(size_t)(m0 + arow[i]) * K + k0 + kc8];
    }
    #pragma unroll
    for (int j = 0; j < 4; ++j)
      rb[j] = *(const bfx8*)&Bt[(size_t)(n0 + brow[j]) * K + k0 + bc8[j]];
  };
  gload(0);
  for (int k0 = 0; k0 < K; k0 += 64) {
    __syncthreads();
    #pragma unroll
    for (int i = 0; i < 2; ++i) {
      *(bfx4*)&As[arow[i]][ap0[i]] = __builtin_shufflevector(ra[i], ra[i], 0, 1, 2, 3);
      *(bfx4*)&As[arow[i]][ap1[i]] = __builtin_shufflevector(ra[i], ra[i], 4, 5, 6, 7);
    }
    #pragma unroll
    for (int j = 0; j < 4; ++j) {
      *(bfx4*)&Bs[brow[j]][bp0[j]] = __builtin_shufflevector(rb[j], rb[j], 0, 1, 2, 3);
      *(bfx4*)&Bs[brow[j]][bp1[j]] = __builtin_shufflevector(rb[j], rb[j], 4, 5, 6, 7);
    }
    __syncthreads();
    if (k0 + 64 < K) gload(k0 + 64);
    #pragma unroll
    for (int ks = 0; ks < 2; ++ks) {
      bfx8 af[2], bf[4];
      #pragma unroll
      for (int mi = 0; mi < 2; ++mi)
        af[mi] = *(const bfx8*)&As[wr * 32 + mi * 16 + lr][ks * 32 + kb * 2];
      #pragma unroll
      for (int ni = 0; ni < 4; ++ni)
        bf[ni] = *(const bfx8*)&Bs[wc * 64 + ni * 16 + lr][ks * 32 + kb * 2];
      #pragma unroll
      for (int mi = 0; mi < 2; ++mi)
        #pragma unroll
        for (int ni = 0; ni < 4; ++ni)
          acc[mi][ni] = __builtin_amdgcn_mfma_f32_16x16x32_bf16(af[mi], bf[ni],
                                                                acc[mi][ni], 0, 0, 0);
    }
  }
  if (n0 >= 512) {
    #pragma unroll
    for (int mi = 0; mi < 2; ++mi)
      #pragma unroll
      for (int ni = 0; ni < 4; ++ni) {
        int n = n0 + wc * 64 + ni * 16 + lr;
        int cp = n - 512, hh = cp >> 5, dd = cp & 31;
        int m = m0 + wr * 32 + mi * 16 + kb;
        int bb_ = m >> 10, tok = m & 1023;
        bfx4 o;
        o[0] = (__bf16)acc[mi][ni][0]; o[1] = (__bf16)acc[mi][ni][1];
        o[2] = (__bf16)acc[mi][ni][2]; o[3] = (__bf16)acc[mi][ni][3];
        *(bfx4*)&vTout[(((size_t)bb_ * NHEAD + hh) * DHEAD + dd) * NTOK + tok] = o;
      }
    return;
  }
  #pragma unroll
  for (int mi = 0; mi < 2; ++mi)
    #pragma unroll
    for (int ni = 0; ni < 4; ++ni)
      #pragma unroll
      for (int r = 0; r < 4; ++r) {
        int m = m0 + wr * 32 + mi * 16 + kb + r;
        int n = n0 + wc * 64 + ni * 16 + lr;
        outp[(size_t)m * QKVD + n] = (__bf16)acc[mi][ni][r];
      }
}

// ---- W1 GEMM (BM=64, BN=128, 256 thr) + bias + GELU -> bf16 ----------------
__launch_bounds__(256)
__global__ void gemmW1G_kernel(const __bf16* __restrict__ A, const __bf16* __restrict__ Bt,
                               const float* __restrict__ bias, __bf16* __restrict__ outp) {
  __shared__ char smem[27648];
  __bf16 (*As)[72] = (__bf16(*)[72])smem;             // 64 x 72 (9.2 KB)
  __bf16 (*Bs)[72] = (__bf16(*)[72])(smem + 9216);    // 128 x 72 (18.4 KB)
  const int t = threadIdx.x, lane = t & 63, w = t >> 6;
  const int m0 = blockIdx.x * 64, n0 = blockIdx.y * 128;
  const int wr = w >> 1, wc = w & 1;
  const int lr = lane & 15, kb = (lane >> 4) * 4;
  const int K = 256, Nn = 512;
  int arow[2], ap0[2], ap1[2];
  #pragma unroll
  for (int i = 0; i < 2; ++i) {
    int cid = i * 256 + t, kb8 = (cid & 7) * 8;
    arow[i] = cid >> 3;
    int b0 = kb8, b1 = kb8 + 4;
    ap0[i] = (b0 & 32) + ((b0 & 12) << 1) + (((b0 >> 4) & 1) << 2) + (b0 & 3);
    ap1[i] = (b1 & 32) + ((b1 & 12) << 1) + (((b1 >> 4) & 1) << 2) + (b1 & 3);
  }
  int brow[4], bp0[4], bp1[4], bc8[4];
  #pragma unroll
  for (int j = 0; j < 4; ++j) {
    int cid = j * 256 + t;
    brow[j] = cid >> 3;
    bc8[j] = (cid & 7) * 8;
    int b0 = bc8[j], b1 = bc8[j] + 4;
    bp0[j] = (b0 & 32) + ((b0 & 12) << 1) + (((b0 >> 4) & 1) << 2) + (b0 & 3);
    bp1[j] = (b1 & 32) + ((b1 & 12) << 1) + (((b1 >> 4) & 1) << 2) + (b1 & 3);
  }
  f32x4 acc[2][4] = {};
  bfx8 ra[2], rb[4];
  auto gload = [&](int k0) {
    #pragma unroll
    for (int i = 0; i < 2; ++i) {
      int kc8 = ((i * 256 + t) & 7) * 8;
      ra[i] = *(const bfx8*)&A[(size_t)(m0 + arow[i]) * K + k0 + kc8];
    }
    #pragma unroll
    for (int j = 0; j < 4; ++j)
      rb[j] = *(const bfx8*)&Bt[(size_t)(n0 + brow[j]) * K + k0 + bc8[j]];
  };
  gload(0);
  for (int k0 = 0; k0 < K; k0 += 64) {
    __syncthreads();
    #pragma unroll
    for (int i = 0; i < 2; ++i) {
      *(bfx4*)&As[arow[i]][ap0[i]] = __builtin_shufflevector(ra[i], ra[i], 0, 1, 2, 3);
      *(bfx4*)&As[arow[i]][ap1[i]] = __builtin_shufflevector(ra[i], ra[i], 4, 5, 6, 7);
    }
    #pragma unroll
    for (int j = 0; j < 4; ++j) {
      *(bfx4*)&Bs[brow[j]][bp0[j]] = __builtin_shufflevector(rb[j], rb[j], 0, 1, 2, 3);
      *(bfx4*)&Bs[brow[j]][bp1[j]] = __builtin_shufflevector(rb[j], rb[j], 4, 5, 6, 7);
    }
    __syncthreads();
    if (k0 + 64 < K) gload(k0 + 64);
    #pragma unroll
    for (int ks = 0; ks < 2; ++ks) {
      bfx8 af[2], bf[4];
      #pragma unroll
      for (int mi = 0; mi < 2; ++mi)
        af[mi] = *(const bfx8*)&As[wr * 32 + mi * 16 + lr][ks * 32 + kb * 2];
      #pragma unroll
      for (int ni = 0; ni < 4; ++ni)
        bf[ni] = *(const bfx8*)&Bs[wc * 64 + ni * 16 + lr][ks * 32 + kb * 2];
      #pragma unroll
      for (int mi = 0; mi < 2; ++mi)
        #pragma unroll
        for (int ni = 0; ni < 4; ++ni)
          acc[mi][ni] = __builtin_amdgcn_mfma_f32_16x16x32_bf16(af[mi], bf[ni],
                                                                acc[mi][ni], 0, 0, 0);
    }
  }
  #pragma unroll
  for (int mi = 0; mi < 2; ++mi)
    #pragma unroll
    for (int ni = 0; ni < 4; ++ni) {
      int n = n0 + wc * 64 + ni * 16 + lr;
      float bn = bias[n];
      #pragma unroll
      for (int r = 0; r < 4; ++r) {
        int m = m0 + wr * 32 + mi * 16 + kb + r;
        float v = acc[mi][ni][r] + bn;
        v = 0.5f * v * (1.0f + erff(v * 0.70710678118f));
        outp[(size_t)m * Nn + n] = (__bf16)v;
      }
    }
}

// ---- Wo GEMM (BM=32, BN=256 full width, 256 thr) + bias + resid + LN2 ------
__launch_bounds__(256)
__global__ void gemmWoLn_kernel(const __bf16* __restrict__ A, const __bf16* __restrict__ Bt,
                                const float* __restrict__ bias,
                                const __bf16* __restrict__ residb,
                                const float* __restrict__ g2, const float* __restrict__ b2v,
                                __bf16* __restrict__ t2, __bf16* __restrict__ hln) {
  __shared__ char smem[41472];
  __bf16 (*As)[72] = (__bf16(*)[72])smem;             // 32 x 72 (4.6 KB)
  __bf16 (*Bs)[72] = (__bf16(*)[72])(smem + 4608);    // 256 x 72 (36.9 KB)
  const int t = threadIdx.x, lane = t & 63, w = t >> 6;   // 4 waves
  const int m0 = blockIdx.x * 32;
  const int lr = lane & 15, kb = (lane >> 4) * 4;
  const int K = 256;
  const int arow = t >> 3, ac8 = (t & 7) * 8;             // A: 32 rows x 64
  int ap0, ap1;
  {
    int b0 = ac8, b1 = ac8 + 4;
    ap0 = (b0 & 32) + ((b0 & 12) << 1) + (((b0 >> 4) & 1) << 2) + (b0 & 3);
    ap1 = (b1 & 32) + ((b1 & 12) << 1) + (((b1 >> 4) & 1) << 2) + (b1 & 3);
  }
  int brow[8], bp0[8], bp1[8], bc8[8];
  #pragma unroll
  for (int j = 0; j < 8; ++j) {
    int cid = j * 256 + t;
    brow[j] = cid >> 3;
    bc8[j] = (cid & 7) * 8;
    int b0 = bc8[j], b1 = bc8[j] + 4;
    bp0[j] = (b0 & 32) + ((b0 & 12) << 1) + (((b0 >> 4) & 1) << 2) + (b0 & 3);
    bp1[j] = (b1 & 32) + ((b1 & 12) << 1) + (((b1 >> 4) & 1) << 2) + (b1 & 3);
  }
  f32x4 acc[2][4] = {};
  bfx8 ra, rb[8];
  auto gload = [&](int k0) {
    ra = *(const bfx8*)&A[(size_t)(m0 + arow) * K + k0 + ac8];
    #pragma unroll
    for (int j = 0; j < 8; ++j)
      rb[j] = *(const bfx8*)&Bt[(size_t)brow[j] * K + k0 + bc8[j]];
  };
  gload(0);
  for (int k0 = 0; k0 < K; k0 += 64) {
    __syncthreads();
    *(bfx4*)&As[arow][ap0] = __builtin_shufflevector(ra, ra, 0, 1, 2, 3);
    *(bfx4*)&As[arow][ap1] = __builtin_shufflevector(ra, ra, 4, 5, 6, 7);
    #pragma unroll
    for (int j = 0; j < 8; ++j) {
      *(bfx4*)&Bs[brow[j]][bp0[j]] = __builtin_shufflevector(rb[j], rb[j], 0, 1, 2, 3);
      *(bfx4*)&Bs[brow[j]][bp1[j]] = __builtin_shufflevector(rb[j], rb[j], 4, 5, 6, 7);
    }
    __syncthreads();
    if (k0 + 64 < K) gload(k0 + 64);
    #pragma unroll
    for (int ks = 0; ks < 2; ++ks) {
      bfx8 af[2], bf[4];
      #pragma unroll
      for (int mi = 0; mi < 2; ++mi)
        af[mi] = *(const bfx8*)&As[mi * 16 + lr][ks * 32 + kb * 2];
      #pragma unroll
      for (int ni = 0; ni < 4; ++ni)
        bf[ni] = *(const bfx8*)&Bs[w * 64 + ni * 16 + lr][ks * 32 + kb * 2];
      #pragma unroll
      for (int mi = 0; mi < 2; ++mi)
        #pragma unroll
        for (int ni = 0; ni < 4; ++ni)
          acc[mi][ni] = __builtin_amdgcn_mfma_f32_16x16x32_bf16(af[mi], bf[ni],
                                                                acc[mi][ni], 0, 0, 0);
    }
  }
  float colg[4], colb[4];
  #pragma unroll
  for (int ni = 0; ni < 4; ++ni) {
    int colq = w * 64 + ni * 16 + lr;
    float bn = bias[colq];
    colg[ni] = g2[colq];
    colb[ni] = b2v[colq];
    #pragma unroll
    for (int mi = 0; mi < 2; ++mi)
      #pragma unroll
      for (int r = 0; r < 4; ++r) {
        int m = m0 + mi * 16 + kb + r;
        acc[mi][ni][r] += bn + (float)residb[(size_t)m * CDIM + colq];
      }
  }
  float ps[2][4], pq[2][4];
  #pragma unroll
  for (int mi = 0; mi < 2; ++mi)
    #pragma unroll
    for (int r = 0; r < 4; ++r) {
      float s = 0.f, q = 0.f;
      #pragma unroll
      for (int ni = 0; ni < 4; ++ni) {
        float v = acc[mi][ni][r];
        s += v; q += v * v;
      }
      #pragma unroll
      for (int o = 1; o < 16; o <<= 1) { s += __shfl_xor(s, o); q += __shfl_xor(q, o); }
      ps[mi][r] = s; pq[mi][r] = q;
    }
  __syncthreads();
  float* red = (float*)smem;              // [32][8]
  if (lr == 0) {
    #pragma unroll
    for (int mi = 0; mi < 2; ++mi)
      #pragma unroll
      for (int r = 0; r < 4; ++r) {
        int rl = mi * 16 + kb + r;
        red[rl * 8 + w] = ps[mi][r];
        red[rl * 8 + 4 + w] = pq[mi][r];
      }
  }
  __syncthreads();
  if (t < 32) {
    float s = red[t * 8] + red[t * 8 + 1] + red[t * 8 + 2] + red[t * 8 + 3];
    float q = red[t * 8 + 4] + red[t * 8 + 5] + red[t * 8 + 6] + red[t * 8 + 7];
    float mu = s * 0.00390625f;
    float var = q * 0.00390625f - mu * mu;
    red[t * 8] = mu;
    red[t * 8 + 1] = rsqrtf(var + 1e-5f);
  }
  __syncthreads();
  #pragma unroll
  for (int mi = 0; mi < 2; ++mi)
    #pragma unroll
    for (int r = 0; r < 4; ++r) {
      int rl = mi * 16 + kb + r;
      float mu = red[rl * 8], rs = red[rl * 8 + 1];
      size_t rowoff = (size_t)(m0 + rl) * CDIM;
      #pragma unroll
      for (int ni = 0; ni < 4; ++ni) {
        int colq = w * 64 + ni * 16 + lr;
        float v = acc[mi][ni][r];
        t2[rowoff + colq] = (__bf16)v;
        hln[rowoff + colq] = (__bf16)((v - mu) * rs * colg[ni] + colb[ni]);
      }
    }
}

// ---- W2 GEMM (BM=32, BN=256, K=512, 256 thr) + bias + resid, transposed ----
// LDS 41.5 KB -> 3 blocks/CU at grid 512 (12 waves/CU vs old 8).
__launch_bounds__(256)
__global__ void gemmW2T_kernel(const __bf16* __restrict__ A, const __bf16* __restrict__ Bt,
                               const float* __restrict__ bias,
                               const __bf16* __restrict__ residb,
                               float* __restrict__ outp) {
  __shared__ char smem[41472];
  __bf16 (*As)[72] = (__bf16(*)[72])smem;             // 32 x 72 (4.6 KB)
  __bf16 (*Bs)[72] = (__bf16(*)[72])(smem + 4608);    // 256 x 72 (36.9 KB)
  const int t = threadIdx.x, lane = t & 63, w = t >> 6;   // 4 waves
  const int m0 = blockIdx.x * 32;
  const int lr = lane & 15, kb = (lane >> 4) * 4;
  const int K = 512;
  const int arow = t >> 3, ac8 = (t & 7) * 8;             // A: 32 rows x 64
  int ap0, ap1;
  {
    int b0 = ac8, b1 = ac8 + 4;
    ap0 = (b0 & 32) + ((b0 & 12) << 1) + (((b0 >> 4) & 1) << 2) + (b0 & 3);
    ap1 = (b1 & 32) + ((b1 & 12) << 1) + (((b1 >> 4) & 1) << 2) + (b1 & 3);
  }
  int brow[8], bp0[8], bp1[8], bc8[8];
  #pragma unroll
  for (int j = 0; j < 8; ++j) {
    int cid = j * 256 + t;
    brow[j] = cid >> 3;
    bc8[j] = (cid & 7) * 8;
    int b0 = bc8[j], b1 = bc8[j] + 4;
    bp0[j] = (b0 & 32) + ((b0 & 12) << 1) + (((b0 >> 4) & 1) << 2) + (b0 & 3);
    bp1[j] = (b1 & 32) + ((b1 & 12) << 1) + (((b1 >> 4) & 1) << 2) + (b1 & 3);
  }
  f32x4 acc[2][4] = {};
  bfx8 ra, rb[8];
  auto gload = [&](int k0) {
    ra = *(const bfx8*)&A[(size_t)(m0 + arow) * K + k0 + ac8];
    #pragma unroll
    for (int j = 0; j < 8; ++j)
      rb[j] = *(const bfx8*)&Bt[(size_t)brow[j] * K + k0 + bc8[j]];
  };
  gload(0);
  for (int k0 = 0; k0 < K; k0 += 64) {
    __syncthreads();
    *(bfx4*)&As[arow][ap0] = __builtin_shufflevector(ra, ra, 0, 1, 2, 3);
    *(bfx4*)&As[arow][ap1] = __builtin_shufflevector(ra, ra, 4, 5, 6, 7);
    #pragma unroll
    for (int j = 0; j < 8; ++j) {
      *(bfx4*)&Bs[brow[j]][bp0[j]] = __builtin_shufflevector(rb[j], rb[j], 0, 1, 2, 3);
      *(bfx4*)&Bs[brow[j]][bp1[j]] = __builtin_shufflevector(rb[j], rb[j], 4, 5, 6, 7);
    }
    __syncthreads();
    if (k0 + 64 < K) gload(k0 + 64);
    #pragma unroll
    for (int ks = 0; ks < 2; ++ks) {
      bfx8 af[2], bf[4];
      #pragma unroll
      for (int mi = 0; mi < 2; ++mi)
        af[mi] = *(const bfx8*)&As[mi * 16 + lr][ks * 32 + kb * 2];
      #pragma unroll
      for (int ni = 0; ni < 4; ++ni)
        bf[ni] = *(const bfx8*)&Bs[w * 64 + ni * 16 + lr][ks * 32 + kb * 2];
      #pragma unroll
      for (int mi = 0; mi < 2; ++mi)
        #pragma unroll
        for (int ni = 0; ni < 4; ++ni)
          acc[mi][ni] = __builtin_amdgcn_mfma_f32_16x16x32_bf16(af[mi], bf[ni],
                                                                acc[mi][ni], 0, 0, 0);
    }
  }
  // epilogue: v = acc + bias + resid -> Ty[256 ch][36 tok] -> coalesced store
  float* Ty = (float*)smem;               // 36.9 KB, reuses staging space
  __syncthreads();                        // staging reads done
  #pragma unroll
  for (int ni = 0; ni < 4; ++ni) {
    int colq = w * 64 + ni * 16 + lr;
    float bn = bias[colq];
    #pragma unroll
    for (int mi = 0; mi < 2; ++mi) {
      int tk = mi * 16 + kb;
      float4 v4;
      #pragma unroll
      for (int r = 0; r < 4; ++r)
        ((float*)&v4)[r] = acc[mi][ni][r] + bn +
            (float)residb[(size_t)(m0 + tk + r) * CDIM + colq];
      *(float4*)&Ty[colq * 36 + tk] = v4;
    }
  }
  __syncthreads();
  const int bb_ = m0 >> 10, tok0 = m0 & 1023;
  float* obase = outp + (size_t)bb_ * CDIM * NTOK + tok0;
  #pragma unroll
  for (int j = 0; j < 8; ++j) {
    int lin = j * 256 + t;
    int ch = lin >> 3, f4 = (lin & 7) * 4;
    *(float4*)&obase[(size_t)ch * NTOK + f4] = *(const float4*)&Ty[ch * 36 + f4];
  }
}

// -------- flash attention, QBLK=256, 8 waves (32 q-rows/wave) — R13 exact ---
__launch_bounds__(512)
__global__ void attn_kernel(const __bf16* __restrict__ qkv, const __bf16* __restrict__ vT,
                            const __bf16* __restrict__ biasB, __bf16* __restrict__ outb) {
  __shared__ __bf16 Ks[64][40];
  __shared__ __bf16 Vs[32][72];
  __shared__ __bf16 Bls[256][72];
  const int q0 = blockIdx.x * 256, h = blockIdx.y, b = blockIdx.z;
  const int t = threadIdx.x, lane = t & 63, w = t >> 6;     // 8 waves
  const int lr = lane & 15, kb = (lane >> 4) * 4;
  const size_t qbase = (size_t)b * NTOK * QKVD;
  const float qsc = SCALE * LOG2E;
  bfx8 qf[2];
  #pragma unroll
  for (int tq = 0; tq < 2; ++tq) {
    const __bf16* qp = &qkv[qbase + (size_t)(q0 + 32 * w + 16 * tq + lr) * QKVD + h * DHEAD];
    bfx4 lo = *(const bfx4*)&qp[kb];
    bfx4 hi = *(const bfx4*)&qp[kb + 16];
    #pragma unroll
    for (int j = 0; j < 4; ++j) {
      qf[tq][j]     = (__bf16)((float)lo[j] * qsc);
      qf[tq][j + 4] = (__bf16)((float)hi[j] * qsc);
    }
  }
  float l_run[2] = {0.f, 0.f};
  f32x4 oacc[2][2] = {};
  const int st_ = t & 255;
  const int krow = st_ >> 2, kc8 = (st_ & 3) * 8;   // K stage (t<256): 64x32
  const int vrow = st_ >> 3, vc8 = (st_ & 7) * 8;   // V stage (t>=256): 32x64
  const __bf16* kvptr = (t < 256)
      ? &qkv[qbase + (size_t)krow * QKVD + INNER + h * DHEAD + kc8]
      : &vT[(((size_t)b * NHEAD + h) * DHEAD + vrow) * NTOK + vc8];
  const __bf16* bbase = &biasB[((size_t)h * NTOK + q0) * NTOK];
  bfx8 rkv, rbias[4];
  auto issue = [&](int k0) {
    rkv = (t < 256) ? *(const bfx8*)&kvptr[(size_t)k0 * QKVD]
                    : *(const bfx8*)&kvptr[k0];
    #pragma unroll
    for (int j = 0; j < 4; ++j) {
      int lin = j * 512 + t;                  // 2048 chunks: 256 rows x 128B
      int br = lin >> 3, bc8 = (lin & 7) * 8;
      rbias[j] = *(const bfx8*)&bbase[(size_t)br * NTOK + k0 + bc8];
    }
  };
  issue(0);
  for (int kt = 0; kt < 16; ++kt) {
    __syncthreads();
    if (t < 256) *(bfx8*)&Ks[krow][kc8] = rkv;
    else         *(bfx8*)&Vs[vrow][vc8] = rkv;
    #pragma unroll
    for (int j = 0; j < 4; ++j) {
      int lin = j * 512 + t;
      int br = lin >> 3, bc8 = (lin & 7) * 8;
      *(bfx8*)&Bls[br][bc8] = rbias[j];
    }
    __syncthreads();
    if (kt < 15) issue((kt + 1) * 64);
    bfx8 kf[4], vfr[4];
    #pragma unroll
    for (int f = 0; f < 4; ++f) {
      bfx4 klo = *(const bfx4*)&Ks[16 * f + lr][kb];
      bfx4 khi = *(const bfx4*)&Ks[16 * f + lr][kb + 16];
      kf[f] = __builtin_shufflevector(klo, khi, 0, 1, 2, 3, 4, 5, 6, 7);
    }
    #pragma unroll
    for (int s = 0; s < 2; ++s)
      #pragma unroll
      for (int df = 0; df < 2; ++df) {
        bfx4 vlo = *(const bfx4*)&Vs[16 * df + lr][s * 32 + kb];
        bfx4 vhi = *(const bfx4*)&Vs[16 * df + lr][s * 32 + kb + 16];
        vfr[s * 2 + df] = __builtin_shufflevector(vlo, vhi, 0, 1, 2, 3, 4, 5, 6, 7);
      }
    #pragma unroll
    for (int tq = 0; tq < 2; ++tq) {
      const int qrow_l = 32 * w + 16 * tq + lr;
      f32x4 st[4];
      #pragma unroll
      for (int f = 0; f < 4; ++f) {
        bfx4 bv = *(const bfx4*)&Bls[qrow_l][16 * f + kb];
        f32x4 c;
        c[0] = (float)bv[0]; c[1] = (float)bv[1];
        c[2] = (float)bv[2]; c[3] = (float)bv[3];
        st[f] = __builtin_amdgcn_mfma_f32_16x16x32_bf16(kf[f], qf[tq], c, 0, 0, 0);
      }
      float p[4][4], tsum = 0.f;
      #pragma unroll
      for (int f = 0; f < 4; ++f)
        #pragma unroll
        for (int r = 0; r < 4; ++r) {
          float e = EXP2(st[f][r]);
          p[f][r] = e;
          tsum += e;
        }
      l_run[tq] += tsum;
      bfx8 pa0, pa1;
      #pragma unroll
      for (int r = 0; r < 4; ++r) {
        pa0[r] = (__bf16)p[0][r];  pa0[r + 4] = (__bf16)p[1][r];
        pa1[r] = (__bf16)p[2][r];  pa1[r + 4] = (__bf16)p[3][r];
      }
      #pragma unroll
      for (int s = 0; s < 2; ++s) {
        bfx8 pa = s ? pa1 : pa0;
        #pragma unroll
        for (int df = 0; df < 2; ++df)
          oacc[tq][df] = __builtin_amdgcn_mfma_f32_16x16x32_bf16(pa, vfr[s * 2 + df],
                                                                 oacc[tq][df], 0, 0, 0);
      }
    }
  }
  #pragma unroll
  for (int tq = 0; tq < 2; ++tq) {
    float l = l_run[tq];
    l += __shfl_xor(l, 16);
    l += __shfl_xor(l, 32);
    float il[4];
    #pragma unroll
    for (int r = 0; r < 4; ++r) il[r] = 1.f / __shfl(l, kb + r);
    #pragma unroll
    for (int r = 0; r < 4; ++r) {
      size_t rowoff = (size_t)b * NTOK * CDIM +
                      (size_t)(q0 + 32 * w + 16 * tq + kb + r) * CDIM + h * DHEAD;
      outb[rowoff + lr]      = (__bf16)(oacc[tq][0][r] * il[r]);
      outb[rowoff + 16 + lr] = (__bf16)(oacc[tq][1][r] * il[r]);
    }
  }
}

// ---------------------------------------------------------------------------
extern "C" void kernel_launch(void* const* d_in, const int* in_sizes, int n_in,
                              void* d_out, int out_size, void* d_ws, size_t ws_size,
                              hipStream_t stream) {
  const float* x     = (const float*)d_in[0];
  const float* ln1_g = (const float*)d_in[2];
  const float* ln1_b = (const float*)d_in[3];
  const float* Wqkv  = (const float*)d_in[4];
  const float* table = (const float*)d_in[5];
  const float* Wo    = (const float*)d_in[6];
  const float* bo    = (const float*)d_in[7];
  const float* ln2_g = (const float*)d_in[8];
  const float* ln2_b = (const float*)d_in[9];
  const float* W1    = (const float*)d_in[10];
  const float* b1    = (const float*)d_in[11];
  const float* W2    = (const float*)d_in[12];
  const float* b2    = (const float*)d_in[13];

  char* ws = (char*)d_ws;
  __bf16* t_bf  = (__bf16*)(ws + 0);          // 8 MB residual 1 (bf16)
  __bf16* t2_bf = (__bf16*)(ws + 8388608);    // 8 MB residual 2 (bf16)
  __bf16* qkv   = (__bf16*)(ws + 33554432);   // 24 MB
  __bf16* hln   = (__bf16*)(ws + 58720256);   // 8 MB (ln1 out, reused for ln2)
  __bf16* aout  = (__bf16*)(ws + 67108864);   // 8 MB
  __bf16* hid   = (__bf16*)(ws + 75497472);   // 16 MB (aliased: vT during attention)
  __bf16* vT    = (__bf16*)(ws + 75497472);   // 8.4 MB, dead before hid is written
  __bf16* biasB = (__bf16*)(ws + 92274688);   // 16 MB
  __bf16* Wqkvt = (__bf16*)(ws + 109051904);
  __bf16* Wot   = (__bf16*)(ws + 109445120);
  __bf16* W1t   = (__bf16*)(ws + 109576192);
  __bf16* W2t   = (__bf16*)(ws + 109838336);  // ends 110100480
  if (ws_size < 110100480) return;            // visible failure instead of OOB

  prepTx_kernel<<<6656, 256, 0, stream>>>(Wqkv, Wo, W1, W2, Wqkvt, Wot, W1t, W2t,
                                          table, biasB, x, ln1_g, ln1_b, t_bf, hln);
  gemmQKV_kernel<<<dim3(256, 6), 256, 0, stream>>>(hln, Wqkvt, qkv, vT);
  attn_kernel<<<dim3(4, 8, 16), 512, 0, stream>>>(qkv, vT, biasB, aout);
  gemmWoLn_kernel<<<512, 256, 0, stream>>>(aout, Wot, bo, t_bf, ln2_g, ln2_b, t2_bf, hln);
  gemmW1G_kernel<<<dim3(256, 4), 256, 0, stream>>>(hln, W1t, b1, hid);
  gemmW2T_kernel<<<512, 256, 0, stream>>>(hid, W2t, b2, t2_bf, (float*)d_out);
}